// Round 1
// baseline (9498.949 us; speedup 1.0000x reference)
//
#include <hip/hip_runtime.h>
#include <math.h>

#define N_PTS 10000
#define KNB 60
#define N_EDGES 160000

static __device__ __forceinline__ float finf() { return __int_as_float(0x7f800000); }

// ---------------- Stage 1: per-edge MLP2 + segment_max via atomicMax ----------------
__global__ __launch_bounds__(256) void k_edge1(
    const float* __restrict__ x, const int* __restrict__ ei,
    const float* __restrict__ w1a, const float* __restrict__ b1a,
    const float* __restrict__ w1b, const float* __restrict__ b1b,
    float* __restrict__ x1)
{
    __shared__ float sw1a[32 * 64];
    __shared__ float sw1b[64 * 64];
    __shared__ float sb1a[64], sb1b[64];
    int tid = threadIdx.x;
    for (int t = tid; t < 32 * 64; t += 256) sw1a[t] = w1a[t];
    for (int t = tid; t < 64 * 64; t += 256) sw1b[t] = w1b[t];
    if (tid < 64) { sb1a[tid] = b1a[tid]; sb1b[tid] = b1b[tid]; }
    __syncthreads();

    int e = blockIdx.x * 256 + tid;
    if (e >= N_EDGES) return;
    int src = ei[e];
    int dst = ei[N_EDGES + e];

    float f[32];
    const float* xi = x + (size_t)dst * 16;
    const float* xj = x + (size_t)src * 16;
#pragma unroll
    for (int d = 0; d < 16; ++d) {
        float a = xi[d];
        f[d] = a;
        f[16 + d] = xj[d] - a;
    }
    float h[64];
#pragma unroll
    for (int o = 0; o < 64; ++o) h[o] = sb1a[o];
    for (int d = 0; d < 32; ++d) {
        float fd = f[d];
#pragma unroll
        for (int o = 0; o < 64; ++o) h[o] = fmaf(fd, sw1a[d * 64 + o], h[o]);
    }
#pragma unroll
    for (int o = 0; o < 64; ++o) h[o] = fmaxf(h[o], 0.f);

    float* row = x1 + (size_t)dst * 64;
    for (int o = 0; o < 64; ++o) {
        float m = sb1b[o];
#pragma unroll 8
        for (int k = 0; k < 64; ++k) m = fmaf(h[k], sw1b[k * 64 + o], m);
        m = fmaxf(m, 0.f);
        atomicMax((int*)&row[o], __float_as_int(m));  // valid: m >= 0
    }
}

// ---------------- KNN: one block per row, 40KB LDS dist + 60x block argmin ----------------
__global__ __launch_bounds__(256) void k_knn(const float* __restrict__ feat,
                                             int* __restrict__ nbr)
{
    __shared__ float dist[N_PTS];
    __shared__ float xi_s[64];
    __shared__ float rv[256];
    __shared__ int   ri[256];
    int i = blockIdx.x;
    int tid = threadIdx.x;
    if (tid < 64) xi_s[tid] = feat[(size_t)i * 64 + tid];
    __syncthreads();

    for (int j = tid; j < N_PTS; j += 256) {
        const float4* fj = (const float4*)(feat + (size_t)j * 64);
        float d = 0.f;
#pragma unroll
        for (int q = 0; q < 16; ++q) {
            float4 a = fj[q];
            float d0 = xi_s[4 * q + 0] - a.x;
            float d1 = xi_s[4 * q + 1] - a.y;
            float d2 = xi_s[4 * q + 2] - a.z;
            float d3 = xi_s[4 * q + 3] - a.w;
            d = fmaf(d0, d0, d);
            d = fmaf(d1, d1, d);
            d = fmaf(d2, d2, d);
            d = fmaf(d3, d3, d);
        }
        dist[j] = (j == i) ? finf() : d;
    }
    __syncthreads();

    for (int t = 0; t < KNB; ++t) {
        float bv = finf();
        int bi = N_PTS;
        for (int j = tid; j < N_PTS; j += 256) {
            float d = dist[j];
            if (d < bv) { bv = d; bi = j; }  // strict <: keeps smallest index in-thread
        }
        rv[tid] = bv; ri[tid] = bi;
        __syncthreads();
        for (int s = 128; s > 0; s >>= 1) {
            if (tid < s) {
                float ov = rv[tid + s]; int oi = ri[tid + s];
                if (ov < rv[tid] || (ov == rv[tid] && oi < ri[tid])) {
                    rv[tid] = ov; ri[tid] = oi;
                }
            }
            __syncthreads();
        }
        if (tid == 0) {
            nbr[(size_t)i * KNB + t] = ri[0];
            dist[ri[0]] = finf();
        }
        __syncthreads();
    }
}

// ---------------- Stage 2: per-node EdgeConv MLP2 + max over K (block per node) ----------------
__global__ __launch_bounds__(256) void k_conv2(
    const float* __restrict__ feat, const int* __restrict__ nbr,
    const float* __restrict__ w2a, const float* __restrict__ b2a,
    const float* __restrict__ w2b, const float* __restrict__ b2b,
    float* __restrict__ out)
{
    __shared__ float sA[128 * 64];     // 32KB
    __shared__ float df[KNB][64];      // 15KB
    __shared__ float h[KNB][64];       // 15KB
    __shared__ float xi_s[64], hx[64], sba[64], sbb[64];
    __shared__ int   nbr_s[KNB];
    __shared__ float red[4][64];
    int tid = threadIdx.x;
    int i = blockIdx.x;

    for (int t = tid; t < 128 * 64; t += 256) sA[t] = w2a[t];
    if (tid < 64) { sba[tid] = b2a[tid]; sbb[tid] = b2b[tid]; xi_s[tid] = feat[(size_t)i * 64 + tid]; }
    if (tid < KNB) nbr_s[tid] = nbr[(size_t)i * KNB + tid];
    __syncthreads();

    for (int t = tid; t < KNB * 64; t += 256) {
        int k = t >> 6, d = t & 63;
        int j = nbr_s[k];
        df[k][d] = feat[(size_t)j * 64 + d] - xi_s[d];
    }
    if (tid < 64) {
        float acc = sba[tid];
        for (int d = 0; d < 64; ++d) acc = fmaf(xi_s[d], sA[d * 64 + tid], acc);
        hx[tid] = acc;
    }
    __syncthreads();

    // layer 1: h[k][o] = relu(hx[o] + sum_d df[k][d] * w2a[64+d][o])
    for (int t = tid; t < KNB * 64; t += 256) {
        int k = t >> 6, o = t & 63;
        float acc = hx[o];
#pragma unroll 8
        for (int d = 0; d < 64; ++d) acc = fmaf(df[k][d], sA[(64 + d) * 64 + o], acc);
        h[k][o] = fmaxf(acc, 0.f);
    }
    __syncthreads();

    // layer 2 + fold max over k (each thread's k's share the same o = tid&63)
    float mx = 0.f;
    for (int t = tid; t < KNB * 64; t += 256) {
        int k = t >> 6, o = t & 63;
        float acc = sbb[o];
#pragma unroll 8
        for (int d = 0; d < 64; ++d) acc = fmaf(h[k][d], w2b[d * 64 + o], acc);
        mx = fmaxf(mx, fmaxf(acc, 0.f));
    }
    red[tid >> 6][tid & 63] = mx;
    __syncthreads();
    if (tid < 64)
        out[(size_t)i * 64 + tid] =
            fmaxf(fmaxf(red[0][tid], red[1][tid]), fmaxf(red[2][tid], red[3][tid]));
}

// ---------------- Stage 3: single-layer EdgeConv + max over K ----------------
__global__ __launch_bounds__(256) void k_conv3(
    const float* __restrict__ feat, const int* __restrict__ nbr,
    const float* __restrict__ w3, const float* __restrict__ b3,
    float* __restrict__ out)
{
    __shared__ float sA[128 * 64];     // 32KB
    __shared__ float df[KNB][64];      // 15KB
    __shared__ float xi_s[64], hx[64], sb[64];
    __shared__ int   nbr_s[KNB];
    __shared__ float red[4][64];
    int tid = threadIdx.x;
    int i = blockIdx.x;

    for (int t = tid; t < 128 * 64; t += 256) sA[t] = w3[t];
    if (tid < 64) { sb[tid] = b3[tid]; xi_s[tid] = feat[(size_t)i * 64 + tid]; }
    if (tid < KNB) nbr_s[tid] = nbr[(size_t)i * KNB + tid];
    __syncthreads();

    for (int t = tid; t < KNB * 64; t += 256) {
        int k = t >> 6, d = t & 63;
        int j = nbr_s[k];
        df[k][d] = feat[(size_t)j * 64 + d] - xi_s[d];
    }
    if (tid < 64) {
        float acc = sb[tid];
        for (int d = 0; d < 64; ++d) acc = fmaf(xi_s[d], sA[d * 64 + tid], acc);
        hx[tid] = acc;
    }
    __syncthreads();

    float mx = 0.f;
    for (int t = tid; t < KNB * 64; t += 256) {
        int k = t >> 6, o = t & 63;
        float acc = hx[o];
#pragma unroll 8
        for (int d = 0; d < 64; ++d) acc = fmaf(df[k][d], sA[(64 + d) * 64 + o], acc);
        mx = fmaxf(mx, fmaxf(acc, 0.f));
    }
    red[tid >> 6][tid & 63] = mx;
    __syncthreads();
    if (tid < 64)
        out[(size_t)i * 64 + tid] =
            fmaxf(fmaxf(red[0][tid], red[1][tid]), fmaxf(red[2][tid], red[3][tid]));
}

// ---------------- concat [x1 | y | z] -> s1 (N x 192) ----------------
__global__ void k_concat(const float* __restrict__ x1, const float* __restrict__ yv,
                         const float* __restrict__ zv, float* __restrict__ s1)
{
    int gid = blockIdx.x * 256 + threadIdx.x;
    if (gid >= N_PTS * 192) return;
    int n = gid / 192, c = gid % 192;
    float v = (c < 64) ? x1[n * 64 + c]
            : (c < 128) ? yv[n * 64 + (c - 64)]
                        : zv[n * 64 + (c - 128)];
    s1[gid] = v;
}

// ---------------- generic FC: out = relu(in @ W + b), NB rows per block ----------------
template <int IN_DIM, int OUT_DIM, int NB, int THREADS>
__global__ __launch_bounds__(THREADS) void k_fc(
    const float* __restrict__ in, const float* __restrict__ W,
    const float* __restrict__ bias, float* __restrict__ out)
{
    __shared__ float s_in[NB][IN_DIM];
    constexpr int OCHUNKS = OUT_DIM / THREADS;
    int tid = threadIdx.x;
    int nblk = blockIdx.x / OCHUNKS;
    int ochunk = blockIdx.x % OCHUNKS;
    int n0 = nblk * NB;
    for (int t = tid; t < NB * IN_DIM; t += THREADS) {
        int r = t / IN_DIM, c = t % IN_DIM;
        s_in[r][c] = in[(size_t)(n0 + r) * IN_DIM + c];
    }
    __syncthreads();
    int o = ochunk * THREADS + tid;
    float acc[NB];
#pragma unroll
    for (int r = 0; r < NB; ++r) acc[r] = 0.f;
    for (int k = 0; k < IN_DIM; ++k) {
        float w = W[(size_t)k * OUT_DIM + o];
#pragma unroll
        for (int r = 0; r < NB; ++r) acc[r] = fmaf(s_in[r][k], w, acc[r]);
    }
    float b = bias[o];
#pragma unroll
    for (int r = 0; r < NB; ++r)
        out[(size_t)(n0 + r) * OUT_DIM + o] = fmaxf(acc[r] + b, 0.f);
}

// ---------------- FC2: dual-input (s1:192 | a:1024) @ wf2(1216x256) ----------------
__global__ __launch_bounds__(256) void k_fc2(
    const float* __restrict__ s1, const float* __restrict__ av,
    const float* __restrict__ W, const float* __restrict__ bias,
    float* __restrict__ out)
{
    __shared__ float s_in[8][1216];
    int tid = threadIdx.x;
    int n0 = blockIdx.x * 8;
    for (int t = tid; t < 8 * 192; t += 256) {
        int r = t / 192, c = t % 192;
        s_in[r][c] = s1[(size_t)(n0 + r) * 192 + c];
    }
    for (int t = tid; t < 8 * 1024; t += 256) {
        int r = t / 1024, c = t % 1024;
        s_in[r][192 + c] = av[(size_t)(n0 + r) * 1024 + c];
    }
    __syncthreads();
    float acc[8];
#pragma unroll
    for (int r = 0; r < 8; ++r) acc[r] = 0.f;
    for (int k = 0; k < 1216; ++k) {
        float w = W[(size_t)k * 256 + tid];
#pragma unroll
        for (int r = 0; r < 8; ++r) acc[r] = fmaf(s_in[r][k], w, acc[r]);
    }
    float b = bias[tid];
#pragma unroll
    for (int r = 0; r < 8; ++r)
        out[(size_t)(n0 + r) * 256 + tid] = fmaxf(acc[r] + b, 0.f);
}

// ---------------- FC5 + sigmoid + BCE partial sums ----------------
__global__ __launch_bounds__(256) void k_fc5(
    const float* __restrict__ in, const float* __restrict__ w5,
    const float* __restrict__ b5, const float* __restrict__ labels,
    float* __restrict__ out, float* __restrict__ lsum)
{
    __shared__ float red[4];
    int tid = threadIdx.x;
    int lane = tid & 63;
    int wv = tid >> 6;
    int n = blockIdx.x * 4 + wv;
    float part = 0.f;
    if (n < N_PTS) {
        const float* r = in + (size_t)n * 128;
        float d = r[lane] * w5[lane] + r[64 + lane] * w5[64 + lane];
        for (int off = 32; off > 0; off >>= 1) d += __shfl_down(d, off, 64);
        if (lane == 0) {
            float v = d + b5[0];
            float s = 1.f / (1.f + expf(-v));
            out[1 + n] = s;
            float p = fminf(fmaxf(s, 1e-7f), 1.f - 1e-7f);
            float lab = labels[n];
            part = lab * logf(p) + (1.f - lab) * logf(1.f - p);
        }
    }
    if (lane == 0) red[wv] = part;
    __syncthreads();
    if (tid == 0) atomicAdd(lsum, red[0] + red[1] + red[2] + red[3]);
}

__global__ void k_final(const float* __restrict__ lsum, float* __restrict__ out)
{
    out[0] = -lsum[0] / (float)N_PTS;
}

// ---------------- launch ----------------
extern "C" void kernel_launch(void* const* d_in, const int* in_sizes, int n_in,
                              void* d_out, int out_size, void* d_ws, size_t ws_size,
                              hipStream_t stream)
{
    const float* x   = (const float*)d_in[0];
    const int*   ei  = (const int*)d_in[1];
    const float* lab = (const float*)d_in[2];
    const float* w1a = (const float*)d_in[3];  const float* b1a = (const float*)d_in[4];
    const float* w1b = (const float*)d_in[5];  const float* b1b = (const float*)d_in[6];
    const float* w2a = (const float*)d_in[7];  const float* b2a = (const float*)d_in[8];
    const float* w2b = (const float*)d_in[9];  const float* b2b = (const float*)d_in[10];
    const float* w3  = (const float*)d_in[11]; const float* b3  = (const float*)d_in[12];
    const float* wf1 = (const float*)d_in[13]; const float* bf1 = (const float*)d_in[14];
    const float* wf2 = (const float*)d_in[15]; const float* bf2 = (const float*)d_in[16];
    const float* wf3 = (const float*)d_in[17]; const float* bf3 = (const float*)d_in[18];
    const float* wf4 = (const float*)d_in[19]; const float* bf4 = (const float*)d_in[20];
    const float* wf5 = (const float*)d_in[21]; const float* bf5 = (const float*)d_in[22];
    float* out = (float*)d_out;

    char* wsp = (char*)d_ws;
    size_t off = 0;
    auto alloc = [&](size_t bytes) -> void* {
        void* p = wsp + off;
        off += (bytes + 255) & ~(size_t)255;
        return p;
    };
    float* x1   = (float*)alloc((size_t)N_PTS * 64 * 4);
    float* yv   = (float*)alloc((size_t)N_PTS * 64 * 4);
    float* zv   = (float*)alloc((size_t)N_PTS * 64 * 4);
    int*   nbr  = (int*)  alloc((size_t)N_PTS * KNB * 4);
    float* s1   = (float*)alloc((size_t)N_PTS * 192 * 4);
    float* av   = (float*)alloc((size_t)N_PTS * 1024 * 4);
    float* c1   = (float*)alloc((size_t)N_PTS * 256 * 4);
    float* c2   = (float*)alloc((size_t)N_PTS * 256 * 4);
    float* c3   = (float*)alloc((size_t)N_PTS * 128 * 4);
    float* lsum = (float*)alloc(256);

    hipMemsetAsync(x1, 0, (size_t)N_PTS * 64 * 4, stream);
    hipMemsetAsync(lsum, 0, 4, stream);

    k_edge1<<<N_EDGES / 256, 256, 0, stream>>>(x, ei, w1a, b1a, w1b, b1b, x1);
    k_knn<<<N_PTS, 256, 0, stream>>>(x1, nbr);
    k_conv2<<<N_PTS, 256, 0, stream>>>(x1, nbr, w2a, b2a, w2b, b2b, yv);
    k_knn<<<N_PTS, 256, 0, stream>>>(yv, nbr);
    k_conv3<<<N_PTS, 256, 0, stream>>>(yv, nbr, w3, b3, zv);
    k_concat<<<(N_PTS * 192 + 255) / 256, 256, 0, stream>>>(x1, yv, zv, s1);
    k_fc<192, 1024, 8, 256><<<(N_PTS / 8) * (1024 / 256), 256, 0, stream>>>(s1, wf1, bf1, av);
    k_fc2<<<N_PTS / 8, 256, 0, stream>>>(s1, av, wf2, bf2, c1);
    k_fc<256, 256, 8, 256><<<N_PTS / 8, 256, 0, stream>>>(c1, wf3, bf3, c2);
    k_fc<256, 128, 8, 128><<<N_PTS / 8, 128, 0, stream>>>(c2, wf4, bf4, c3);
    k_fc5<<<(N_PTS + 3) / 4, 256, 0, stream>>>(c3, wf5, bf5, lab, out, lsum);
    k_final<<<1, 1, 0, stream>>>(lsum, out);
}

// Round 3
// 7196.485 us; speedup vs baseline: 1.3199x; 1.3199x over previous
//
#include <hip/hip_runtime.h>
#include <math.h>

#define N_PTS 10000
#define KNB 60
#define N_EDGES 160000

static __device__ __forceinline__ float finf() { return __int_as_float(0x7f800000); }

// ---------------- Stage 1: per-edge MLP2 + segment_max via atomicMax ----------------
__global__ __launch_bounds__(256) void k_edge1(
    const float* __restrict__ x, const int* __restrict__ ei,
    const float* __restrict__ w1a, const float* __restrict__ b1a,
    const float* __restrict__ w1b, const float* __restrict__ b1b,
    float* __restrict__ x1)
{
    __shared__ float sw1a[32 * 64];
    __shared__ float sw1b[64 * 64];
    __shared__ float sb1a[64], sb1b[64];
    int tid = threadIdx.x;
    for (int t = tid; t < 32 * 64; t += 256) sw1a[t] = w1a[t];
    for (int t = tid; t < 64 * 64; t += 256) sw1b[t] = w1b[t];
    if (tid < 64) { sb1a[tid] = b1a[tid]; sb1b[tid] = b1b[tid]; }
    __syncthreads();

    int e = blockIdx.x * 256 + tid;
    if (e >= N_EDGES) return;
    int src = ei[e];
    int dst = ei[N_EDGES + e];

    float f[32];
    const float* xi = x + (size_t)dst * 16;
    const float* xj = x + (size_t)src * 16;
#pragma unroll
    for (int d = 0; d < 16; ++d) {
        float a = xi[d];
        f[d] = a;
        f[16 + d] = xj[d] - a;
    }
    float h[64];
#pragma unroll
    for (int o = 0; o < 64; ++o) h[o] = sb1a[o];
    for (int d = 0; d < 32; ++d) {
        float fd = f[d];
#pragma unroll
        for (int o = 0; o < 64; ++o) h[o] = fmaf(fd, sw1a[d * 64 + o], h[o]);
    }
#pragma unroll
    for (int o = 0; o < 64; ++o) h[o] = fmaxf(h[o], 0.f);

    float* row = x1 + (size_t)dst * 64;
    for (int o = 0; o < 64; ++o) {
        float m = sb1b[o];
#pragma unroll 8
        for (int k = 0; k < 64; ++k) m = fmaf(h[k], sw1b[k * 64 + o], m);
        m = fmaxf(m, 0.f);
        atomicMax((int*)&row[o], __float_as_int(m));  // valid: m >= 0
    }
}

// ---------------- KNN via 2-level radix select on float bits ----------------
// Set-selection only: downstream max-pool over k is permutation-invariant.
// Tie-break at the boundary bin by (key, index) lex-min == top_k stability.

static __device__ __forceinline__ void radix_find(
    unsigned* hist, unsigned* csum, unsigned need, int tid,
    volatile unsigned* outB, volatile unsigned* outCB)
{
    int base = tid * 8;
    unsigned my = 0;
#pragma unroll
    for (int b = 0; b < 8; ++b) my += hist[base + b];
    csum[tid] = my;
    __syncthreads();
    // Hillis-Steele inclusive scan over 256 chunk sums
    for (int off = 1; off < 256; off <<= 1) {
        unsigned add = (tid >= off) ? csum[tid - off] : 0u;
        __syncthreads();
        csum[tid] += add;
        __syncthreads();
    }
    unsigned incl = csum[tid];
    unsigned excl = incl - my;
    if (excl < need && incl >= need) {   // exactly one thread
        unsigned run = excl;
#pragma unroll
        for (int b = 0; b < 8; ++b) {
            unsigned h = hist[base + b];
            if (run + h >= need) { *outB = base + b; *outCB = run; break; }
            run += h;
        }
    }
    __syncthreads();
}

__global__ __launch_bounds__(256) void k_knn(const float* __restrict__ feat,
                                             int* __restrict__ nbr)
{
    __shared__ unsigned keys[N_PTS];        // 40000 B
    __shared__ unsigned hist[2048];         // 8192 B
    __shared__ unsigned csum[256];          // 1024 B
    __shared__ unsigned cand_key[512];      // 2048 B
    __shared__ int      cand_idx[512];      // 2048 B
    __shared__ float    xi_s[64];
    __shared__ unsigned sB1, sCB1, sB2, sCB2, s_cnt, s_slot;

    int i = blockIdx.x;
    int tid = threadIdx.x;
    if (tid < 64) xi_s[tid] = feat[(size_t)i * 64 + tid];
    if (tid == 0) { s_cnt = 0; s_slot = 0; }
    __syncthreads();

    float4 xr[16];
#pragma unroll
    for (int q = 0; q < 16; ++q) xr[q] = ((const float4*)xi_s)[q];

    // distance phase (identical arithmetic to round 1 -> identical selection)
    for (int j = tid; j < N_PTS; j += 256) {
        const float4* fj = (const float4*)(feat + (size_t)j * 64);
        float d = 0.f;
#pragma unroll
        for (int q = 0; q < 16; ++q) {
            float4 a = fj[q];
            float d0 = xr[q].x - a.x;
            float d1 = xr[q].y - a.y;
            float d2 = xr[q].z - a.z;
            float d3 = xr[q].w - a.w;
            d = fmaf(d0, d0, d);
            d = fmaf(d1, d1, d);
            d = fmaf(d2, d2, d);
            d = fmaf(d3, d3, d);
        }
        keys[j] = (j == i) ? 0x7f800000u : __float_as_uint(d);
    }

    // level-1 histogram on bits 30:20
    for (int b = tid; b < 2048; b += 256) hist[b] = 0;
    __syncthreads();
    for (int j = tid; j < N_PTS; j += 256) atomicAdd(&hist[keys[j] >> 20], 1u);
    __syncthreads();
    radix_find(hist, csum, KNB, tid, &sB1, &sCB1);
    unsigned B1 = sB1;
    unsigned need2 = KNB - sCB1;

    // level-2 histogram on bits 19:9 within bin B1
    for (int b = tid; b < 2048; b += 256) hist[b] = 0;
    __syncthreads();
    for (int j = tid; j < N_PTS; j += 256) {
        unsigned k = keys[j];
        if ((k >> 20) == B1) atomicAdd(&hist[(k >> 9) & 2047u], 1u);
    }
    __syncthreads();
    radix_find(hist, csum, need2, tid, &sB2, &sCB2);
    unsigned B2 = sB2;

    // gather: definite neighbors + boundary candidates
    for (int j = tid; j < N_PTS; j += 256) {
        unsigned k = keys[j];
        unsigned b1 = k >> 20;
        if (b1 < B1) {
            unsigned slot = atomicAdd(&s_slot, 1u);
            nbr[(size_t)i * KNB + slot] = j;
        } else if (b1 == B1) {
            unsigned b2 = (k >> 9) & 2047u;
            if (b2 < B2) {
                unsigned slot = atomicAdd(&s_slot, 1u);
                nbr[(size_t)i * KNB + slot] = j;
            } else if (b2 == B2) {
                unsigned c = atomicAdd(&s_cnt, 1u);
                if (c < 512) { cand_key[c] = k; cand_idx[c] = j; }
            }
        }
    }
    __syncthreads();

    // resolve boundary bin: needf smallest by (key, idx)
    if (tid == 0) {
        int definite = (int)s_slot;
        int needf = KNB - definite;
        int cnt = (int)(s_cnt < 512u ? s_cnt : 512u);
        for (int t = 0; t < needf; ++t) {
            unsigned bk = 0xFFFFFFFFu;
            int bi = 0x7FFFFFFF, bp = -1;
            for (int c = 0; c < cnt; ++c) {
                unsigned k = cand_key[c];
                int id = cand_idx[c];
                if (k < bk || (k == bk && id < bi)) { bk = k; bi = id; bp = c; }
            }
            cand_key[bp] = 0xFFFFFFFFu;
            nbr[(size_t)i * KNB + definite + t] = bi;
        }
    }
}

// ---------------- Stage 2: per-node EdgeConv MLP2 + max over K (block per node) ----------------
__global__ __launch_bounds__(256) void k_conv2(
    const float* __restrict__ feat, const int* __restrict__ nbr,
    const float* __restrict__ w2a, const float* __restrict__ b2a,
    const float* __restrict__ w2b, const float* __restrict__ b2b,
    float* __restrict__ out)
{
    __shared__ float sA[128 * 64];     // 32KB
    __shared__ float df[KNB][64];      // 15KB
    __shared__ float h[KNB][64];       // 15KB
    __shared__ float xi_s[64], hx[64], sba[64], sbb[64];
    __shared__ int   nbr_s[KNB];
    __shared__ float red[4][64];
    int tid = threadIdx.x;
    int i = blockIdx.x;

    for (int t = tid; t < 128 * 64; t += 256) sA[t] = w2a[t];
    if (tid < 64) { sba[tid] = b2a[tid]; sbb[tid] = b2b[tid]; xi_s[tid] = feat[(size_t)i * 64 + tid]; }
    if (tid < KNB) nbr_s[tid] = nbr[(size_t)i * KNB + tid];
    __syncthreads();

    for (int t = tid; t < KNB * 64; t += 256) {
        int k = t >> 6, d = t & 63;
        int j = nbr_s[k];
        df[k][d] = feat[(size_t)j * 64 + d] - xi_s[d];
    }
    if (tid < 64) {
        float acc = sba[tid];
        for (int d = 0; d < 64; ++d) acc = fmaf(xi_s[d], sA[d * 64 + tid], acc);
        hx[tid] = acc;
    }
    __syncthreads();

    // layer 1: h[k][o] = relu(hx[o] + sum_d df[k][d] * w2a[64+d][o])
    for (int t = tid; t < KNB * 64; t += 256) {
        int k = t >> 6, o = t & 63;
        float acc = hx[o];
#pragma unroll 8
        for (int d = 0; d < 64; ++d) acc = fmaf(df[k][d], sA[(64 + d) * 64 + o], acc);
        h[k][o] = fmaxf(acc, 0.f);
    }
    __syncthreads();

    // layer 2 + fold max over k (each thread's k's share the same o = tid&63)
    float mx = 0.f;
    for (int t = tid; t < KNB * 64; t += 256) {
        int k = t >> 6, o = t & 63;
        float acc = sbb[o];
#pragma unroll 8
        for (int d = 0; d < 64; ++d) acc = fmaf(h[k][d], w2b[d * 64 + o], acc);
        mx = fmaxf(mx, fmaxf(acc, 0.f));
    }
    red[tid >> 6][tid & 63] = mx;
    __syncthreads();
    if (tid < 64)
        out[(size_t)i * 64 + tid] =
            fmaxf(fmaxf(red[0][tid], red[1][tid]), fmaxf(red[2][tid], red[3][tid]));
}

// ---------------- Stage 3: single-layer EdgeConv + max over K ----------------
__global__ __launch_bounds__(256) void k_conv3(
    const float* __restrict__ feat, const int* __restrict__ nbr,
    const float* __restrict__ w3, const float* __restrict__ b3,
    float* __restrict__ out)
{
    __shared__ float sA[128 * 64];     // 32KB
    __shared__ float df[KNB][64];      // 15KB
    __shared__ float xi_s[64], hx[64], sb[64];
    __shared__ int   nbr_s[KNB];
    __shared__ float red[4][64];
    int tid = threadIdx.x;
    int i = blockIdx.x;

    for (int t = tid; t < 128 * 64; t += 256) sA[t] = w3[t];
    if (tid < 64) { sb[tid] = b3[tid]; xi_s[tid] = feat[(size_t)i * 64 + tid]; }
    if (tid < KNB) nbr_s[tid] = nbr[(size_t)i * KNB + tid];
    __syncthreads();

    for (int t = tid; t < KNB * 64; t += 256) {
        int k = t >> 6, d = t & 63;
        int j = nbr_s[k];
        df[k][d] = feat[(size_t)j * 64 + d] - xi_s[d];
    }
    if (tid < 64) {
        float acc = sb[tid];
        for (int d = 0; d < 64; ++d) acc = fmaf(xi_s[d], sA[d * 64 + tid], acc);
        hx[tid] = acc;
    }
    __syncthreads();

    float mx = 0.f;
    for (int t = tid; t < KNB * 64; t += 256) {
        int k = t >> 6, o = t & 63;
        float acc = hx[o];
#pragma unroll 8
        for (int d = 0; d < 64; ++d) acc = fmaf(df[k][d], sA[(64 + d) * 64 + o], acc);
        mx = fmaxf(mx, fmaxf(acc, 0.f));
    }
    red[tid >> 6][tid & 63] = mx;
    __syncthreads();
    if (tid < 64)
        out[(size_t)i * 64 + tid] =
            fmaxf(fmaxf(red[0][tid], red[1][tid]), fmaxf(red[2][tid], red[3][tid]));
}

// ---------------- concat [x1 | y | z] -> s1 (N x 192) ----------------
__global__ void k_concat(const float* __restrict__ x1, const float* __restrict__ yv,
                         const float* __restrict__ zv, float* __restrict__ s1)
{
    int gid = blockIdx.x * 256 + threadIdx.x;
    if (gid >= N_PTS * 192) return;
    int n = gid / 192, c = gid % 192;
    float v = (c < 64) ? x1[n * 64 + c]
            : (c < 128) ? yv[n * 64 + (c - 64)]
                        : zv[n * 64 + (c - 128)];
    s1[gid] = v;
}

// ---------------- generic FC: out = relu(in @ W + b), NB rows per block ----------------
template <int IN_DIM, int OUT_DIM, int NB, int THREADS>
__global__ __launch_bounds__(THREADS) void k_fc(
    const float* __restrict__ in, const float* __restrict__ W,
    const float* __restrict__ bias, float* __restrict__ out)
{
    __shared__ float s_in[NB][IN_DIM];
    constexpr int OCHUNKS = OUT_DIM / THREADS;
    int tid = threadIdx.x;
    int nblk = blockIdx.x / OCHUNKS;
    int ochunk = blockIdx.x % OCHUNKS;
    int n0 = nblk * NB;
    for (int t = tid; t < NB * IN_DIM; t += THREADS) {
        int r = t / IN_DIM, c = t % IN_DIM;
        s_in[r][c] = in[(size_t)(n0 + r) * IN_DIM + c];
    }
    __syncthreads();
    int o = ochunk * THREADS + tid;
    float acc[NB];
#pragma unroll
    for (int r = 0; r < NB; ++r) acc[r] = 0.f;
    for (int k = 0; k < IN_DIM; ++k) {
        float w = W[(size_t)k * OUT_DIM + o];
#pragma unroll
        for (int r = 0; r < NB; ++r) acc[r] = fmaf(s_in[r][k], w, acc[r]);
    }
    float b = bias[o];
#pragma unroll
    for (int r = 0; r < NB; ++r)
        out[(size_t)(n0 + r) * OUT_DIM + o] = fmaxf(acc[r] + b, 0.f);
}

// ---------------- FC2: dual-input (s1:192 | a:1024) @ wf2(1216x256) ----------------
__global__ __launch_bounds__(256) void k_fc2(
    const float* __restrict__ s1, const float* __restrict__ av,
    const float* __restrict__ W, const float* __restrict__ bias,
    float* __restrict__ out)
{
    __shared__ float s_in[8][1216];
    int tid = threadIdx.x;
    int n0 = blockIdx.x * 8;
    for (int t = tid; t < 8 * 192; t += 256) {
        int r = t / 192, c = t % 192;
        s_in[r][c] = s1[(size_t)(n0 + r) * 192 + c];
    }
    for (int t = tid; t < 8 * 1024; t += 256) {
        int r = t / 1024, c = t % 1024;
        s_in[r][192 + c] = av[(size_t)(n0 + r) * 1024 + c];
    }
    __syncthreads();
    float acc[8];
#pragma unroll
    for (int r = 0; r < 8; ++r) acc[r] = 0.f;
    for (int k = 0; k < 1216; ++k) {
        float w = W[(size_t)k * 256 + tid];
#pragma unroll
        for (int r = 0; r < 8; ++r) acc[r] = fmaf(s_in[r][k], w, acc[r]);
    }
    float b = bias[tid];
#pragma unroll
    for (int r = 0; r < 8; ++r)
        out[(size_t)(n0 + r) * 256 + tid] = fmaxf(acc[r] + b, 0.f);
}

// ---------------- FC5 + sigmoid + BCE partial sums ----------------
__global__ __launch_bounds__(256) void k_fc5(
    const float* __restrict__ in, const float* __restrict__ w5,
    const float* __restrict__ b5, const float* __restrict__ labels,
    float* __restrict__ out, float* __restrict__ lsum)
{
    __shared__ float red[4];
    int tid = threadIdx.x;
    int lane = tid & 63;
    int wv = tid >> 6;
    int n = blockIdx.x * 4 + wv;
    float part = 0.f;
    if (n < N_PTS) {
        const float* r = in + (size_t)n * 128;
        float d = r[lane] * w5[lane] + r[64 + lane] * w5[64 + lane];
        for (int off = 32; off > 0; off >>= 1) d += __shfl_down(d, off, 64);
        if (lane == 0) {
            float v = d + b5[0];
            float s = 1.f / (1.f + expf(-v));
            out[1 + n] = s;
            float p = fminf(fmaxf(s, 1e-7f), 1.f - 1e-7f);
            float lab = labels[n];
            part = lab * logf(p) + (1.f - lab) * logf(1.f - p);
        }
    }
    if (lane == 0) red[wv] = part;
    __syncthreads();
    if (tid == 0) atomicAdd(lsum, red[0] + red[1] + red[2] + red[3]);
}

__global__ void k_final(const float* __restrict__ lsum, float* __restrict__ out)
{
    out[0] = -lsum[0] / (float)N_PTS;
}

// ---------------- launch ----------------
extern "C" void kernel_launch(void* const* d_in, const int* in_sizes, int n_in,
                              void* d_out, int out_size, void* d_ws, size_t ws_size,
                              hipStream_t stream)
{
    const float* x   = (const float*)d_in[0];
    const int*   ei  = (const int*)d_in[1];
    const float* lab = (const float*)d_in[2];
    const float* w1a = (const float*)d_in[3];  const float* b1a = (const float*)d_in[4];
    const float* w1b = (const float*)d_in[5];  const float* b1b = (const float*)d_in[6];
    const float* w2a = (const float*)d_in[7];  const float* b2a = (const float*)d_in[8];
    const float* w2b = (const float*)d_in[9];  const float* b2b = (const float*)d_in[10];
    const float* w3  = (const float*)d_in[11]; const float* b3  = (const float*)d_in[12];
    const float* wf1 = (const float*)d_in[13]; const float* bf1 = (const float*)d_in[14];
    const float* wf2 = (const float*)d_in[15]; const float* bf2 = (const float*)d_in[16];
    const float* wf3 = (const float*)d_in[17]; const float* bf3 = (const float*)d_in[18];
    const float* wf4 = (const float*)d_in[19]; const float* bf4 = (const float*)d_in[20];
    const float* wf5 = (const float*)d_in[21]; const float* bf5 = (const float*)d_in[22];
    float* out = (float*)d_out;

    char* wsp = (char*)d_ws;
    size_t off = 0;
    auto alloc = [&](size_t bytes) -> void* {
        void* p = wsp + off;
        off += (bytes + 255) & ~(size_t)255;
        return p;
    };
    float* x1   = (float*)alloc((size_t)N_PTS * 64 * 4);
    float* yv   = (float*)alloc((size_t)N_PTS * 64 * 4);
    float* zv   = (float*)alloc((size_t)N_PTS * 64 * 4);
    int*   nbr  = (int*)  alloc((size_t)N_PTS * KNB * 4);
    float* s1   = (float*)alloc((size_t)N_PTS * 192 * 4);
    float* av   = (float*)alloc((size_t)N_PTS * 1024 * 4);
    float* c1   = (float*)alloc((size_t)N_PTS * 256 * 4);
    float* c2   = (float*)alloc((size_t)N_PTS * 256 * 4);
    float* c3   = (float*)alloc((size_t)N_PTS * 128 * 4);
    float* lsum = (float*)alloc(256);

    hipMemsetAsync(x1, 0, (size_t)N_PTS * 64 * 4, stream);
    hipMemsetAsync(lsum, 0, 4, stream);

    k_edge1<<<N_EDGES / 256, 256, 0, stream>>>(x, ei, w1a, b1a, w1b, b1b, x1);
    k_knn<<<N_PTS, 256, 0, stream>>>(x1, nbr);
    k_conv2<<<N_PTS, 256, 0, stream>>>(x1, nbr, w2a, b2a, w2b, b2b, yv);
    k_knn<<<N_PTS, 256, 0, stream>>>(yv, nbr);
    k_conv3<<<N_PTS, 256, 0, stream>>>(yv, nbr, w3, b3, zv);
    k_concat<<<(N_PTS * 192 + 255) / 256, 256, 0, stream>>>(x1, yv, zv, s1);
    k_fc<192, 1024, 8, 256><<<(N_PTS / 8) * (1024 / 256), 256, 0, stream>>>(s1, wf1, bf1, av);
    k_fc2<<<N_PTS / 8, 256, 0, stream>>>(s1, av, wf2, bf2, c1);
    k_fc<256, 256, 8, 256><<<N_PTS / 8, 256, 0, stream>>>(c1, wf3, bf3, c2);
    k_fc<256, 128, 8, 128><<<N_PTS / 8, 128, 0, stream>>>(c2, wf4, bf4, c3);
    k_fc5<<<(N_PTS + 3) / 4, 256, 0, stream>>>(c3, wf5, bf5, lab, out, lsum);
    k_final<<<1, 1, 0, stream>>>(lsum, out);
}

// Round 5
// 3662.282 us; speedup vs baseline: 2.5937x; 1.9650x over previous
//
#include <hip/hip_runtime.h>
#include <math.h>

#define N_PTS 10000
#define KNB 60
#define N_EDGES 160000
#define QT 20              // queries per k_dist tile
#define NG 2500            // point-groups of 4 (10000/4)
#define CHUNK 1000         // query rows per D-chunk (40 MB)
#define JSPLIT 5           // point-axis split in k_dist (NG/JSPLIT = 500)

static __device__ __forceinline__ float finf() { return __int_as_float(0x7f800000); }

// ---------------- Stage 1: per-edge MLP2 + segment_max via atomicMax ----------------
__global__ __launch_bounds__(256) void k_edge1(
    const float* __restrict__ x, const int* __restrict__ ei,
    const float* __restrict__ w1a, const float* __restrict__ b1a,
    const float* __restrict__ w1b, const float* __restrict__ b1b,
    float* __restrict__ x1)
{
    __shared__ float sw1a[32 * 64];
    __shared__ float sw1b[64 * 64];
    __shared__ float sb1a[64], sb1b[64];
    int tid = threadIdx.x;
    for (int t = tid; t < 32 * 64; t += 256) sw1a[t] = w1a[t];
    for (int t = tid; t < 64 * 64; t += 256) sw1b[t] = w1b[t];
    if (tid < 64) { sb1a[tid] = b1a[tid]; sb1b[tid] = b1b[tid]; }
    __syncthreads();

    int e = blockIdx.x * 256 + tid;
    if (e >= N_EDGES) return;
    int src = ei[e];
    int dst = ei[N_EDGES + e];

    float f[32];
    const float* xi = x + (size_t)dst * 16;
    const float* xj = x + (size_t)src * 16;
#pragma unroll
    for (int d = 0; d < 16; ++d) {
        float a = xi[d];
        f[d] = a;
        f[16 + d] = xj[d] - a;
    }
    float h[64];
#pragma unroll
    for (int o = 0; o < 64; ++o) h[o] = sb1a[o];
    for (int d = 0; d < 32; ++d) {
        float fd = f[d];
#pragma unroll
        for (int o = 0; o < 64; ++o) h[o] = fmaf(fd, sw1a[d * 64 + o], h[o]);
    }
#pragma unroll
    for (int o = 0; o < 64; ++o) h[o] = fmaxf(h[o], 0.f);

    float* row = x1 + (size_t)dst * 64;
    for (int o = 0; o < 64; ++o) {
        float m = sb1b[o];
#pragma unroll 8
        for (int k = 0; k < 64; ++k) m = fmaf(h[k], sw1b[k * 64 + o], m);
        m = fmaxf(m, 0.f);
        atomicMax((int*)&row[o], __float_as_int(m));  // valid: m >= 0
    }
}

// ---------------- transpose feat[10000][64] -> featT[64][10000] ----------------
__global__ __launch_bounds__(256) void k_transpose(const float* __restrict__ feat,
                                                   float* __restrict__ featT)
{
    __shared__ float tile[64][65];
    int tid = threadIdx.x;
    int jb = blockIdx.x * 64;
    for (int t = tid; t < 64 * 64; t += 256) {
        int j = t >> 6, d = t & 63;
        if (jb + j < N_PTS) tile[j][d] = feat[(size_t)(jb + j) * 64 + d];
    }
    __syncthreads();
    for (int t = tid; t < 64 * 64; t += 256) {
        int d = t >> 6, j = t & 63;
        if (jb + j < N_PTS) featT[(size_t)d * N_PTS + jb + j] = tile[j][d];
    }
}

// ---------------- distance chunk: rows [row0, row0+CHUNK), QT queries x 500 groups/block ----
// Per-pair fmaf chain is dims-ascending (single accumulator) == verified round-1/3 chain.
__global__ __launch_bounds__(256) void k_dist(const float* __restrict__ feat,
                                              const float* __restrict__ featT,
                                              float* __restrict__ D, int row0)
{
    __shared__ float qtile[QT][64];
    int tid = threadIdx.x;
    int qi = blockIdx.x / JSPLIT;
    int js = blockIdx.x % JSPLIT;
    int qb = row0 + qi * QT;
    for (int t = tid; t < QT * 64; t += 256) {
        int q = t >> 6, d = t & 63;
        qtile[q][d] = feat[(size_t)(qb + q) * 64 + d];
    }
    __syncthreads();

    const float4* fT4 = (const float4*)featT;       // [64][NG] float4s
    const float4* qt4 = (const float4*)qtile;       // [QT][16]
    int g0 = js * (NG / JSPLIT);
    int g1 = g0 + (NG / JSPLIT);

    for (int g = g0 + tid; g < g1; g += 256) {
        float acc[QT][4];
#pragma unroll
        for (int q = 0; q < QT; ++q) {
            acc[q][0] = 0.f; acc[q][1] = 0.f; acc[q][2] = 0.f; acc[q][3] = 0.f;
        }
        for (int dc = 0; dc < 16; ++dc) {
            float4 p0 = fT4[(size_t)(4 * dc + 0) * NG + g];
            float4 p1 = fT4[(size_t)(4 * dc + 1) * NG + g];
            float4 p2 = fT4[(size_t)(4 * dc + 2) * NG + g];
            float4 p3 = fT4[(size_t)(4 * dc + 3) * NG + g];
#pragma unroll
            for (int q = 0; q < QT; ++q) {
                float4 xq = qt4[q * 16 + dc];       // LDS broadcast
                float dx;
                dx = xq.x - p0.x; acc[q][0] = fmaf(dx, dx, acc[q][0]);
                dx = xq.y - p1.x; acc[q][0] = fmaf(dx, dx, acc[q][0]);
                dx = xq.z - p2.x; acc[q][0] = fmaf(dx, dx, acc[q][0]);
                dx = xq.w - p3.x; acc[q][0] = fmaf(dx, dx, acc[q][0]);
                dx = xq.x - p0.y; acc[q][1] = fmaf(dx, dx, acc[q][1]);
                dx = xq.y - p1.y; acc[q][1] = fmaf(dx, dx, acc[q][1]);
                dx = xq.z - p2.y; acc[q][1] = fmaf(dx, dx, acc[q][1]);
                dx = xq.w - p3.y; acc[q][1] = fmaf(dx, dx, acc[q][1]);
                dx = xq.x - p0.z; acc[q][2] = fmaf(dx, dx, acc[q][2]);
                dx = xq.y - p1.z; acc[q][2] = fmaf(dx, dx, acc[q][2]);
                dx = xq.z - p2.z; acc[q][2] = fmaf(dx, dx, acc[q][2]);
                dx = xq.w - p3.z; acc[q][2] = fmaf(dx, dx, acc[q][2]);
                dx = xq.x - p0.w; acc[q][3] = fmaf(dx, dx, acc[q][3]);
                dx = xq.y - p1.w; acc[q][3] = fmaf(dx, dx, acc[q][3]);
                dx = xq.z - p2.w; acc[q][3] = fmaf(dx, dx, acc[q][3]);
                dx = xq.w - p3.w; acc[q][3] = fmaf(dx, dx, acc[q][3]);
            }
        }
#pragma unroll
        for (int q = 0; q < QT; ++q) {
            float4 v = make_float4(acc[q][0], acc[q][1], acc[q][2], acc[q][3]);
            ((float4*)(D + (size_t)(qb + q - row0) * N_PTS))[g] = v;
        }
    }
}

// ---------------- radix select (2-level, keys in registers) ----------------
static __device__ __forceinline__ void radix_find(
    unsigned* hist, unsigned* csum, unsigned need, int tid,
    volatile unsigned* outB, volatile unsigned* outCB)
{
    int base = tid * 8;
    unsigned my = 0;
#pragma unroll
    for (int b = 0; b < 8; ++b) my += hist[base + b];
    csum[tid] = my;
    __syncthreads();
    for (int off = 1; off < 256; off <<= 1) {
        unsigned add = (tid >= off) ? csum[tid - off] : 0u;
        __syncthreads();
        csum[tid] += add;
        __syncthreads();
    }
    unsigned incl = csum[tid];
    unsigned excl = incl - my;
    if (excl < need && incl >= need) {   // exactly one thread
        unsigned run = excl;
#pragma unroll
        for (int b = 0; b < 8; ++b) {
            unsigned h = hist[base + b];
            if (run + h >= need) { *outB = base + b; *outCB = run; break; }
            run += h;
        }
    }
    __syncthreads();
}

__global__ __launch_bounds__(256) void k_select(const float* __restrict__ D,
                                                int* __restrict__ nbr, int row0)
{
    __shared__ unsigned hist[2048];
    __shared__ unsigned csum[256];
    __shared__ unsigned cand_key[512];
    __shared__ int      cand_idx[512];
    __shared__ unsigned sB1, sCB1, sB2, sCB2, s_cnt, s_slot;

    int i = row0 + blockIdx.x;
    int tid = threadIdx.x;
    if (tid == 0) { s_cnt = 0; s_slot = 0; }

    // load row into registers: 10 float4 groups per thread, g = tid + 256*r
    unsigned kv[10][4];
    const float4* row4 = (const float4*)(D + (size_t)blockIdx.x * N_PTS);
#pragma unroll
    for (int r = 0; r < 10; ++r) {
        int g = tid + 256 * r;
        if (g < NG) {
            float4 v = row4[g];
            kv[r][0] = __float_as_uint(v.x);
            kv[r][1] = __float_as_uint(v.y);
            kv[r][2] = __float_as_uint(v.z);
            kv[r][3] = __float_as_uint(v.w);
            if (g == (i >> 2)) kv[r][i & 3] = 0x7f800000u;   // diagonal -> +inf
        } else {
            kv[r][0] = kv[r][1] = kv[r][2] = kv[r][3] = 0x7fffffffu;  // OOB sentinel
        }
    }

    for (int b = tid; b < 2048; b += 256) hist[b] = 0;
    __syncthreads();
#pragma unroll
    for (int r = 0; r < 10; ++r)
#pragma unroll
        for (int c = 0; c < 4; ++c) atomicAdd(&hist[kv[r][c] >> 20], 1u);
    __syncthreads();
    radix_find(hist, csum, KNB, tid, &sB1, &sCB1);
    unsigned B1 = sB1;
    unsigned need2 = KNB - sCB1;

    for (int b = tid; b < 2048; b += 256) hist[b] = 0;
    __syncthreads();
#pragma unroll
    for (int r = 0; r < 10; ++r)
#pragma unroll
        for (int c = 0; c < 4; ++c) {
            unsigned k = kv[r][c];
            if ((k >> 20) == B1) atomicAdd(&hist[(k >> 9) & 2047u], 1u);
        }
    __syncthreads();
    radix_find(hist, csum, need2, tid, &sB2, &sCB2);
    unsigned B2 = sB2;

#pragma unroll
    for (int r = 0; r < 10; ++r)
#pragma unroll
        for (int c = 0; c < 4; ++c) {
            unsigned k = kv[r][c];
            unsigned b1 = k >> 20;
            int j = 4 * (tid + 256 * r) + c;
            if (b1 < B1) {
                unsigned slot = atomicAdd(&s_slot, 1u);
                nbr[(size_t)i * KNB + slot] = j;
            } else if (b1 == B1) {
                unsigned b2 = (k >> 9) & 2047u;
                if (b2 < B2) {
                    unsigned slot = atomicAdd(&s_slot, 1u);
                    nbr[(size_t)i * KNB + slot] = j;
                } else if (b2 == B2) {
                    unsigned cc = atomicAdd(&s_cnt, 1u);
                    if (cc < 512) { cand_key[cc] = k; cand_idx[cc] = j; }
                }
            }
        }
    __syncthreads();

    if (tid == 0) {
        int definite = (int)s_slot;
        int needf = KNB - definite;
        int cnt = (int)(s_cnt < 512u ? s_cnt : 512u);
        for (int t = 0; t < needf; ++t) {
            unsigned bk = 0xFFFFFFFFu;
            int bi = 0x7FFFFFFF, bp = -1;
            for (int c = 0; c < cnt; ++c) {
                unsigned k = cand_key[c];
                int id = cand_idx[c];
                if (k < bk || (k == bk && id < bi)) { bk = k; bi = id; bp = c; }
            }
            cand_key[bp] = 0xFFFFFFFFu;
            nbr[(size_t)i * KNB + definite + t] = bi;
        }
    }
}

// ---------------- Stage 2: per-node EdgeConv MLP2 + max over K (block per node) ----------------
__global__ __launch_bounds__(256) void k_conv2(
    const float* __restrict__ feat, const int* __restrict__ nbr,
    const float* __restrict__ w2a, const float* __restrict__ b2a,
    const float* __restrict__ w2b, const float* __restrict__ b2b,
    float* __restrict__ out)
{
    __shared__ float sA[128 * 64];     // 32KB
    __shared__ float df[KNB][64];      // 15KB
    __shared__ float h[KNB][64];       // 15KB
    __shared__ float xi_s[64], hx[64], sba[64], sbb[64];
    __shared__ int   nbr_s[KNB];
    __shared__ float red[4][64];
    int tid = threadIdx.x;
    int i = blockIdx.x;

    for (int t = tid; t < 128 * 64; t += 256) sA[t] = w2a[t];
    if (tid < 64) { sba[tid] = b2a[tid]; sbb[tid] = b2b[tid]; xi_s[tid] = feat[(size_t)i * 64 + tid]; }
    if (tid < KNB) nbr_s[tid] = nbr[(size_t)i * KNB + tid];
    __syncthreads();

    for (int t = tid; t < KNB * 64; t += 256) {
        int k = t >> 6, d = t & 63;
        int j = nbr_s[k];
        df[k][d] = feat[(size_t)j * 64 + d] - xi_s[d];
    }
    if (tid < 64) {
        float acc = sba[tid];
        for (int d = 0; d < 64; ++d) acc = fmaf(xi_s[d], sA[d * 64 + tid], acc);
        hx[tid] = acc;
    }
    __syncthreads();

    for (int t = tid; t < KNB * 64; t += 256) {
        int k = t >> 6, o = t & 63;
        float acc = hx[o];
#pragma unroll 8
        for (int d = 0; d < 64; ++d) acc = fmaf(df[k][d], sA[(64 + d) * 64 + o], acc);
        h[k][o] = fmaxf(acc, 0.f);
    }
    __syncthreads();

    float mx = 0.f;
    for (int t = tid; t < KNB * 64; t += 256) {
        int k = t >> 6, o = t & 63;
        float acc = sbb[o];
#pragma unroll 8
        for (int d = 0; d < 64; ++d) acc = fmaf(h[k][d], w2b[d * 64 + o], acc);
        mx = fmaxf(mx, fmaxf(acc, 0.f));
    }
    red[tid >> 6][tid & 63] = mx;
    __syncthreads();
    if (tid < 64)
        out[(size_t)i * 64 + tid] =
            fmaxf(fmaxf(red[0][tid], red[1][tid]), fmaxf(red[2][tid], red[3][tid]));
}

// ---------------- Stage 3: single-layer EdgeConv + max over K ----------------
__global__ __launch_bounds__(256) void k_conv3(
    const float* __restrict__ feat, const int* __restrict__ nbr,
    const float* __restrict__ w3, const float* __restrict__ b3,
    float* __restrict__ out)
{
    __shared__ float sA[128 * 64];     // 32KB
    __shared__ float df[KNB][64];      // 15KB
    __shared__ float xi_s[64], hx[64], sb[64];
    __shared__ int   nbr_s[KNB];
    __shared__ float red[4][64];
    int tid = threadIdx.x;
    int i = blockIdx.x;

    for (int t = tid; t < 128 * 64; t += 256) sA[t] = w3[t];
    if (tid < 64) { sb[tid] = b3[tid]; xi_s[tid] = feat[(size_t)i * 64 + tid]; }
    if (tid < KNB) nbr_s[tid] = nbr[(size_t)i * KNB + tid];
    __syncthreads();

    for (int t = tid; t < KNB * 64; t += 256) {
        int k = t >> 6, d = t & 63;
        int j = nbr_s[k];
        df[k][d] = feat[(size_t)j * 64 + d] - xi_s[d];
    }
    if (tid < 64) {
        float acc = sb[tid];
        for (int d = 0; d < 64; ++d) acc = fmaf(xi_s[d], sA[d * 64 + tid], acc);
        hx[tid] = acc;
    }
    __syncthreads();

    float mx = 0.f;
    for (int t = tid; t < KNB * 64; t += 256) {
        int k = t >> 6, o = t & 63;
        float acc = hx[o];
#pragma unroll 8
        for (int d = 0; d < 64; ++d) acc = fmaf(df[k][d], sA[(64 + d) * 64 + o], acc);
        mx = fmaxf(mx, fmaxf(acc, 0.f));
    }
    red[tid >> 6][tid & 63] = mx;
    __syncthreads();
    if (tid < 64)
        out[(size_t)i * 64 + tid] =
            fmaxf(fmaxf(red[0][tid], red[1][tid]), fmaxf(red[2][tid], red[3][tid]));
}

// ---------------- concat [x1 | y | z] -> s1 (N x 192) ----------------
__global__ void k_concat(const float* __restrict__ x1, const float* __restrict__ yv,
                         const float* __restrict__ zv, float* __restrict__ s1)
{
    int gid = blockIdx.x * 256 + threadIdx.x;
    if (gid >= N_PTS * 192) return;
    int n = gid / 192, c = gid % 192;
    float v = (c < 64) ? x1[n * 64 + c]
            : (c < 128) ? yv[n * 64 + (c - 64)]
                        : zv[n * 64 + (c - 128)];
    s1[gid] = v;
}

// ---------------- generic FC: out = relu(in @ W + b), NB rows per block ----------------
template <int IN_DIM, int OUT_DIM, int NB, int THREADS>
__global__ __launch_bounds__(THREADS) void k_fc(
    const float* __restrict__ in, const float* __restrict__ W,
    const float* __restrict__ bias, float* __restrict__ out)
{
    __shared__ float s_in[NB][IN_DIM];
    constexpr int OCHUNKS = OUT_DIM / THREADS;
    int tid = threadIdx.x;
    int nblk = blockIdx.x / OCHUNKS;
    int ochunk = blockIdx.x % OCHUNKS;
    int n0 = nblk * NB;
    for (int t = tid; t < NB * IN_DIM; t += THREADS) {
        int r = t / IN_DIM, c = t % IN_DIM;
        s_in[r][c] = in[(size_t)(n0 + r) * IN_DIM + c];
    }
    __syncthreads();
    int o = ochunk * THREADS + tid;
    float acc[NB];
#pragma unroll
    for (int r = 0; r < NB; ++r) acc[r] = 0.f;
    for (int k = 0; k < IN_DIM; ++k) {
        float w = W[(size_t)k * OUT_DIM + o];
#pragma unroll
        for (int r = 0; r < NB; ++r) acc[r] = fmaf(s_in[r][k], w, acc[r]);
    }
    float b = bias[o];
#pragma unroll
    for (int r = 0; r < NB; ++r)
        out[(size_t)(n0 + r) * OUT_DIM + o] = fmaxf(acc[r] + b, 0.f);
}

// ---------------- FC2: dual-input (s1:192 | a:1024) @ wf2(1216x256) ----------------
__global__ __launch_bounds__(256) void k_fc2(
    const float* __restrict__ s1, const float* __restrict__ av,
    const float* __restrict__ W, const float* __restrict__ bias,
    float* __restrict__ out)
{
    __shared__ float s_in[8][1216];
    int tid = threadIdx.x;
    int n0 = blockIdx.x * 8;
    for (int t = tid; t < 8 * 192; t += 256) {
        int r = t / 192, c = t % 192;
        s_in[r][c] = s1[(size_t)(n0 + r) * 192 + c];
    }
    for (int t = tid; t < 8 * 1024; t += 256) {
        int r = t / 1024, c = t % 1024;
        s_in[r][192 + c] = av[(size_t)(n0 + r) * 1024 + c];
    }
    __syncthreads();
    float acc[8];
#pragma unroll
    for (int r = 0; r < 8; ++r) acc[r] = 0.f;
    for (int k = 0; k < 1216; ++k) {
        float w = W[(size_t)k * 256 + tid];
#pragma unroll
        for (int r = 0; r < 8; ++r) acc[r] = fmaf(s_in[r][k], w, acc[r]);
    }
    float b = bias[tid];
#pragma unroll
    for (int r = 0; r < 8; ++r)
        out[(size_t)(n0 + r) * 256 + tid] = fmaxf(acc[r] + b, 0.f);
}

// ---------------- FC5 + sigmoid + BCE partial sums ----------------
__global__ __launch_bounds__(256) void k_fc5(
    const float* __restrict__ in, const float* __restrict__ w5,
    const float* __restrict__ b5, const float* __restrict__ labels,
    float* __restrict__ out, float* __restrict__ lsum)
{
    __shared__ float red[4];
    int tid = threadIdx.x;
    int lane = tid & 63;
    int wv = tid >> 6;
    int n = blockIdx.x * 4 + wv;
    float part = 0.f;
    if (n < N_PTS) {
        const float* r = in + (size_t)n * 128;
        float d = r[lane] * w5[lane] + r[64 + lane] * w5[64 + lane];
        for (int off = 32; off > 0; off >>= 1) d += __shfl_down(d, off, 64);
        if (lane == 0) {
            float v = d + b5[0];
            float s = 1.f / (1.f + expf(-v));
            out[1 + n] = s;
            float p = fminf(fmaxf(s, 1e-7f), 1.f - 1e-7f);
            float lab = labels[n];
            part = lab * logf(p) + (1.f - lab) * logf(1.f - p);
        }
    }
    if (lane == 0) red[wv] = part;
    __syncthreads();
    if (tid == 0) atomicAdd(lsum, red[0] + red[1] + red[2] + red[3]);
}

__global__ void k_final(const float* __restrict__ lsum, float* __restrict__ out)
{
    out[0] = -lsum[0] / (float)N_PTS;
}

// ---------------- launch ----------------
extern "C" void kernel_launch(void* const* d_in, const int* in_sizes, int n_in,
                              void* d_out, int out_size, void* d_ws, size_t ws_size,
                              hipStream_t stream)
{
    const float* x   = (const float*)d_in[0];
    const int*   ei  = (const int*)d_in[1];
    const float* lab = (const float*)d_in[2];
    const float* w1a = (const float*)d_in[3];  const float* b1a = (const float*)d_in[4];
    const float* w1b = (const float*)d_in[5];  const float* b1b = (const float*)d_in[6];
    const float* w2a = (const float*)d_in[7];  const float* b2a = (const float*)d_in[8];
    const float* w2b = (const float*)d_in[9];  const float* b2b = (const float*)d_in[10];
    const float* w3  = (const float*)d_in[11]; const float* b3  = (const float*)d_in[12];
    const float* wf1 = (const float*)d_in[13]; const float* bf1 = (const float*)d_in[14];
    const float* wf2 = (const float*)d_in[15]; const float* bf2 = (const float*)d_in[16];
    const float* wf3 = (const float*)d_in[17]; const float* bf3 = (const float*)d_in[18];
    const float* wf4 = (const float*)d_in[19]; const float* bf4 = (const float*)d_in[20];
    const float* wf5 = (const float*)d_in[21]; const float* bf5 = (const float*)d_in[22];
    float* out = (float*)d_out;

    char* wsp = (char*)d_ws;
    size_t off = 0;
    auto alloc = [&](size_t bytes) -> void* {
        void* p = wsp + off;
        off += (bytes + 255) & ~(size_t)255;
        return p;
    };
    // persistent buffers
    float* x1    = (float*)alloc((size_t)N_PTS * 64 * 4);
    float* yv    = (float*)alloc((size_t)N_PTS * 64 * 4);
    float* zv    = (float*)alloc((size_t)N_PTS * 64 * 4);
    int*   nbr   = (int*)  alloc((size_t)N_PTS * KNB * 4);
    float* lsum  = (float*)alloc(256);
    // overlapped region: {featT, Dm} during KNN ; {s1, av, c1, c2, c3} during MLP head
    size_t regionA = off;
    float* featT = (float*)alloc((size_t)64 * N_PTS * 4);            // 2.56 MB
    float* Dm    = (float*)alloc((size_t)CHUNK * N_PTS * 4);         // 40 MB
    off = regionA;                                                   // rewind: alias
    float* s1    = (float*)alloc((size_t)N_PTS * 192 * 4);
    float* av    = (float*)alloc((size_t)N_PTS * 1024 * 4);
    float* c1    = (float*)alloc((size_t)N_PTS * 256 * 4);
    float* c2    = (float*)alloc((size_t)N_PTS * 256 * 4);
    float* c3    = (float*)alloc((size_t)N_PTS * 128 * 4);

    hipMemsetAsync(x1, 0, (size_t)N_PTS * 64 * 4, stream);
    hipMemsetAsync(lsum, 0, 4, stream);

    k_edge1<<<N_EDGES / 256, 256, 0, stream>>>(x, ei, w1a, b1a, w1b, b1b, x1);

    // KNN 1 on x1 (chunked distance matrix + register radix select)
    k_transpose<<<157, 256, 0, stream>>>(x1, featT);
    for (int c = 0; c < N_PTS / CHUNK; ++c) {
        k_dist<<<(CHUNK / QT) * JSPLIT, 256, 0, stream>>>(x1, featT, Dm, c * CHUNK);
        k_select<<<CHUNK, 256, 0, stream>>>(Dm, nbr, c * CHUNK);
    }
    k_conv2<<<N_PTS, 256, 0, stream>>>(x1, nbr, w2a, b2a, w2b, b2b, yv);

    // KNN 2 on yv
    k_transpose<<<157, 256, 0, stream>>>(yv, featT);
    for (int c = 0; c < N_PTS / CHUNK; ++c) {
        k_dist<<<(CHUNK / QT) * JSPLIT, 256, 0, stream>>>(yv, featT, Dm, c * CHUNK);
        k_select<<<CHUNK, 256, 0, stream>>>(Dm, nbr, c * CHUNK);
    }
    k_conv3<<<N_PTS, 256, 0, stream>>>(yv, nbr, w3, b3, zv);

    k_concat<<<(N_PTS * 192 + 255) / 256, 256, 0, stream>>>(x1, yv, zv, s1);
    k_fc<192, 1024, 8, 256><<<(N_PTS / 8) * (1024 / 256), 256, 0, stream>>>(s1, wf1, bf1, av);
    k_fc2<<<N_PTS / 8, 256, 0, stream>>>(s1, av, wf2, bf2, c1);
    k_fc<256, 256, 8, 256><<<N_PTS / 8, 256, 0, stream>>>(c1, wf3, bf3, c2);
    k_fc<256, 128, 8, 128><<<N_PTS / 8, 128, 0, stream>>>(c2, wf4, bf4, c3);
    k_fc5<<<(N_PTS + 3) / 4, 256, 0, stream>>>(c3, wf5, bf5, lab, out, lsum);
    k_final<<<1, 1, 0, stream>>>(lsum, out);
}

// Round 6
// 3188.257 us; speedup vs baseline: 2.9794x; 1.1487x over previous
//
#include <hip/hip_runtime.h>
#include <math.h>

#define N_PTS 10000
#define KNB 60
#define N_EDGES 160000
#define QT 20              // queries per k_dist tile
#define NG 2500            // point-groups of 4 (10000/4)
#define CHUNK 1000         // query rows per D-chunk (40 MB)
#define JSPLIT 5           // point-axis split in k_dist (NG/JSPLIT = 500)
#define PAD 68             // df/h row stride: 272B rows -> 16B aligned, bank-spread

static __device__ __forceinline__ float finf() { return __int_as_float(0x7f800000); }

// ---------------- Stage 1: per-edge MLP2 + segment_max via atomicMax ----------------
__global__ __launch_bounds__(256) void k_edge1(
    const float* __restrict__ x, const int* __restrict__ ei,
    const float* __restrict__ w1a, const float* __restrict__ b1a,
    const float* __restrict__ w1b, const float* __restrict__ b1b,
    float* __restrict__ x1)
{
    __shared__ float sw1a[32 * 64];
    __shared__ float sw1b[64 * 64];
    __shared__ float sb1a[64], sb1b[64];
    int tid = threadIdx.x;
    for (int t = tid; t < 32 * 64; t += 256) sw1a[t] = w1a[t];
    for (int t = tid; t < 64 * 64; t += 256) sw1b[t] = w1b[t];
    if (tid < 64) { sb1a[tid] = b1a[tid]; sb1b[tid] = b1b[tid]; }
    __syncthreads();

    int e = blockIdx.x * 256 + tid;
    if (e >= N_EDGES) return;
    int src = ei[e];
    int dst = ei[N_EDGES + e];

    float f[32];
    const float* xi = x + (size_t)dst * 16;
    const float* xj = x + (size_t)src * 16;
#pragma unroll
    for (int d = 0; d < 16; ++d) {
        float a = xi[d];
        f[d] = a;
        f[16 + d] = xj[d] - a;
    }
    float h[64];
#pragma unroll
    for (int o = 0; o < 64; ++o) h[o] = sb1a[o];
    for (int d = 0; d < 32; ++d) {
        float fd = f[d];
#pragma unroll
        for (int o = 0; o < 64; ++o) h[o] = fmaf(fd, sw1a[d * 64 + o], h[o]);
    }
#pragma unroll
    for (int o = 0; o < 64; ++o) h[o] = fmaxf(h[o], 0.f);

    float* row = x1 + (size_t)dst * 64;
    for (int o = 0; o < 64; ++o) {
        float m = sb1b[o];
#pragma unroll 8
        for (int k = 0; k < 64; ++k) m = fmaf(h[k], sw1b[k * 64 + o], m);
        m = fmaxf(m, 0.f);
        atomicMax((int*)&row[o], __float_as_int(m));  // valid: m >= 0
    }
}

// ---------------- transpose feat[10000][64] -> featT[64][10000] ----------------
__global__ __launch_bounds__(256) void k_transpose(const float* __restrict__ feat,
                                                   float* __restrict__ featT)
{
    __shared__ float tile[64][65];
    int tid = threadIdx.x;
    int jb = blockIdx.x * 64;
    for (int t = tid; t < 64 * 64; t += 256) {
        int j = t >> 6, d = t & 63;
        if (jb + j < N_PTS) tile[j][d] = feat[(size_t)(jb + j) * 64 + d];
    }
    __syncthreads();
    for (int t = tid; t < 64 * 64; t += 256) {
        int d = t >> 6, j = t & 63;
        if (jb + j < N_PTS) featT[(size_t)d * N_PTS + jb + j] = tile[j][d];
    }
}

// ---------------- distance chunk: rows [row0, row0+CHUNK), QT queries x 500 groups/block ----
// Per-pair fmaf chain is dims-ascending (single accumulator) == verified round-1/3 chain.
__global__ __launch_bounds__(256) void k_dist(const float* __restrict__ feat,
                                              const float* __restrict__ featT,
                                              float* __restrict__ D, int row0)
{
    __shared__ float qtile[QT][64];
    int tid = threadIdx.x;
    int qi = blockIdx.x / JSPLIT;
    int js = blockIdx.x % JSPLIT;
    int qb = row0 + qi * QT;
    for (int t = tid; t < QT * 64; t += 256) {
        int q = t >> 6, d = t & 63;
        qtile[q][d] = feat[(size_t)(qb + q) * 64 + d];
    }
    __syncthreads();

    const float4* fT4 = (const float4*)featT;       // [64][NG] float4s
    const float4* qt4 = (const float4*)qtile;       // [QT][16]
    int g0 = js * (NG / JSPLIT);
    int g1 = g0 + (NG / JSPLIT);

    for (int g = g0 + tid; g < g1; g += 256) {
        float acc[QT][4];
#pragma unroll
        for (int q = 0; q < QT; ++q) {
            acc[q][0] = 0.f; acc[q][1] = 0.f; acc[q][2] = 0.f; acc[q][3] = 0.f;
        }
        for (int dc = 0; dc < 16; ++dc) {
            float4 p0 = fT4[(size_t)(4 * dc + 0) * NG + g];
            float4 p1 = fT4[(size_t)(4 * dc + 1) * NG + g];
            float4 p2 = fT4[(size_t)(4 * dc + 2) * NG + g];
            float4 p3 = fT4[(size_t)(4 * dc + 3) * NG + g];
#pragma unroll
            for (int q = 0; q < QT; ++q) {
                float4 xq = qt4[q * 16 + dc];       // LDS broadcast
                float dx;
                dx = xq.x - p0.x; acc[q][0] = fmaf(dx, dx, acc[q][0]);
                dx = xq.y - p1.x; acc[q][0] = fmaf(dx, dx, acc[q][0]);
                dx = xq.z - p2.x; acc[q][0] = fmaf(dx, dx, acc[q][0]);
                dx = xq.w - p3.x; acc[q][0] = fmaf(dx, dx, acc[q][0]);
                dx = xq.x - p0.y; acc[q][1] = fmaf(dx, dx, acc[q][1]);
                dx = xq.y - p1.y; acc[q][1] = fmaf(dx, dx, acc[q][1]);
                dx = xq.z - p2.y; acc[q][1] = fmaf(dx, dx, acc[q][1]);
                dx = xq.w - p3.y; acc[q][1] = fmaf(dx, dx, acc[q][1]);
                dx = xq.x - p0.z; acc[q][2] = fmaf(dx, dx, acc[q][2]);
                dx = xq.y - p1.z; acc[q][2] = fmaf(dx, dx, acc[q][2]);
                dx = xq.z - p2.z; acc[q][2] = fmaf(dx, dx, acc[q][2]);
                dx = xq.w - p3.z; acc[q][2] = fmaf(dx, dx, acc[q][2]);
                dx = xq.x - p0.w; acc[q][3] = fmaf(dx, dx, acc[q][3]);
                dx = xq.y - p1.w; acc[q][3] = fmaf(dx, dx, acc[q][3]);
                dx = xq.z - p2.w; acc[q][3] = fmaf(dx, dx, acc[q][3]);
                dx = xq.w - p3.w; acc[q][3] = fmaf(dx, dx, acc[q][3]);
            }
        }
#pragma unroll
        for (int q = 0; q < QT; ++q) {
            float4 v = make_float4(acc[q][0], acc[q][1], acc[q][2], acc[q][3]);
            ((float4*)(D + (size_t)(qb + q - row0) * N_PTS))[g] = v;
        }
    }
}

// ---------------- radix select (2-level, keys in registers) ----------------
static __device__ __forceinline__ void radix_find(
    unsigned* hist, unsigned* csum, unsigned need, int tid,
    volatile unsigned* outB, volatile unsigned* outCB)
{
    int base = tid * 8;
    unsigned my = 0;
#pragma unroll
    for (int b = 0; b < 8; ++b) my += hist[base + b];
    csum[tid] = my;
    __syncthreads();
    for (int off = 1; off < 256; off <<= 1) {
        unsigned add = (tid >= off) ? csum[tid - off] : 0u;
        __syncthreads();
        csum[tid] += add;
        __syncthreads();
    }
    unsigned incl = csum[tid];
    unsigned excl = incl - my;
    if (excl < need && incl >= need) {   // exactly one thread
        unsigned run = excl;
#pragma unroll
        for (int b = 0; b < 8; ++b) {
            unsigned h = hist[base + b];
            if (run + h >= need) { *outB = base + b; *outCB = run; break; }
            run += h;
        }
    }
    __syncthreads();
}

__global__ __launch_bounds__(256) void k_select(const float* __restrict__ D,
                                                int* __restrict__ nbr, int row0)
{
    __shared__ unsigned hist[2048];
    __shared__ unsigned csum[256];
    __shared__ unsigned cand_key[512];
    __shared__ int      cand_idx[512];
    __shared__ unsigned sB1, sCB1, sB2, sCB2, s_cnt, s_slot;

    int i = row0 + blockIdx.x;
    int tid = threadIdx.x;
    if (tid == 0) { s_cnt = 0; s_slot = 0; }

    // load row into registers: 10 float4 groups per thread, g = tid + 256*r
    unsigned kv[10][4];
    const float4* row4 = (const float4*)(D + (size_t)blockIdx.x * N_PTS);
#pragma unroll
    for (int r = 0; r < 10; ++r) {
        int g = tid + 256 * r;
        if (g < NG) {
            float4 v = row4[g];
            kv[r][0] = __float_as_uint(v.x);
            kv[r][1] = __float_as_uint(v.y);
            kv[r][2] = __float_as_uint(v.z);
            kv[r][3] = __float_as_uint(v.w);
            if (g == (i >> 2)) kv[r][i & 3] = 0x7f800000u;   // diagonal -> +inf
        } else {
            kv[r][0] = kv[r][1] = kv[r][2] = kv[r][3] = 0x7fffffffu;  // OOB sentinel
        }
    }

    for (int b = tid; b < 2048; b += 256) hist[b] = 0;
    __syncthreads();
#pragma unroll
    for (int r = 0; r < 10; ++r)
#pragma unroll
        for (int c = 0; c < 4; ++c) atomicAdd(&hist[kv[r][c] >> 20], 1u);
    __syncthreads();
    radix_find(hist, csum, KNB, tid, &sB1, &sCB1);
    unsigned B1 = sB1;
    unsigned need2 = KNB - sCB1;

    for (int b = tid; b < 2048; b += 256) hist[b] = 0;
    __syncthreads();
#pragma unroll
    for (int r = 0; r < 10; ++r)
#pragma unroll
        for (int c = 0; c < 4; ++c) {
            unsigned k = kv[r][c];
            if ((k >> 20) == B1) atomicAdd(&hist[(k >> 9) & 2047u], 1u);
        }
    __syncthreads();
    radix_find(hist, csum, need2, tid, &sB2, &sCB2);
    unsigned B2 = sB2;

#pragma unroll
    for (int r = 0; r < 10; ++r)
#pragma unroll
        for (int c = 0; c < 4; ++c) {
            unsigned k = kv[r][c];
            unsigned b1 = k >> 20;
            int j = 4 * (tid + 256 * r) + c;
            if (b1 < B1) {
                unsigned slot = atomicAdd(&s_slot, 1u);
                nbr[(size_t)i * KNB + slot] = j;
            } else if (b1 == B1) {
                unsigned b2 = (k >> 9) & 2047u;
                if (b2 < B2) {
                    unsigned slot = atomicAdd(&s_slot, 1u);
                    nbr[(size_t)i * KNB + slot] = j;
                } else if (b2 == B2) {
                    unsigned cc = atomicAdd(&s_cnt, 1u);
                    if (cc < 512) { cand_key[cc] = k; cand_idx[cc] = j; }
                }
            }
        }
    __syncthreads();

    if (tid == 0) {
        int definite = (int)s_slot;
        int needf = KNB - definite;
        int cnt = (int)(s_cnt < 512u ? s_cnt : 512u);
        for (int t = 0; t < needf; ++t) {
            unsigned bk = 0xFFFFFFFFu;
            int bi = 0x7FFFFFFF, bp = -1;
            for (int c = 0; c < cnt; ++c) {
                unsigned k = cand_key[c];
                int id = cand_idx[c];
                if (k < bk || (k == bk && id < bi)) { bk = k; bi = id; bp = c; }
            }
            cand_key[bp] = 0xFFFFFFFFu;
            nbr[(size_t)i * KNB + definite + t] = bi;
        }
    }
}

// ---------------- Stage 2: EdgeConv MLP2 + max over K, register-tiled ----------------
// Thread (kg,og): kg=t>>4 handles k=4kg..4kg+3 (kg==15 masked), og=t&15 handles o=4og..4og+3.
// Per-output fmaf chains are d-ascending with identical init -> bit-identical to round-1.
__global__ __launch_bounds__(256) void k_conv2(
    const float* __restrict__ feat, const int* __restrict__ nbr,
    const float* __restrict__ w2a, const float* __restrict__ b2a,
    const float* __restrict__ w2b, const float* __restrict__ b2b,
    float* __restrict__ out)
{
    __shared__ float wbuf[64 * 64];    // 16KB: phase1 w2a[0:64], phase2 w2a[64:128], phase3 w2b
    __shared__ float df[64][PAD];      // 17KB (rows 60..63 zeroed)
    __shared__ float h[64][PAD];       // 17KB
    __shared__ float xi_s[64], hx[64], sba[64], sbb[64];
    __shared__ int   nbr_s[KNB];
    __shared__ float redm[4][64];      // per-wave partial max
    int tid = threadIdx.x;
    int node = blockIdx.x;
    int og = tid & 15, kg = tid >> 4;
    int wv = tid >> 6;

    // P1: stage w2a rows 0..63 + vectors
    for (int t = tid; t < 4096; t += 256) wbuf[t] = w2a[t];
    if (tid < 64) {
        sba[tid] = b2a[tid]; sbb[tid] = b2b[tid];
        xi_s[tid] = feat[(size_t)node * 64 + tid];
    }
    if (tid < KNB) nbr_s[tid] = nbr[(size_t)node * KNB + tid];
    __syncthreads();

    // P2: hx (exact 64-chain per o, threads 0..63) + gather df + zero pad rows
    for (int t = tid; t < KNB * 64; t += 256) {
        int k = t >> 6, d = t & 63;
        df[k][d] = feat[(size_t)nbr_s[k] * 64 + d] - xi_s[d];
    }
    if (tid < 4 * 64) df[60 + (tid >> 6)][tid & 63] = 0.f;
    if (tid < 64) {
        float acc = sba[tid];
        for (int d = 0; d < 64; ++d) acc = fmaf(xi_s[d], wbuf[d * 64 + tid], acc);
        hx[tid] = acc;
    }
    __syncthreads();

    // P3: stage w2a rows 64..127
    for (int t = tid; t < 4096; t += 256) wbuf[t] = w2a[4096 + t];
    __syncthreads();

    // P4: layer 1, 4k x 4o register tile
    {
        int k0 = 4 * kg;
        float acc[4][4];
#pragma unroll
        for (int j = 0; j < 4; ++j)
#pragma unroll
            for (int i = 0; i < 4; ++i) acc[j][i] = hx[4 * og + i];
        for (int d = 0; d < 64; d += 4) {
            float4 a0 = *(const float4*)&df[k0 + 0][d];
            float4 a1 = *(const float4*)&df[k0 + 1][d];
            float4 a2 = *(const float4*)&df[k0 + 2][d];
            float4 a3 = *(const float4*)&df[k0 + 3][d];
            float4 b0 = *(const float4*)&wbuf[(d + 0) * 64 + 4 * og];
            float4 b1 = *(const float4*)&wbuf[(d + 1) * 64 + 4 * og];
            float4 b2 = *(const float4*)&wbuf[(d + 2) * 64 + 4 * og];
            float4 b3 = *(const float4*)&wbuf[(d + 3) * 64 + 4 * og];
            const float* av[4] = {(const float*)&a0, (const float*)&a1,
                                  (const float*)&a2, (const float*)&a3};
#pragma unroll
            for (int j = 0; j < 4; ++j) {
#pragma unroll
                for (int i = 0; i < 4; ++i) {
                    acc[j][i] = fmaf(av[j][0], ((const float*)&b0)[i], acc[j][i]);
                    acc[j][i] = fmaf(av[j][1], ((const float*)&b1)[i], acc[j][i]);
                    acc[j][i] = fmaf(av[j][2], ((const float*)&b2)[i], acc[j][i]);
                    acc[j][i] = fmaf(av[j][3], ((const float*)&b3)[i], acc[j][i]);
                }
            }
        }
#pragma unroll
        for (int j = 0; j < 4; ++j) {
            float4 hv;
            hv.x = fmaxf(acc[j][0], 0.f); hv.y = fmaxf(acc[j][1], 0.f);
            hv.z = fmaxf(acc[j][2], 0.f); hv.w = fmaxf(acc[j][3], 0.f);
            *(float4*)&h[k0 + j][4 * og] = hv;
        }
    }
    __syncthreads();

    // P5: stage w2b
    for (int t = tid; t < 4096; t += 256) wbuf[t] = w2b[t];
    __syncthreads();

    // P6: layer 2 + max over k
    {
        int k0 = 4 * kg;
        float acc[4][4];
#pragma unroll
        for (int j = 0; j < 4; ++j)
#pragma unroll
            for (int i = 0; i < 4; ++i) acc[j][i] = sbb[4 * og + i];
        for (int d = 0; d < 64; d += 4) {
            float4 a0 = *(const float4*)&h[k0 + 0][d];
            float4 a1 = *(const float4*)&h[k0 + 1][d];
            float4 a2 = *(const float4*)&h[k0 + 2][d];
            float4 a3 = *(const float4*)&h[k0 + 3][d];
            float4 b0 = *(const float4*)&wbuf[(d + 0) * 64 + 4 * og];
            float4 b1 = *(const float4*)&wbuf[(d + 1) * 64 + 4 * og];
            float4 b2 = *(const float4*)&wbuf[(d + 2) * 64 + 4 * og];
            float4 b3 = *(const float4*)&wbuf[(d + 3) * 64 + 4 * og];
            const float* av[4] = {(const float*)&a0, (const float*)&a1,
                                  (const float*)&a2, (const float*)&a3};
#pragma unroll
            for (int j = 0; j < 4; ++j) {
#pragma unroll
                for (int i = 0; i < 4; ++i) {
                    acc[j][i] = fmaf(av[j][0], ((const float*)&b0)[i], acc[j][i]);
                    acc[j][i] = fmaf(av[j][1], ((const float*)&b1)[i], acc[j][i]);
                    acc[j][i] = fmaf(av[j][2], ((const float*)&b2)[i], acc[j][i]);
                    acc[j][i] = fmaf(av[j][3], ((const float*)&b3)[i], acc[j][i]);
                }
            }
        }
        float m[4];
#pragma unroll
        for (int i = 0; i < 4; ++i) {
            float v = 0.f;   // all true outputs are >= 0 (relu), so 0 is identity
            if (kg < 15) {
#pragma unroll
                for (int j = 0; j < 4; ++j) v = fmaxf(v, fmaxf(acc[j][i], 0.f));
            }
            m[i] = v;
        }
        // reduce max across the wave's 4 kg-subgroups (lanes ^16, ^32)
#pragma unroll
        for (int i = 0; i < 4; ++i) {
            m[i] = fmaxf(m[i], __shfl_xor(m[i], 16, 64));
            m[i] = fmaxf(m[i], __shfl_xor(m[i], 32, 64));
        }
        if ((tid & 63) < 16) {
#pragma unroll
            for (int i = 0; i < 4; ++i) redm[wv][4 * og + i] = m[i];
        }
    }
    __syncthreads();
    if (tid < 64)
        out[(size_t)node * 64 + tid] =
            fmaxf(fmaxf(redm[0][tid], redm[1][tid]), fmaxf(redm[2][tid], redm[3][tid]));
}

// ---------------- Stage 3: single-layer EdgeConv + max over K, register-tiled ----------------
__global__ __launch_bounds__(256) void k_conv3(
    const float* __restrict__ feat, const int* __restrict__ nbr,
    const float* __restrict__ w3, const float* __restrict__ b3,
    float* __restrict__ out)
{
    __shared__ float wbuf[64 * 64];    // 16KB: phase1 w3[0:64], phase2 w3[64:128]
    __shared__ float df[64][PAD];      // 17KB
    __shared__ float xi_s[64], hx[64], sb[64];
    __shared__ int   nbr_s[KNB];
    __shared__ float redm[4][64];
    int tid = threadIdx.x;
    int node = blockIdx.x;
    int og = tid & 15, kg = tid >> 4;
    int wv = tid >> 6;

    for (int t = tid; t < 4096; t += 256) wbuf[t] = w3[t];
    if (tid < 64) { sb[tid] = b3[tid]; xi_s[tid] = feat[(size_t)node * 64 + tid]; }
    if (tid < KNB) nbr_s[tid] = nbr[(size_t)node * KNB + tid];
    __syncthreads();

    for (int t = tid; t < KNB * 64; t += 256) {
        int k = t >> 6, d = t & 63;
        df[k][d] = feat[(size_t)nbr_s[k] * 64 + d] - xi_s[d];
    }
    if (tid < 4 * 64) df[60 + (tid >> 6)][tid & 63] = 0.f;
    if (tid < 64) {
        float acc = sb[tid];
        for (int d = 0; d < 64; ++d) acc = fmaf(xi_s[d], wbuf[d * 64 + tid], acc);
        hx[tid] = acc;
    }
    __syncthreads();

    for (int t = tid; t < 4096; t += 256) wbuf[t] = w3[4096 + t];
    __syncthreads();

    {
        int k0 = 4 * kg;
        float acc[4][4];
#pragma unroll
        for (int j = 0; j < 4; ++j)
#pragma unroll
            for (int i = 0; i < 4; ++i) acc[j][i] = hx[4 * og + i];
        for (int d = 0; d < 64; d += 4) {
            float4 a0 = *(const float4*)&df[k0 + 0][d];
            float4 a1 = *(const float4*)&df[k0 + 1][d];
            float4 a2 = *(const float4*)&df[k0 + 2][d];
            float4 a3 = *(const float4*)&df[k0 + 3][d];
            float4 b0 = *(const float4*)&wbuf[(d + 0) * 64 + 4 * og];
            float4 b1 = *(const float4*)&wbuf[(d + 1) * 64 + 4 * og];
            float4 b2 = *(const float4*)&wbuf[(d + 2) * 64 + 4 * og];
            float4 b3 = *(const float4*)&wbuf[(d + 3) * 64 + 4 * og];
            const float* av[4] = {(const float*)&a0, (const float*)&a1,
                                  (const float*)&a2, (const float*)&a3};
#pragma unroll
            for (int j = 0; j < 4; ++j) {
#pragma unroll
                for (int i = 0; i < 4; ++i) {
                    acc[j][i] = fmaf(av[j][0], ((const float*)&b0)[i], acc[j][i]);
                    acc[j][i] = fmaf(av[j][1], ((const float*)&b1)[i], acc[j][i]);
                    acc[j][i] = fmaf(av[j][2], ((const float*)&b2)[i], acc[j][i]);
                    acc[j][i] = fmaf(av[j][3], ((const float*)&b3)[i], acc[j][i]);
                }
            }
        }
        float m[4];
#pragma unroll
        for (int i = 0; i < 4; ++i) {
            float v = 0.f;
            if (kg < 15) {
#pragma unroll
                for (int j = 0; j < 4; ++j) v = fmaxf(v, fmaxf(acc[j][i], 0.f));
            }
            m[i] = v;
        }
#pragma unroll
        for (int i = 0; i < 4; ++i) {
            m[i] = fmaxf(m[i], __shfl_xor(m[i], 16, 64));
            m[i] = fmaxf(m[i], __shfl_xor(m[i], 32, 64));
        }
        if ((tid & 63) < 16) {
#pragma unroll
            for (int i = 0; i < 4; ++i) redm[wv][4 * og + i] = m[i];
        }
    }
    __syncthreads();
    if (tid < 64)
        out[(size_t)node * 64 + tid] =
            fmaxf(fmaxf(redm[0][tid], redm[1][tid]), fmaxf(redm[2][tid], redm[3][tid]));
}

// ---------------- concat [x1 | y | z] -> s1 (N x 192) ----------------
__global__ void k_concat(const float* __restrict__ x1, const float* __restrict__ yv,
                         const float* __restrict__ zv, float* __restrict__ s1)
{
    int gid = blockIdx.x * 256 + threadIdx.x;
    if (gid >= N_PTS * 192) return;
    int n = gid / 192, c = gid % 192;
    float v = (c < 64) ? x1[n * 64 + c]
            : (c < 128) ? yv[n * 64 + (c - 64)]
                        : zv[n * 64 + (c - 128)];
    s1[gid] = v;
}

// ---------------- generic FC: out = relu(in @ W + b), NB rows per block ----------------
template <int IN_DIM, int OUT_DIM, int NB, int THREADS>
__global__ __launch_bounds__(THREADS) void k_fc(
    const float* __restrict__ in, const float* __restrict__ W,
    const float* __restrict__ bias, float* __restrict__ out)
{
    __shared__ float s_in[NB][IN_DIM];
    constexpr int OCHUNKS = OUT_DIM / THREADS;
    int tid = threadIdx.x;
    int nblk = blockIdx.x / OCHUNKS;
    int ochunk = blockIdx.x % OCHUNKS;
    int n0 = nblk * NB;
    for (int t = tid; t < NB * IN_DIM; t += THREADS) {
        int r = t / IN_DIM, c = t % IN_DIM;
        s_in[r][c] = in[(size_t)(n0 + r) * IN_DIM + c];
    }
    __syncthreads();
    int o = ochunk * THREADS + tid;
    float acc[NB];
#pragma unroll
    for (int r = 0; r < NB; ++r) acc[r] = 0.f;
    for (int k = 0; k < IN_DIM; ++k) {
        float w = W[(size_t)k * OUT_DIM + o];
#pragma unroll
        for (int r = 0; r < NB; ++r) acc[r] = fmaf(s_in[r][k], w, acc[r]);
    }
    float b = bias[o];
#pragma unroll
    for (int r = 0; r < NB; ++r)
        out[(size_t)(n0 + r) * OUT_DIM + o] = fmaxf(acc[r] + b, 0.f);
}

// ---------------- FC2: dual-input (s1:192 | a:1024) @ wf2(1216x256) ----------------
__global__ __launch_bounds__(256) void k_fc2(
    const float* __restrict__ s1, const float* __restrict__ av,
    const float* __restrict__ W, const float* __restrict__ bias,
    float* __restrict__ out)
{
    __shared__ float s_in[8][1216];
    int tid = threadIdx.x;
    int n0 = blockIdx.x * 8;
    for (int t = tid; t < 8 * 192; t += 256) {
        int r = t / 192, c = t % 192;
        s_in[r][c] = s1[(size_t)(n0 + r) * 192 + c];
    }
    for (int t = tid; t < 8 * 1024; t += 256) {
        int r = t / 1024, c = t % 1024;
        s_in[r][192 + c] = av[(size_t)(n0 + r) * 1024 + c];
    }
    __syncthreads();
    float acc[8];
#pragma unroll
    for (int r = 0; r < 8; ++r) acc[r] = 0.f;
    for (int k = 0; k < 1216; ++k) {
        float w = W[(size_t)k * 256 + tid];
#pragma unroll
        for (int r = 0; r < 8; ++r) acc[r] = fmaf(s_in[r][k], w, acc[r]);
    }
    float b = bias[tid];
#pragma unroll
    for (int r = 0; r < 8; ++r)
        out[(size_t)(n0 + r) * 256 + tid] = fmaxf(acc[r] + b, 0.f);
}

// ---------------- FC5 + sigmoid + BCE partial sums ----------------
__global__ __launch_bounds__(256) void k_fc5(
    const float* __restrict__ in, const float* __restrict__ w5,
    const float* __restrict__ b5, const float* __restrict__ labels,
    float* __restrict__ out, float* __restrict__ lsum)
{
    __shared__ float red[4];
    int tid = threadIdx.x;
    int lane = tid & 63;
    int wv = tid >> 6;
    int n = blockIdx.x * 4 + wv;
    float part = 0.f;
    if (n < N_PTS) {
        const float* r = in + (size_t)n * 128;
        float d = r[lane] * w5[lane] + r[64 + lane] * w5[64 + lane];
        for (int off = 32; off > 0; off >>= 1) d += __shfl_down(d, off, 64);
        if (lane == 0) {
            float v = d + b5[0];
            float s = 1.f / (1.f + expf(-v));
            out[1 + n] = s;
            float p = fminf(fmaxf(s, 1e-7f), 1.f - 1e-7f);
            float lab = labels[n];
            part = lab * logf(p) + (1.f - lab) * logf(1.f - p);
        }
    }
    if (lane == 0) red[wv] = part;
    __syncthreads();
    if (tid == 0) atomicAdd(lsum, red[0] + red[1] + red[2] + red[3]);
}

__global__ void k_final(const float* __restrict__ lsum, float* __restrict__ out)
{
    out[0] = -lsum[0] / (float)N_PTS;
}

// ---------------- launch ----------------
extern "C" void kernel_launch(void* const* d_in, const int* in_sizes, int n_in,
                              void* d_out, int out_size, void* d_ws, size_t ws_size,
                              hipStream_t stream)
{
    const float* x   = (const float*)d_in[0];
    const int*   ei  = (const int*)d_in[1];
    const float* lab = (const float*)d_in[2];
    const float* w1a = (const float*)d_in[3];  const float* b1a = (const float*)d_in[4];
    const float* w1b = (const float*)d_in[5];  const float* b1b = (const float*)d_in[6];
    const float* w2a = (const float*)d_in[7];  const float* b2a = (const float*)d_in[8];
    const float* w2b = (const float*)d_in[9];  const float* b2b = (const float*)d_in[10];
    const float* w3  = (const float*)d_in[11]; const float* b3  = (const float*)d_in[12];
    const float* wf1 = (const float*)d_in[13]; const float* bf1 = (const float*)d_in[14];
    const float* wf2 = (const float*)d_in[15]; const float* bf2 = (const float*)d_in[16];
    const float* wf3 = (const float*)d_in[17]; const float* bf3 = (const float*)d_in[18];
    const float* wf4 = (const float*)d_in[19]; const float* bf4 = (const float*)d_in[20];
    const float* wf5 = (const float*)d_in[21]; const float* bf5 = (const float*)d_in[22];
    float* out = (float*)d_out;

    char* wsp = (char*)d_ws;
    size_t off = 0;
    auto alloc = [&](size_t bytes) -> void* {
        void* p = wsp + off;
        off += (bytes + 255) & ~(size_t)255;
        return p;
    };
    // persistent buffers
    float* x1    = (float*)alloc((size_t)N_PTS * 64 * 4);
    float* yv    = (float*)alloc((size_t)N_PTS * 64 * 4);
    float* zv    = (float*)alloc((size_t)N_PTS * 64 * 4);
    int*   nbr   = (int*)  alloc((size_t)N_PTS * KNB * 4);
    float* lsum  = (float*)alloc(256);
    // overlapped region: {featT, Dm} during KNN ; {s1, av, c1, c2, c3} during MLP head
    size_t regionA = off;
    float* featT = (float*)alloc((size_t)64 * N_PTS * 4);            // 2.56 MB
    float* Dm    = (float*)alloc((size_t)CHUNK * N_PTS * 4);         // 40 MB
    off = regionA;                                                   // rewind: alias
    float* s1    = (float*)alloc((size_t)N_PTS * 192 * 4);
    float* av    = (float*)alloc((size_t)N_PTS * 1024 * 4);
    float* c1    = (float*)alloc((size_t)N_PTS * 256 * 4);
    float* c2    = (float*)alloc((size_t)N_PTS * 256 * 4);
    float* c3    = (float*)alloc((size_t)N_PTS * 128 * 4);

    hipMemsetAsync(x1, 0, (size_t)N_PTS * 64 * 4, stream);
    hipMemsetAsync(lsum, 0, 4, stream);

    k_edge1<<<N_EDGES / 256, 256, 0, stream>>>(x, ei, w1a, b1a, w1b, b1b, x1);

    // KNN 1 on x1 (chunked distance matrix + register radix select)
    k_transpose<<<157, 256, 0, stream>>>(x1, featT);
    for (int c = 0; c < N_PTS / CHUNK; ++c) {
        k_dist<<<(CHUNK / QT) * JSPLIT, 256, 0, stream>>>(x1, featT, Dm, c * CHUNK);
        k_select<<<CHUNK, 256, 0, stream>>>(Dm, nbr, c * CHUNK);
    }
    k_conv2<<<N_PTS, 256, 0, stream>>>(x1, nbr, w2a, b2a, w2b, b2b, yv);

    // KNN 2 on yv
    k_transpose<<<157, 256, 0, stream>>>(yv, featT);
    for (int c = 0; c < N_PTS / CHUNK; ++c) {
        k_dist<<<(CHUNK / QT) * JSPLIT, 256, 0, stream>>>(yv, featT, Dm, c * CHUNK);
        k_select<<<CHUNK, 256, 0, stream>>>(Dm, nbr, c * CHUNK);
    }
    k_conv3<<<N_PTS, 256, 0, stream>>>(yv, nbr, w3, b3, zv);

    k_concat<<<(N_PTS * 192 + 255) / 256, 256, 0, stream>>>(x1, yv, zv, s1);
    k_fc<192, 1024, 8, 256><<<(N_PTS / 8) * (1024 / 256), 256, 0, stream>>>(s1, wf1, bf1, av);
    k_fc2<<<N_PTS / 8, 256, 0, stream>>>(s1, av, wf2, bf2, c1);
    k_fc<256, 256, 8, 256><<<N_PTS / 8, 256, 0, stream>>>(c1, wf3, bf3, c2);
    k_fc<256, 128, 8, 128><<<N_PTS / 8, 128, 0, stream>>>(c2, wf4, bf4, c3);
    k_fc5<<<(N_PTS + 3) / 4, 256, 0, stream>>>(c3, wf5, bf5, lab, out, lsum);
    k_final<<<1, 1, 0, stream>>>(lsum, out);
}

// Round 8
// 2723.125 us; speedup vs baseline: 3.4883x; 1.1708x over previous
//
#include <hip/hip_runtime.h>
#include <math.h>

#define N_PTS 10000
#define KNB 60
#define N_EDGES 160000
#define QT 20              // queries per k_dist tile
#define NG 2500            // point-groups of 4 (10000/4)
#define CHUNK 1000         // query rows per D-chunk (40 MB)
#define JSPLIT 5           // point-axis split in k_dist (NG/JSPLIT = 500)
#define PAD 68             // df/h row stride: 272B rows -> 16B aligned, bank-spread

static __device__ __forceinline__ float finf() { return __int_as_float(0x7f800000); }

// ---------------- Stage 1: warp-per-edge MLP2 + coalesced segment_max atomics ----------
// Lane o owns output channel o. Same d-ascending / k-ascending fmaf chains as the
// verified round-1 kernel -> bit-identical m -> identical x1.
__global__ __launch_bounds__(256) void k_edge1(
    const float* __restrict__ x, const int* __restrict__ ei,
    const float* __restrict__ w1a, const float* __restrict__ b1a,
    const float* __restrict__ w1b, const float* __restrict__ b1b,
    float* __restrict__ x1)
{
    __shared__ float sw1a[32 * 64];    // 8KB
    __shared__ float sw1b[64 * 64];    // 16KB
    __shared__ float sb1a[64], sb1b[64];
    __shared__ float hbuf[4][64];
    int tid = threadIdx.x;
    for (int t = tid; t < 32 * 64; t += 256) sw1a[t] = w1a[t];
    for (int t = tid; t < 64 * 64; t += 256) sw1b[t] = w1b[t];
    if (tid < 64) { sb1a[tid] = b1a[tid]; sb1b[tid] = b1b[tid]; }
    __syncthreads();

    int lane = tid & 63;
    int wv = tid >> 6;
    int e0 = blockIdx.x * 256 + wv * 64;

    for (int it = 0; it < 64; ++it) {
        int e = e0 + it;
        int src = ei[e];
        int dst = ei[N_EDGES + e];
        const float4* xi4 = (const float4*)(x + (size_t)dst * 16);
        const float4* xj4 = (const float4*)(x + (size_t)src * 16);
        float f[32];
#pragma unroll
        for (int q = 0; q < 4; ++q) {
            float4 a = xi4[q];              // broadcast loads (uniform addr per wave)
            float4 b = xj4[q];
            f[4 * q + 0] = a.x; f[4 * q + 1] = a.y;
            f[4 * q + 2] = a.z; f[4 * q + 3] = a.w;
            f[16 + 4 * q + 0] = b.x - a.x; f[16 + 4 * q + 1] = b.y - a.y;
            f[16 + 4 * q + 2] = b.z - a.z; f[16 + 4 * q + 3] = b.w - a.w;
        }
        float h = sb1a[lane];
#pragma unroll
        for (int d = 0; d < 32; ++d) h = fmaf(f[d], sw1a[d * 64 + lane], h);
        h = fmaxf(h, 0.f);
        hbuf[wv][lane] = h;                 // wave-synchronous LDS exchange
        float m = sb1b[lane];
#pragma unroll 8
        for (int k = 0; k < 64; ++k) m = fmaf(hbuf[wv][k], sw1b[k * 64 + lane], m);
        m = fmaxf(m, 0.f);
        // 64 lanes hit one contiguous 256B row -> coalesced RMW (valid: m >= 0)
        atomicMax((int*)&x1[(size_t)dst * 64 + lane], __float_as_int(m));
    }
}

// ---------------- transpose feat[10000][64] -> featT[64][10000] ----------------
__global__ __launch_bounds__(256) void k_transpose(const float* __restrict__ feat,
                                                   float* __restrict__ featT)
{
    __shared__ float tile[64][65];
    int tid = threadIdx.x;
    int jb = blockIdx.x * 64;
    for (int t = tid; t < 64 * 64; t += 256) {
        int j = t >> 6, d = t & 63;
        if (jb + j < N_PTS) tile[j][d] = feat[(size_t)(jb + j) * 64 + d];
    }
    __syncthreads();
    for (int t = tid; t < 64 * 64; t += 256) {
        int d = t >> 6, j = t & 63;
        if (jb + j < N_PTS) featT[(size_t)d * N_PTS + jb + j] = tile[j][d];
    }
}

// ---------------- distance chunk: rows [row0, row0+CHUNK), QT queries x 500 groups/block ----
// Per-pair fmaf chain is dims-ascending (single accumulator) == verified round-1/3 chain.
__global__ __launch_bounds__(256) void k_dist(const float* __restrict__ feat,
                                              const float* __restrict__ featT,
                                              float* __restrict__ D, int row0)
{
    __shared__ float qtile[QT][64];
    int tid = threadIdx.x;
    int qi = blockIdx.x / JSPLIT;
    int js = blockIdx.x % JSPLIT;
    int qb = row0 + qi * QT;
    for (int t = tid; t < QT * 64; t += 256) {
        int q = t >> 6, d = t & 63;
        qtile[q][d] = feat[(size_t)(qb + q) * 64 + d];
    }
    __syncthreads();

    const float4* fT4 = (const float4*)featT;       // [64][NG] float4s
    const float4* qt4 = (const float4*)qtile;       // [QT][16]
    int g0 = js * (NG / JSPLIT);
    int g1 = g0 + (NG / JSPLIT);

    for (int g = g0 + tid; g < g1; g += 256) {
        float acc[QT][4];
#pragma unroll
        for (int q = 0; q < QT; ++q) {
            acc[q][0] = 0.f; acc[q][1] = 0.f; acc[q][2] = 0.f; acc[q][3] = 0.f;
        }
        for (int dc = 0; dc < 16; ++dc) {
            float4 p0 = fT4[(size_t)(4 * dc + 0) * NG + g];
            float4 p1 = fT4[(size_t)(4 * dc + 1) * NG + g];
            float4 p2 = fT4[(size_t)(4 * dc + 2) * NG + g];
            float4 p3 = fT4[(size_t)(4 * dc + 3) * NG + g];
#pragma unroll
            for (int q = 0; q < QT; ++q) {
                float4 xq = qt4[q * 16 + dc];       // LDS broadcast
                float dx;
                dx = xq.x - p0.x; acc[q][0] = fmaf(dx, dx, acc[q][0]);
                dx = xq.y - p1.x; acc[q][0] = fmaf(dx, dx, acc[q][0]);
                dx = xq.z - p2.x; acc[q][0] = fmaf(dx, dx, acc[q][0]);
                dx = xq.w - p3.x; acc[q][0] = fmaf(dx, dx, acc[q][0]);
                dx = xq.x - p0.y; acc[q][1] = fmaf(dx, dx, acc[q][1]);
                dx = xq.y - p1.y; acc[q][1] = fmaf(dx, dx, acc[q][1]);
                dx = xq.z - p2.y; acc[q][1] = fmaf(dx, dx, acc[q][1]);
                dx = xq.w - p3.y; acc[q][1] = fmaf(dx, dx, acc[q][1]);
                dx = xq.x - p0.z; acc[q][2] = fmaf(dx, dx, acc[q][2]);
                dx = xq.y - p1.z; acc[q][2] = fmaf(dx, dx, acc[q][2]);
                dx = xq.z - p2.z; acc[q][2] = fmaf(dx, dx, acc[q][2]);
                dx = xq.w - p3.z; acc[q][2] = fmaf(dx, dx, acc[q][2]);
                dx = xq.x - p0.w; acc[q][3] = fmaf(dx, dx, acc[q][3]);
                dx = xq.y - p1.w; acc[q][3] = fmaf(dx, dx, acc[q][3]);
                dx = xq.z - p2.w; acc[q][3] = fmaf(dx, dx, acc[q][3]);
                dx = xq.w - p3.w; acc[q][3] = fmaf(dx, dx, acc[q][3]);
            }
        }
#pragma unroll
        for (int q = 0; q < QT; ++q) {
            float4 v = make_float4(acc[q][0], acc[q][1], acc[q][2], acc[q][3]);
            ((float4*)(D + (size_t)(qb + q - row0) * N_PTS))[g] = v;
        }
    }
}

// ---------------- radix select (2-level, keys in registers) ----------------
static __device__ __forceinline__ void radix_find(
    unsigned* hist, unsigned* csum, unsigned need, int tid,
    volatile unsigned* outB, volatile unsigned* outCB)
{
    int base = tid * 8;
    unsigned my = 0;
#pragma unroll
    for (int b = 0; b < 8; ++b) my += hist[base + b];
    csum[tid] = my;
    __syncthreads();
    for (int off = 1; off < 256; off <<= 1) {
        unsigned add = (tid >= off) ? csum[tid - off] : 0u;
        __syncthreads();
        csum[tid] += add;
        __syncthreads();
    }
    unsigned incl = csum[tid];
    unsigned excl = incl - my;
    if (excl < need && incl >= need) {   // exactly one thread
        unsigned run = excl;
#pragma unroll
        for (int b = 0; b < 8; ++b) {
            unsigned h = hist[base + b];
            if (run + h >= need) { *outB = base + b; *outCB = run; break; }
            run += h;
        }
    }
    __syncthreads();
}

__global__ __launch_bounds__(256) void k_select(const float* __restrict__ D,
                                                int* __restrict__ nbr, int row0)
{
    __shared__ unsigned hist[2048];
    __shared__ unsigned csum[256];
    __shared__ unsigned cand_key[512];
    __shared__ int      cand_idx[512];
    __shared__ unsigned sB1, sCB1, sB2, sCB2, s_cnt, s_slot;

    int i = row0 + blockIdx.x;
    int tid = threadIdx.x;
    if (tid == 0) { s_cnt = 0; s_slot = 0; }

    // load row into registers: 10 float4 groups per thread, g = tid + 256*r
    unsigned kv[10][4];
    const float4* row4 = (const float4*)(D + (size_t)blockIdx.x * N_PTS);
#pragma unroll
    for (int r = 0; r < 10; ++r) {
        int g = tid + 256 * r;
        if (g < NG) {
            float4 v = row4[g];
            kv[r][0] = __float_as_uint(v.x);
            kv[r][1] = __float_as_uint(v.y);
            kv[r][2] = __float_as_uint(v.z);
            kv[r][3] = __float_as_uint(v.w);
            if (g == (i >> 2)) kv[r][i & 3] = 0x7f800000u;   // diagonal -> +inf
        } else {
            kv[r][0] = kv[r][1] = kv[r][2] = kv[r][3] = 0x7fffffffu;  // OOB sentinel
        }
    }

    for (int b = tid; b < 2048; b += 256) hist[b] = 0;
    __syncthreads();
#pragma unroll
    for (int r = 0; r < 10; ++r)
#pragma unroll
        for (int c = 0; c < 4; ++c) atomicAdd(&hist[kv[r][c] >> 20], 1u);
    __syncthreads();
    radix_find(hist, csum, KNB, tid, &sB1, &sCB1);
    unsigned B1 = sB1;
    unsigned need2 = KNB - sCB1;

    for (int b = tid; b < 2048; b += 256) hist[b] = 0;
    __syncthreads();
#pragma unroll
    for (int r = 0; r < 10; ++r)
#pragma unroll
        for (int c = 0; c < 4; ++c) {
            unsigned k = kv[r][c];
            if ((k >> 20) == B1) atomicAdd(&hist[(k >> 9) & 2047u], 1u);
        }
    __syncthreads();
    radix_find(hist, csum, need2, tid, &sB2, &sCB2);
    unsigned B2 = sB2;

#pragma unroll
    for (int r = 0; r < 10; ++r)
#pragma unroll
        for (int c = 0; c < 4; ++c) {
            unsigned k = kv[r][c];
            unsigned b1 = k >> 20;
            int j = 4 * (tid + 256 * r) + c;
            if (b1 < B1) {
                unsigned slot = atomicAdd(&s_slot, 1u);
                nbr[(size_t)i * KNB + slot] = j;
            } else if (b1 == B1) {
                unsigned b2 = (k >> 9) & 2047u;
                if (b2 < B2) {
                    unsigned slot = atomicAdd(&s_slot, 1u);
                    nbr[(size_t)i * KNB + slot] = j;
                } else if (b2 == B2) {
                    unsigned cc = atomicAdd(&s_cnt, 1u);
                    if (cc < 512) { cand_key[cc] = k; cand_idx[cc] = j; }
                }
            }
        }
    __syncthreads();

    if (tid == 0) {
        int definite = (int)s_slot;
        int needf = KNB - definite;
        int cnt = (int)(s_cnt < 512u ? s_cnt : 512u);
        for (int t = 0; t < needf; ++t) {
            unsigned bk = 0xFFFFFFFFu;
            int bi = 0x7FFFFFFF, bp = -1;
            for (int c = 0; c < cnt; ++c) {
                unsigned k = cand_key[c];
                int id = cand_idx[c];
                if (k < bk || (k == bk && id < bi)) { bk = k; bi = id; bp = c; }
            }
            cand_key[bp] = 0xFFFFFFFFu;
            nbr[(size_t)i * KNB + definite + t] = bi;
        }
    }
}

// ---------------- Stage 2: EdgeConv MLP2 + max over K, register-tiled ----------------
// Thread (kg,og): kg=t>>4 handles k=4kg..4kg+3 (kg==15 masked), og=t&15 handles o=4og..4og+3.
// Per-output fmaf chains are d-ascending with identical init -> bit-identical to round-1.
__global__ __launch_bounds__(256) void k_conv2(
    const float* __restrict__ feat, const int* __restrict__ nbr,
    const float* __restrict__ w2a, const float* __restrict__ b2a,
    const float* __restrict__ w2b, const float* __restrict__ b2b,
    float* __restrict__ out)
{
    __shared__ float wbuf[64 * 64];    // 16KB: phase1 w2a[0:64], phase2 w2a[64:128], phase3 w2b
    __shared__ float df[64][PAD];      // 17KB (rows 60..63 zeroed)
    __shared__ float h[64][PAD];       // 17KB
    __shared__ float xi_s[64], hx[64], sba[64], sbb[64];
    __shared__ int   nbr_s[KNB];
    __shared__ float redm[4][64];      // per-wave partial max
    int tid = threadIdx.x;
    int node = blockIdx.x;
    int og = tid & 15, kg = tid >> 4;
    int wv = tid >> 6;

    // P1: stage w2a rows 0..63 + vectors
    for (int t = tid; t < 4096; t += 256) wbuf[t] = w2a[t];
    if (tid < 64) {
        sba[tid] = b2a[tid]; sbb[tid] = b2b[tid];
        xi_s[tid] = feat[(size_t)node * 64 + tid];
    }
    if (tid < KNB) nbr_s[tid] = nbr[(size_t)node * KNB + tid];
    __syncthreads();

    // P2: hx (exact 64-chain per o, threads 0..63) + gather df + zero pad rows
    for (int t = tid; t < KNB * 64; t += 256) {
        int k = t >> 6, d = t & 63;
        df[k][d] = feat[(size_t)nbr_s[k] * 64 + d] - xi_s[d];
    }
    if (tid < 4 * 64) df[60 + (tid >> 6)][tid & 63] = 0.f;
    if (tid < 64) {
        float acc = sba[tid];
        for (int d = 0; d < 64; ++d) acc = fmaf(xi_s[d], wbuf[d * 64 + tid], acc);
        hx[tid] = acc;
    }
    __syncthreads();

    // P3: stage w2a rows 64..127
    for (int t = tid; t < 4096; t += 256) wbuf[t] = w2a[4096 + t];
    __syncthreads();

    // P4: layer 1, 4k x 4o register tile
    {
        int k0 = 4 * kg;
        float acc[4][4];
#pragma unroll
        for (int j = 0; j < 4; ++j)
#pragma unroll
            for (int i = 0; i < 4; ++i) acc[j][i] = hx[4 * og + i];
        for (int d = 0; d < 64; d += 4) {
            float4 a0 = *(const float4*)&df[k0 + 0][d];
            float4 a1 = *(const float4*)&df[k0 + 1][d];
            float4 a2 = *(const float4*)&df[k0 + 2][d];
            float4 a3 = *(const float4*)&df[k0 + 3][d];
            float4 b0 = *(const float4*)&wbuf[(d + 0) * 64 + 4 * og];
            float4 b1 = *(const float4*)&wbuf[(d + 1) * 64 + 4 * og];
            float4 b2 = *(const float4*)&wbuf[(d + 2) * 64 + 4 * og];
            float4 b3 = *(const float4*)&wbuf[(d + 3) * 64 + 4 * og];
            const float* av[4] = {(const float*)&a0, (const float*)&a1,
                                  (const float*)&a2, (const float*)&a3};
#pragma unroll
            for (int j = 0; j < 4; ++j) {
#pragma unroll
                for (int i = 0; i < 4; ++i) {
                    acc[j][i] = fmaf(av[j][0], ((const float*)&b0)[i], acc[j][i]);
                    acc[j][i] = fmaf(av[j][1], ((const float*)&b1)[i], acc[j][i]);
                    acc[j][i] = fmaf(av[j][2], ((const float*)&b2)[i], acc[j][i]);
                    acc[j][i] = fmaf(av[j][3], ((const float*)&b3)[i], acc[j][i]);
                }
            }
        }
#pragma unroll
        for (int j = 0; j < 4; ++j) {
            float4 hv;
            hv.x = fmaxf(acc[j][0], 0.f); hv.y = fmaxf(acc[j][1], 0.f);
            hv.z = fmaxf(acc[j][2], 0.f); hv.w = fmaxf(acc[j][3], 0.f);
            *(float4*)&h[k0 + j][4 * og] = hv;
        }
    }
    __syncthreads();

    // P5: stage w2b
    for (int t = tid; t < 4096; t += 256) wbuf[t] = w2b[t];
    __syncthreads();

    // P6: layer 2 + max over k
    {
        int k0 = 4 * kg;
        float acc[4][4];
#pragma unroll
        for (int j = 0; j < 4; ++j)
#pragma unroll
            for (int i = 0; i < 4; ++i) acc[j][i] = sbb[4 * og + i];
        for (int d = 0; d < 64; d += 4) {
            float4 a0 = *(const float4*)&h[k0 + 0][d];
            float4 a1 = *(const float4*)&h[k0 + 1][d];
            float4 a2 = *(const float4*)&h[k0 + 2][d];
            float4 a3 = *(const float4*)&h[k0 + 3][d];
            float4 b0 = *(const float4*)&wbuf[(d + 0) * 64 + 4 * og];
            float4 b1 = *(const float4*)&wbuf[(d + 1) * 64 + 4 * og];
            float4 b2 = *(const float4*)&wbuf[(d + 2) * 64 + 4 * og];
            float4 b3 = *(const float4*)&wbuf[(d + 3) * 64 + 4 * og];
            const float* av[4] = {(const float*)&a0, (const float*)&a1,
                                  (const float*)&a2, (const float*)&a3};
#pragma unroll
            for (int j = 0; j < 4; ++j) {
#pragma unroll
                for (int i = 0; i < 4; ++i) {
                    acc[j][i] = fmaf(av[j][0], ((const float*)&b0)[i], acc[j][i]);
                    acc[j][i] = fmaf(av[j][1], ((const float*)&b1)[i], acc[j][i]);
                    acc[j][i] = fmaf(av[j][2], ((const float*)&b2)[i], acc[j][i]);
                    acc[j][i] = fmaf(av[j][3], ((const float*)&b3)[i], acc[j][i]);
                }
            }
        }
        float m[4];
#pragma unroll
        for (int i = 0; i < 4; ++i) {
            float v = 0.f;   // all true outputs are >= 0 (relu), so 0 is identity
            if (kg < 15) {
#pragma unroll
                for (int j = 0; j < 4; ++j) v = fmaxf(v, fmaxf(acc[j][i], 0.f));
            }
            m[i] = v;
        }
        // reduce max across the wave's 4 kg-subgroups (lanes ^16, ^32)
#pragma unroll
        for (int i = 0; i < 4; ++i) {
            m[i] = fmaxf(m[i], __shfl_xor(m[i], 16, 64));
            m[i] = fmaxf(m[i], __shfl_xor(m[i], 32, 64));
        }
        if ((tid & 63) < 16) {
#pragma unroll
            for (int i = 0; i < 4; ++i) redm[wv][4 * og + i] = m[i];
        }
    }
    __syncthreads();
    if (tid < 64)
        out[(size_t)node * 64 + tid] =
            fmaxf(fmaxf(redm[0][tid], redm[1][tid]), fmaxf(redm[2][tid], redm[3][tid]));
}

// ---------------- Stage 3: single-layer EdgeConv + max over K, register-tiled ----------------
__global__ __launch_bounds__(256) void k_conv3(
    const float* __restrict__ feat, const int* __restrict__ nbr,
    const float* __restrict__ w3, const float* __restrict__ b3,
    float* __restrict__ out)
{
    __shared__ float wbuf[64 * 64];    // 16KB: phase1 w3[0:64], phase2 w3[64:128]
    __shared__ float df[64][PAD];      // 17KB
    __shared__ float xi_s[64], hx[64], sb[64];
    __shared__ int   nbr_s[KNB];
    __shared__ float redm[4][64];
    int tid = threadIdx.x;
    int node = blockIdx.x;
    int og = tid & 15, kg = tid >> 4;
    int wv = tid >> 6;

    for (int t = tid; t < 4096; t += 256) wbuf[t] = w3[t];
    if (tid < 64) { sb[tid] = b3[tid]; xi_s[tid] = feat[(size_t)node * 64 + tid]; }
    if (tid < KNB) nbr_s[tid] = nbr[(size_t)node * KNB + tid];
    __syncthreads();

    for (int t = tid; t < KNB * 64; t += 256) {
        int k = t >> 6, d = t & 63;
        df[k][d] = feat[(size_t)nbr_s[k] * 64 + d] - xi_s[d];
    }
    if (tid < 4 * 64) df[60 + (tid >> 6)][tid & 63] = 0.f;
    if (tid < 64) {
        float acc = sb[tid];
        for (int d = 0; d < 64; ++d) acc = fmaf(xi_s[d], wbuf[d * 64 + tid], acc);
        hx[tid] = acc;
    }
    __syncthreads();

    for (int t = tid; t < 4096; t += 256) wbuf[t] = w3[4096 + t];
    __syncthreads();

    {
        int k0 = 4 * kg;
        float acc[4][4];
#pragma unroll
        for (int j = 0; j < 4; ++j)
#pragma unroll
            for (int i = 0; i < 4; ++i) acc[j][i] = hx[4 * og + i];
        for (int d = 0; d < 64; d += 4) {
            float4 a0 = *(const float4*)&df[k0 + 0][d];
            float4 a1 = *(const float4*)&df[k0 + 1][d];
            float4 a2 = *(const float4*)&df[k0 + 2][d];
            float4 a3 = *(const float4*)&df[k0 + 3][d];
            float4 b0 = *(const float4*)&wbuf[(d + 0) * 64 + 4 * og];
            float4 b1 = *(const float4*)&wbuf[(d + 1) * 64 + 4 * og];
            float4 b2 = *(const float4*)&wbuf[(d + 2) * 64 + 4 * og];
            float4 b3 = *(const float4*)&wbuf[(d + 3) * 64 + 4 * og];
            const float* av[4] = {(const float*)&a0, (const float*)&a1,
                                  (const float*)&a2, (const float*)&a3};
#pragma unroll
            for (int j = 0; j < 4; ++j) {
#pragma unroll
                for (int i = 0; i < 4; ++i) {
                    acc[j][i] = fmaf(av[j][0], ((const float*)&b0)[i], acc[j][i]);
                    acc[j][i] = fmaf(av[j][1], ((const float*)&b1)[i], acc[j][i]);
                    acc[j][i] = fmaf(av[j][2], ((const float*)&b2)[i], acc[j][i]);
                    acc[j][i] = fmaf(av[j][3], ((const float*)&b3)[i], acc[j][i]);
                }
            }
        }
        float m[4];
#pragma unroll
        for (int i = 0; i < 4; ++i) {
            float v = 0.f;
            if (kg < 15) {
#pragma unroll
                for (int j = 0; j < 4; ++j) v = fmaxf(v, fmaxf(acc[j][i], 0.f));
            }
            m[i] = v;
        }
#pragma unroll
        for (int i = 0; i < 4; ++i) {
            m[i] = fmaxf(m[i], __shfl_xor(m[i], 16, 64));
            m[i] = fmaxf(m[i], __shfl_xor(m[i], 32, 64));
        }
        if ((tid & 63) < 16) {
#pragma unroll
            for (int i = 0; i < 4; ++i) redm[wv][4 * og + i] = m[i];
        }
    }
    __syncthreads();
    if (tid < 64)
        out[(size_t)node * 64 + tid] =
            fmaxf(fmaxf(redm[0][tid], redm[1][tid]), fmaxf(redm[2][tid], redm[3][tid]));
}

// ---------------- concat [x1 | y | z] -> s1 (N x 192) ----------------
__global__ void k_concat(const float* __restrict__ x1, const float* __restrict__ yv,
                         const float* __restrict__ zv, float* __restrict__ s1)
{
    int gid = blockIdx.x * 256 + threadIdx.x;
    if (gid >= N_PTS * 192) return;
    int n = gid / 192, c = gid % 192;
    float v = (c < 64) ? x1[n * 64 + c]
            : (c < 128) ? yv[n * 64 + (c - 64)]
                        : zv[n * 64 + (c - 128)];
    s1[gid] = v;
}

// ---------------- generic FC: out = relu(in @ W + b), NB rows per block ----------------
template <int IN_DIM, int OUT_DIM, int NB, int THREADS>
__global__ __launch_bounds__(THREADS) void k_fc(
    const float* __restrict__ in, const float* __restrict__ W,
    const float* __restrict__ bias, float* __restrict__ out)
{
    __shared__ float s_in[NB][IN_DIM];
    constexpr int OCHUNKS = OUT_DIM / THREADS;
    int tid = threadIdx.x;
    int nblk = blockIdx.x / OCHUNKS;
    int ochunk = blockIdx.x % OCHUNKS;
    int n0 = nblk * NB;
    for (int t = tid; t < NB * IN_DIM; t += THREADS) {
        int r = t / IN_DIM, c = t % IN_DIM;
        s_in[r][c] = in[(size_t)(n0 + r) * IN_DIM + c];
    }
    __syncthreads();
    int o = ochunk * THREADS + tid;
    float acc[NB];
#pragma unroll
    for (int r = 0; r < NB; ++r) acc[r] = 0.f;
    for (int k = 0; k < IN_DIM; ++k) {
        float w = W[(size_t)k * OUT_DIM + o];
#pragma unroll
        for (int r = 0; r < NB; ++r) acc[r] = fmaf(s_in[r][k], w, acc[r]);
    }
    float b = bias[o];
#pragma unroll
    for (int r = 0; r < NB; ++r)
        out[(size_t)(n0 + r) * OUT_DIM + o] = fmaxf(acc[r] + b, 0.f);
}

// ---------------- FC2: dual-input (s1:192 | a:1024) @ wf2(1216x256) ----------------
__global__ __launch_bounds__(256) void k_fc2(
    const float* __restrict__ s1, const float* __restrict__ av,
    const float* __restrict__ W, const float* __restrict__ bias,
    float* __restrict__ out)
{
    __shared__ float s_in[8][1216];
    int tid = threadIdx.x;
    int n0 = blockIdx.x * 8;
    for (int t = tid; t < 8 * 192; t += 256) {
        int r = t / 192, c = t % 192;
        s_in[r][c] = s1[(size_t)(n0 + r) * 192 + c];
    }
    for (int t = tid; t < 8 * 1024; t += 256) {
        int r = t / 1024, c = t % 1024;
        s_in[r][192 + c] = av[(size_t)(n0 + r) * 1024 + c];
    }
    __syncthreads();
    float acc[8];
#pragma unroll
    for (int r = 0; r < 8; ++r) acc[r] = 0.f;
    for (int k = 0; k < 1216; ++k) {
        float w = W[(size_t)k * 256 + tid];
#pragma unroll
        for (int r = 0; r < 8; ++r) acc[r] = fmaf(s_in[r][k], w, acc[r]);
    }
    float b = bias[tid];
#pragma unroll
    for (int r = 0; r < 8; ++r)
        out[(size_t)(n0 + r) * 256 + tid] = fmaxf(acc[r] + b, 0.f);
}

// ---------------- FC5 + sigmoid + BCE partial sums ----------------
__global__ __launch_bounds__(256) void k_fc5(
    const float* __restrict__ in, const float* __restrict__ w5,
    const float* __restrict__ b5, const float* __restrict__ labels,
    float* __restrict__ out, float* __restrict__ lsum)
{
    __shared__ float red[4];
    int tid = threadIdx.x;
    int lane = tid & 63;
    int wv = tid >> 6;
    int n = blockIdx.x * 4 + wv;
    float part = 0.f;
    if (n < N_PTS) {
        const float* r = in + (size_t)n * 128;
        float d = r[lane] * w5[lane] + r[64 + lane] * w5[64 + lane];
        for (int off = 32; off > 0; off >>= 1) d += __shfl_down(d, off, 64);
        if (lane == 0) {
            float v = d + b5[0];
            float s = 1.f / (1.f + expf(-v));
            out[1 + n] = s;
            float p = fminf(fmaxf(s, 1e-7f), 1.f - 1e-7f);
            float lab = labels[n];
            part = lab * logf(p) + (1.f - lab) * logf(1.f - p);
        }
    }
    if (lane == 0) red[wv] = part;
    __syncthreads();
    if (tid == 0) atomicAdd(lsum, red[0] + red[1] + red[2] + red[3]);
}

__global__ void k_final(const float* __restrict__ lsum, float* __restrict__ out)
{
    out[0] = -lsum[0] / (float)N_PTS;
}

// ---------------- launch ----------------
extern "C" void kernel_launch(void* const* d_in, const int* in_sizes, int n_in,
                              void* d_out, int out_size, void* d_ws, size_t ws_size,
                              hipStream_t stream)
{
    const float* x   = (const float*)d_in[0];
    const int*   ei  = (const int*)d_in[1];
    const float* lab = (const float*)d_in[2];
    const float* w1a = (const float*)d_in[3];  const float* b1a = (const float*)d_in[4];
    const float* w1b = (const float*)d_in[5];  const float* b1b = (const float*)d_in[6];
    const float* w2a = (const float*)d_in[7];  const float* b2a = (const float*)d_in[8];
    const float* w2b = (const float*)d_in[9];  const float* b2b = (const float*)d_in[10];
    const float* w3  = (const float*)d_in[11]; const float* b3  = (const float*)d_in[12];
    const float* wf1 = (const float*)d_in[13]; const float* bf1 = (const float*)d_in[14];
    const float* wf2 = (const float*)d_in[15]; const float* bf2 = (const float*)d_in[16];
    const float* wf3 = (const float*)d_in[17]; const float* bf3 = (const float*)d_in[18];
    const float* wf4 = (const float*)d_in[19]; const float* bf4 = (const float*)d_in[20];
    const float* wf5 = (const float*)d_in[21]; const float* bf5 = (const float*)d_in[22];
    float* out = (float*)d_out;

    char* wsp = (char*)d_ws;
    size_t off = 0;
    auto alloc = [&](size_t bytes) -> void* {
        void* p = wsp + off;
        off += (bytes + 255) & ~(size_t)255;
        return p;
    };
    // persistent buffers
    float* x1    = (float*)alloc((size_t)N_PTS * 64 * 4);
    float* yv    = (float*)alloc((size_t)N_PTS * 64 * 4);
    float* zv    = (float*)alloc((size_t)N_PTS * 64 * 4);
    int*   nbr   = (int*)  alloc((size_t)N_PTS * KNB * 4);
    float* lsum  = (float*)alloc(256);
    // overlapped region: {featT, Dm} during KNN ; {s1, av, c1, c2, c3} during MLP head
    size_t regionA = off;
    float* featT = (float*)alloc((size_t)64 * N_PTS * 4);            // 2.56 MB
    float* Dm    = (float*)alloc((size_t)CHUNK * N_PTS * 4);         // 40 MB
    off = regionA;                                                   // rewind: alias
    float* s1    = (float*)alloc((size_t)N_PTS * 192 * 4);
    float* av    = (float*)alloc((size_t)N_PTS * 1024 * 4);
    float* c1    = (float*)alloc((size_t)N_PTS * 256 * 4);
    float* c2    = (float*)alloc((size_t)N_PTS * 256 * 4);
    float* c3    = (float*)alloc((size_t)N_PTS * 128 * 4);

    hipMemsetAsync(x1, 0, (size_t)N_PTS * 64 * 4, stream);
    hipMemsetAsync(lsum, 0, 4, stream);

    k_edge1<<<N_EDGES / 256, 256, 0, stream>>>(x, ei, w1a, b1a, w1b, b1b, x1);

    // KNN 1 on x1 (chunked distance matrix + register radix select)
    k_transpose<<<157, 256, 0, stream>>>(x1, featT);
    for (int c = 0; c < N_PTS / CHUNK; ++c) {
        k_dist<<<(CHUNK / QT) * JSPLIT, 256, 0, stream>>>(x1, featT, Dm, c * CHUNK);
        k_select<<<CHUNK, 256, 0, stream>>>(Dm, nbr, c * CHUNK);
    }
    k_conv2<<<N_PTS, 256, 0, stream>>>(x1, nbr, w2a, b2a, w2b, b2b, yv);

    // KNN 2 on yv
    k_transpose<<<157, 256, 0, stream>>>(yv, featT);
    for (int c = 0; c < N_PTS / CHUNK; ++c) {
        k_dist<<<(CHUNK / QT) * JSPLIT, 256, 0, stream>>>(yv, featT, Dm, c * CHUNK);
        k_select<<<CHUNK, 256, 0, stream>>>(Dm, nbr, c * CHUNK);
    }
    k_conv3<<<N_PTS, 256, 0, stream>>>(yv, nbr, w3, b3, zv);

    k_concat<<<(N_PTS * 192 + 255) / 256, 256, 0, stream>>>(x1, yv, zv, s1);
    k_fc<192, 1024, 8, 256><<<(N_PTS / 8) * (1024 / 256), 256, 0, stream>>>(s1, wf1, bf1, av);
    k_fc2<<<N_PTS / 8, 256, 0, stream>>>(s1, av, wf2, bf2, c1);
    k_fc<256, 256, 8, 256><<<N_PTS / 8, 256, 0, stream>>>(c1, wf3, bf3, c2);
    k_fc<256, 128, 8, 128><<<N_PTS / 8, 128, 0, stream>>>(c2, wf4, bf4, c3);
    k_fc5<<<(N_PTS + 3) / 4, 256, 0, stream>>>(c3, wf5, bf5, lab, out, lsum);
    k_final<<<1, 1, 0, stream>>>(lsum, out);
}

// Round 9
// 2443.715 us; speedup vs baseline: 3.8871x; 1.1143x over previous
//
#include <hip/hip_runtime.h>
#include <math.h>

#define N_PTS 10000
#define KNB 60
#define N_EDGES 160000
#define QT 10              // queries per k_dist tile (10 -> 40 acc VGPR, 1000 blocks/chunk)
#define NG 2500            // point-groups of 4 (10000/4)
#define CHUNK 1000         // query rows per D-chunk (40 MB)
#define JSPLIT 10          // point-axis split in k_dist (NG/JSPLIT = 250)
#define PAD 68             // df/h row stride: 272B rows -> 16B aligned, bank-spread

static __device__ __forceinline__ float finf() { return __int_as_float(0x7f800000); }

// ---------------- Stage 1: warp-per-edge MLP2 + coalesced segment_max atomics ----------
__global__ __launch_bounds__(256) void k_edge1(
    const float* __restrict__ x, const int* __restrict__ ei,
    const float* __restrict__ w1a, const float* __restrict__ b1a,
    const float* __restrict__ w1b, const float* __restrict__ b1b,
    float* __restrict__ x1)
{
    __shared__ float sw1a[32 * 64];    // 8KB
    __shared__ float sw1b[64 * 64];    // 16KB
    __shared__ float sb1a[64], sb1b[64];
    __shared__ float hbuf[4][64];
    int tid = threadIdx.x;
    for (int t = tid; t < 32 * 64; t += 256) sw1a[t] = w1a[t];
    for (int t = tid; t < 64 * 64; t += 256) sw1b[t] = w1b[t];
    if (tid < 64) { sb1a[tid] = b1a[tid]; sb1b[tid] = b1b[tid]; }
    __syncthreads();

    int lane = tid & 63;
    int wv = tid >> 6;
    int e0 = blockIdx.x * 256 + wv * 64;

    for (int it = 0; it < 64; ++it) {
        int e = e0 + it;
        int src = ei[e];
        int dst = ei[N_EDGES + e];
        const float4* xi4 = (const float4*)(x + (size_t)dst * 16);
        const float4* xj4 = (const float4*)(x + (size_t)src * 16);
        float f[32];
#pragma unroll
        for (int q = 0; q < 4; ++q) {
            float4 a = xi4[q];              // broadcast loads (uniform addr per wave)
            float4 b = xj4[q];
            f[4 * q + 0] = a.x; f[4 * q + 1] = a.y;
            f[4 * q + 2] = a.z; f[4 * q + 3] = a.w;
            f[16 + 4 * q + 0] = b.x - a.x; f[16 + 4 * q + 1] = b.y - a.y;
            f[16 + 4 * q + 2] = b.z - a.z; f[16 + 4 * q + 3] = b.w - a.w;
        }
        float h = sb1a[lane];
#pragma unroll
        for (int d = 0; d < 32; ++d) h = fmaf(f[d], sw1a[d * 64 + lane], h);
        h = fmaxf(h, 0.f);
        hbuf[wv][lane] = h;                 // wave-synchronous LDS exchange
        float m = sb1b[lane];
#pragma unroll 8
        for (int k = 0; k < 64; ++k) m = fmaf(hbuf[wv][k], sw1b[k * 64 + lane], m);
        m = fmaxf(m, 0.f);
        atomicMax((int*)&x1[(size_t)dst * 64 + lane], __float_as_int(m));
    }
}

// ---------------- transpose feat[10000][64] -> featT[64][10000] ----------------
__global__ __launch_bounds__(256) void k_transpose(const float* __restrict__ feat,
                                                   float* __restrict__ featT)
{
    __shared__ float tile[64][65];
    int tid = threadIdx.x;
    int jb = blockIdx.x * 64;
    for (int t = tid; t < 64 * 64; t += 256) {
        int j = t >> 6, d = t & 63;
        if (jb + j < N_PTS) tile[j][d] = feat[(size_t)(jb + j) * 64 + d];
    }
    __syncthreads();
    for (int t = tid; t < 64 * 64; t += 256) {
        int d = t >> 6, j = t & 63;
        if (jb + j < N_PTS) featT[(size_t)d * N_PTS + jb + j] = tile[j][d];
    }
}

// ---------------- distance chunk: rows [row0, row0+CHUNK), QT queries x 250 groups/block ----
// Per-pair fmaf chain is dims-ascending (single accumulator) == verified round-1/3 chain.
__global__ __launch_bounds__(256) void k_dist(const float* __restrict__ feat,
                                              const float* __restrict__ featT,
                                              float* __restrict__ D, int row0)
{
    __shared__ float qtile[QT][64];
    int tid = threadIdx.x;
    int qi = blockIdx.x / JSPLIT;
    int js = blockIdx.x % JSPLIT;
    int qb = row0 + qi * QT;
    for (int t = tid; t < QT * 64; t += 256) {
        int q = t >> 6, d = t & 63;
        qtile[q][d] = feat[(size_t)(qb + q) * 64 + d];
    }
    __syncthreads();

    const float4* fT4 = (const float4*)featT;       // [64][NG] float4s
    const float4* qt4 = (const float4*)qtile;       // [QT][16]
    int g0 = js * (NG / JSPLIT);
    int g1 = g0 + (NG / JSPLIT);

    for (int g = g0 + tid; g < g1; g += 256) {
        float acc[QT][4];
#pragma unroll
        for (int q = 0; q < QT; ++q) {
            acc[q][0] = 0.f; acc[q][1] = 0.f; acc[q][2] = 0.f; acc[q][3] = 0.f;
        }
        for (int dc = 0; dc < 16; ++dc) {
            float4 p0 = fT4[(size_t)(4 * dc + 0) * NG + g];
            float4 p1 = fT4[(size_t)(4 * dc + 1) * NG + g];
            float4 p2 = fT4[(size_t)(4 * dc + 2) * NG + g];
            float4 p3 = fT4[(size_t)(4 * dc + 3) * NG + g];
#pragma unroll
            for (int q = 0; q < QT; ++q) {
                float4 xq = qt4[q * 16 + dc];       // LDS broadcast
                float dx;
                dx = xq.x - p0.x; acc[q][0] = fmaf(dx, dx, acc[q][0]);
                dx = xq.y - p1.x; acc[q][0] = fmaf(dx, dx, acc[q][0]);
                dx = xq.z - p2.x; acc[q][0] = fmaf(dx, dx, acc[q][0]);
                dx = xq.w - p3.x; acc[q][0] = fmaf(dx, dx, acc[q][0]);
                dx = xq.x - p0.y; acc[q][1] = fmaf(dx, dx, acc[q][1]);
                dx = xq.y - p1.y; acc[q][1] = fmaf(dx, dx, acc[q][1]);
                dx = xq.z - p2.y; acc[q][1] = fmaf(dx, dx, acc[q][1]);
                dx = xq.w - p3.y; acc[q][1] = fmaf(dx, dx, acc[q][1]);
                dx = xq.x - p0.z; acc[q][2] = fmaf(dx, dx, acc[q][2]);
                dx = xq.y - p1.z; acc[q][2] = fmaf(dx, dx, acc[q][2]);
                dx = xq.z - p2.z; acc[q][2] = fmaf(dx, dx, acc[q][2]);
                dx = xq.w - p3.z; acc[q][2] = fmaf(dx, dx, acc[q][2]);
                dx = xq.x - p0.w; acc[q][3] = fmaf(dx, dx, acc[q][3]);
                dx = xq.y - p1.w; acc[q][3] = fmaf(dx, dx, acc[q][3]);
                dx = xq.z - p2.w; acc[q][3] = fmaf(dx, dx, acc[q][3]);
                dx = xq.w - p3.w; acc[q][3] = fmaf(dx, dx, acc[q][3]);
            }
        }
#pragma unroll
        for (int q = 0; q < QT; ++q) {
            float4 v = make_float4(acc[q][0], acc[q][1], acc[q][2], acc[q][3]);
            ((float4*)(D + (size_t)(qb + q - row0) * N_PTS))[g] = v;
        }
    }
}

// ---------------- radix select (2-level, keys in registers) ----------------
static __device__ __forceinline__ void radix_find(
    unsigned* hist, unsigned* csum, unsigned need, int tid,
    volatile unsigned* outB, volatile unsigned* outCB)
{
    int base = tid * 8;
    unsigned my = 0;
#pragma unroll
    for (int b = 0; b < 8; ++b) my += hist[base + b];
    csum[tid] = my;
    __syncthreads();
    for (int off = 1; off < 256; off <<= 1) {
        unsigned add = (tid >= off) ? csum[tid - off] : 0u;
        __syncthreads();
        csum[tid] += add;
        __syncthreads();
    }
    unsigned incl = csum[tid];
    unsigned excl = incl - my;
    if (excl < need && incl >= need) {   // exactly one thread
        unsigned run = excl;
#pragma unroll
        for (int b = 0; b < 8; ++b) {
            unsigned h = hist[base + b];
            if (run + h >= need) { *outB = base + b; *outCB = run; break; }
            run += h;
        }
    }
    __syncthreads();
}

__global__ __launch_bounds__(256) void k_select(const float* __restrict__ D,
                                                int* __restrict__ nbr, int row0)
{
    __shared__ unsigned hist[2048];
    __shared__ unsigned csum[256];
    __shared__ unsigned cand_key[512];
    __shared__ int      cand_idx[512];
    __shared__ unsigned sB1, sCB1, sB2, sCB2, s_cnt, s_slot;

    int i = row0 + blockIdx.x;
    int tid = threadIdx.x;
    if (tid == 0) { s_cnt = 0; s_slot = 0; }

    // load row into registers: 10 float4 groups per thread, g = tid + 256*r
    unsigned kv[10][4];
    const float4* row4 = (const float4*)(D + (size_t)blockIdx.x * N_PTS);
#pragma unroll
    for (int r = 0; r < 10; ++r) {
        int g = tid + 256 * r;
        if (g < NG) {
            float4 v = row4[g];
            kv[r][0] = __float_as_uint(v.x);
            kv[r][1] = __float_as_uint(v.y);
            kv[r][2] = __float_as_uint(v.z);
            kv[r][3] = __float_as_uint(v.w);
            if (g == (i >> 2)) kv[r][i & 3] = 0x7f800000u;   // diagonal -> +inf
        } else {
            kv[r][0] = kv[r][1] = kv[r][2] = kv[r][3] = 0x7fffffffu;  // OOB sentinel
        }
    }

    for (int b = tid; b < 2048; b += 256) hist[b] = 0;
    __syncthreads();
#pragma unroll
    for (int r = 0; r < 10; ++r)
#pragma unroll
        for (int c = 0; c < 4; ++c) atomicAdd(&hist[kv[r][c] >> 20], 1u);
    __syncthreads();
    radix_find(hist, csum, KNB, tid, &sB1, &sCB1);
    unsigned B1 = sB1;
    unsigned need2 = KNB - sCB1;

    for (int b = tid; b < 2048; b += 256) hist[b] = 0;
    __syncthreads();
#pragma unroll
    for (int r = 0; r < 10; ++r)
#pragma unroll
        for (int c = 0; c < 4; ++c) {
            unsigned k = kv[r][c];
            if ((k >> 20) == B1) atomicAdd(&hist[(k >> 9) & 2047u], 1u);
        }
    __syncthreads();
    radix_find(hist, csum, need2, tid, &sB2, &sCB2);
    unsigned B2 = sB2;

#pragma unroll
    for (int r = 0; r < 10; ++r)
#pragma unroll
        for (int c = 0; c < 4; ++c) {
            unsigned k = kv[r][c];
            unsigned b1 = k >> 20;
            int j = 4 * (tid + 256 * r) + c;
            if (b1 < B1) {
                unsigned slot = atomicAdd(&s_slot, 1u);
                nbr[(size_t)i * KNB + slot] = j;
            } else if (b1 == B1) {
                unsigned b2 = (k >> 9) & 2047u;
                if (b2 < B2) {
                    unsigned slot = atomicAdd(&s_slot, 1u);
                    nbr[(size_t)i * KNB + slot] = j;
                } else if (b2 == B2) {
                    unsigned cc = atomicAdd(&s_cnt, 1u);
                    if (cc < 512) { cand_key[cc] = k; cand_idx[cc] = j; }
                }
            }
        }
    __syncthreads();

    if (tid == 0) {
        int definite = (int)s_slot;
        int needf = KNB - definite;
        int cnt = (int)(s_cnt < 512u ? s_cnt : 512u);
        for (int t = 0; t < needf; ++t) {
            unsigned bk = 0xFFFFFFFFu;
            int bi = 0x7FFFFFFF, bp = -1;
            for (int c = 0; c < cnt; ++c) {
                unsigned k = cand_key[c];
                int id = cand_idx[c];
                if (k < bk || (k == bk && id < bi)) { bk = k; bi = id; bp = c; }
            }
            cand_key[bp] = 0xFFFFFFFFu;
            nbr[(size_t)i * KNB + definite + t] = bi;
        }
    }
}

// ---------------- Stage 2: EdgeConv MLP2 + max over K, register-tiled ----------------
__global__ __launch_bounds__(256) void k_conv2(
    const float* __restrict__ feat, const int* __restrict__ nbr,
    const float* __restrict__ w2a, const float* __restrict__ b2a,
    const float* __restrict__ w2b, const float* __restrict__ b2b,
    float* __restrict__ out)
{
    __shared__ float wbuf[64 * 64];    // 16KB: phase1 w2a[0:64], phase2 w2a[64:128], phase3 w2b
    __shared__ float df[64][PAD];      // 17KB (rows 60..63 zeroed)
    __shared__ float h[64][PAD];       // 17KB
    __shared__ float xi_s[64], hx[64], sba[64], sbb[64];
    __shared__ int   nbr_s[KNB];
    __shared__ float redm[4][64];      // per-wave partial max
    int tid = threadIdx.x;
    int node = blockIdx.x;
    int og = tid & 15, kg = tid >> 4;
    int wv = tid >> 6;

    // P1: stage w2a rows 0..63 + vectors
    for (int t = tid; t < 4096; t += 256) wbuf[t] = w2a[t];
    if (tid < 64) {
        sba[tid] = b2a[tid]; sbb[tid] = b2b[tid];
        xi_s[tid] = feat[(size_t)node * 64 + tid];
    }
    if (tid < KNB) nbr_s[tid] = nbr[(size_t)node * KNB + tid];
    __syncthreads();

    // P2: hx (exact 64-chain per o, threads 0..63) + gather df + zero pad rows
    for (int t = tid; t < KNB * 64; t += 256) {
        int k = t >> 6, d = t & 63;
        df[k][d] = feat[(size_t)nbr_s[k] * 64 + d] - xi_s[d];
    }
    if (tid < 4 * 64) df[60 + (tid >> 6)][tid & 63] = 0.f;
    if (tid < 64) {
        float acc = sba[tid];
        for (int d = 0; d < 64; ++d) acc = fmaf(xi_s[d], wbuf[d * 64 + tid], acc);
        hx[tid] = acc;
    }
    __syncthreads();

    // P3: stage w2a rows 64..127
    for (int t = tid; t < 4096; t += 256) wbuf[t] = w2a[4096 + t];
    __syncthreads();

    // P4: layer 1, 4k x 4o register tile
    {
        int k0 = 4 * kg;
        float acc[4][4];
#pragma unroll
        for (int j = 0; j < 4; ++j)
#pragma unroll
            for (int i = 0; i < 4; ++i) acc[j][i] = hx[4 * og + i];
        for (int d = 0; d < 64; d += 4) {
            float4 a0 = *(const float4*)&df[k0 + 0][d];
            float4 a1 = *(const float4*)&df[k0 + 1][d];
            float4 a2 = *(const float4*)&df[k0 + 2][d];
            float4 a3 = *(const float4*)&df[k0 + 3][d];
            float4 b0 = *(const float4*)&wbuf[(d + 0) * 64 + 4 * og];
            float4 b1 = *(const float4*)&wbuf[(d + 1) * 64 + 4 * og];
            float4 b2 = *(const float4*)&wbuf[(d + 2) * 64 + 4 * og];
            float4 b3 = *(const float4*)&wbuf[(d + 3) * 64 + 4 * og];
            const float* av[4] = {(const float*)&a0, (const float*)&a1,
                                  (const float*)&a2, (const float*)&a3};
#pragma unroll
            for (int j = 0; j < 4; ++j) {
#pragma unroll
                for (int i = 0; i < 4; ++i) {
                    acc[j][i] = fmaf(av[j][0], ((const float*)&b0)[i], acc[j][i]);
                    acc[j][i] = fmaf(av[j][1], ((const float*)&b1)[i], acc[j][i]);
                    acc[j][i] = fmaf(av[j][2], ((const float*)&b2)[i], acc[j][i]);
                    acc[j][i] = fmaf(av[j][3], ((const float*)&b3)[i], acc[j][i]);
                }
            }
        }
#pragma unroll
        for (int j = 0; j < 4; ++j) {
            float4 hv;
            hv.x = fmaxf(acc[j][0], 0.f); hv.y = fmaxf(acc[j][1], 0.f);
            hv.z = fmaxf(acc[j][2], 0.f); hv.w = fmaxf(acc[j][3], 0.f);
            *(float4*)&h[k0 + j][4 * og] = hv;
        }
    }
    __syncthreads();

    // P5: stage w2b
    for (int t = tid; t < 4096; t += 256) wbuf[t] = w2b[t];
    __syncthreads();

    // P6: layer 2 + max over k
    {
        int k0 = 4 * kg;
        float acc[4][4];
#pragma unroll
        for (int j = 0; j < 4; ++j)
#pragma unroll
            for (int i = 0; i < 4; ++i) acc[j][i] = sbb[4 * og + i];
        for (int d = 0; d < 64; d += 4) {
            float4 a0 = *(const float4*)&h[k0 + 0][d];
            float4 a1 = *(const float4*)&h[k0 + 1][d];
            float4 a2 = *(const float4*)&h[k0 + 2][d];
            float4 a3 = *(const float4*)&h[k0 + 3][d];
            float4 b0 = *(const float4*)&wbuf[(d + 0) * 64 + 4 * og];
            float4 b1 = *(const float4*)&wbuf[(d + 1) * 64 + 4 * og];
            float4 b2 = *(const float4*)&wbuf[(d + 2) * 64 + 4 * og];
            float4 b3 = *(const float4*)&wbuf[(d + 3) * 64 + 4 * og];
            const float* av[4] = {(const float*)&a0, (const float*)&a1,
                                  (const float*)&a2, (const float*)&a3};
#pragma unroll
            for (int j = 0; j < 4; ++j) {
#pragma unroll
                for (int i = 0; i < 4; ++i) {
                    acc[j][i] = fmaf(av[j][0], ((const float*)&b0)[i], acc[j][i]);
                    acc[j][i] = fmaf(av[j][1], ((const float*)&b1)[i], acc[j][i]);
                    acc[j][i] = fmaf(av[j][2], ((const float*)&b2)[i], acc[j][i]);
                    acc[j][i] = fmaf(av[j][3], ((const float*)&b3)[i], acc[j][i]);
                }
            }
        }
        float m[4];
#pragma unroll
        for (int i = 0; i < 4; ++i) {
            float v = 0.f;   // all true outputs are >= 0 (relu), so 0 is identity
            if (kg < 15) {
#pragma unroll
                for (int j = 0; j < 4; ++j) v = fmaxf(v, fmaxf(acc[j][i], 0.f));
            }
            m[i] = v;
        }
        // reduce max across the wave's 4 kg-subgroups (lanes ^16, ^32)
#pragma unroll
        for (int i = 0; i < 4; ++i) {
            m[i] = fmaxf(m[i], __shfl_xor(m[i], 16, 64));
            m[i] = fmaxf(m[i], __shfl_xor(m[i], 32, 64));
        }
        if ((tid & 63) < 16) {
#pragma unroll
            for (int i = 0; i < 4; ++i) redm[wv][4 * og + i] = m[i];
        }
    }
    __syncthreads();
    if (tid < 64)
        out[(size_t)node * 64 + tid] =
            fmaxf(fmaxf(redm[0][tid], redm[1][tid]), fmaxf(redm[2][tid], redm[3][tid]));
}

// ---------------- Stage 3: single-layer EdgeConv + max over K, register-tiled ----------------
__global__ __launch_bounds__(256) void k_conv3(
    const float* __restrict__ feat, const int* __restrict__ nbr,
    const float* __restrict__ w3, const float* __restrict__ b3,
    float* __restrict__ out)
{
    __shared__ float wbuf[64 * 64];    // 16KB: phase1 w3[0:64], phase2 w3[64:128]
    __shared__ float df[64][PAD];      // 17KB
    __shared__ float xi_s[64], hx[64], sb[64];
    __shared__ int   nbr_s[KNB];
    __shared__ float redm[4][64];
    int tid = threadIdx.x;
    int node = blockIdx.x;
    int og = tid & 15, kg = tid >> 4;
    int wv = tid >> 6;

    for (int t = tid; t < 4096; t += 256) wbuf[t] = w3[t];
    if (tid < 64) { sb[tid] = b3[tid]; xi_s[tid] = feat[(size_t)node * 64 + tid]; }
    if (tid < KNB) nbr_s[tid] = nbr[(size_t)node * KNB + tid];
    __syncthreads();

    for (int t = tid; t < KNB * 64; t += 256) {
        int k = t >> 6, d = t & 63;
        df[k][d] = feat[(size_t)nbr_s[k] * 64 + d] - xi_s[d];
    }
    if (tid < 4 * 64) df[60 + (tid >> 6)][tid & 63] = 0.f;
    if (tid < 64) {
        float acc = sb[tid];
        for (int d = 0; d < 64; ++d) acc = fmaf(xi_s[d], wbuf[d * 64 + tid], acc);
        hx[tid] = acc;
    }
    __syncthreads();

    for (int t = tid; t < 4096; t += 256) wbuf[t] = w3[4096 + t];
    __syncthreads();

    {
        int k0 = 4 * kg;
        float acc[4][4];
#pragma unroll
        for (int j = 0; j < 4; ++j)
#pragma unroll
            for (int i = 0; i < 4; ++i) acc[j][i] = hx[4 * og + i];
        for (int d = 0; d < 64; d += 4) {
            float4 a0 = *(const float4*)&df[k0 + 0][d];
            float4 a1 = *(const float4*)&df[k0 + 1][d];
            float4 a2 = *(const float4*)&df[k0 + 2][d];
            float4 a3 = *(const float4*)&df[k0 + 3][d];
            float4 b0 = *(const float4*)&wbuf[(d + 0) * 64 + 4 * og];
            float4 b1 = *(const float4*)&wbuf[(d + 1) * 64 + 4 * og];
            float4 b2 = *(const float4*)&wbuf[(d + 2) * 64 + 4 * og];
            float4 b3 = *(const float4*)&wbuf[(d + 3) * 64 + 4 * og];
            const float* av[4] = {(const float*)&a0, (const float*)&a1,
                                  (const float*)&a2, (const float*)&a3};
#pragma unroll
            for (int j = 0; j < 4; ++j) {
#pragma unroll
                for (int i = 0; i < 4; ++i) {
                    acc[j][i] = fmaf(av[j][0], ((const float*)&b0)[i], acc[j][i]);
                    acc[j][i] = fmaf(av[j][1], ((const float*)&b1)[i], acc[j][i]);
                    acc[j][i] = fmaf(av[j][2], ((const float*)&b2)[i], acc[j][i]);
                    acc[j][i] = fmaf(av[j][3], ((const float*)&b3)[i], acc[j][i]);
                }
            }
        }
        float m[4];
#pragma unroll
        for (int i = 0; i < 4; ++i) {
            float v = 0.f;
            if (kg < 15) {
#pragma unroll
                for (int j = 0; j < 4; ++j) v = fmaxf(v, fmaxf(acc[j][i], 0.f));
            }
            m[i] = v;
        }
#pragma unroll
        for (int i = 0; i < 4; ++i) {
            m[i] = fmaxf(m[i], __shfl_xor(m[i], 16, 64));
            m[i] = fmaxf(m[i], __shfl_xor(m[i], 32, 64));
        }
        if ((tid & 63) < 16) {
#pragma unroll
            for (int i = 0; i < 4; ++i) redm[wv][4 * og + i] = m[i];
        }
    }
    __syncthreads();
    if (tid < 64)
        out[(size_t)node * 64 + tid] =
            fmaxf(fmaxf(redm[0][tid], redm[1][tid]), fmaxf(redm[2][tid], redm[3][tid]));
}

// ---------------- concat [x1 | y | z] -> s1 (N x 192) ----------------
__global__ void k_concat(const float* __restrict__ x1, const float* __restrict__ yv,
                         const float* __restrict__ zv, float* __restrict__ s1)
{
    int gid = blockIdx.x * 256 + threadIdx.x;
    if (gid >= N_PTS * 192) return;
    int n = gid / 192, c = gid % 192;
    float v = (c < 64) ? x1[n * 64 + c]
            : (c < 128) ? yv[n * 64 + (c - 64)]
                        : zv[n * 64 + (c - 128)];
    s1[gid] = v;
}

// ---------------- generic FC: out = relu(in @ W + b), NB rows per block ----------------
template <int IN_DIM, int OUT_DIM, int NB, int THREADS>
__global__ __launch_bounds__(THREADS) void k_fc(
    const float* __restrict__ in, const float* __restrict__ W,
    const float* __restrict__ bias, float* __restrict__ out)
{
    __shared__ float s_in[NB][IN_DIM];
    constexpr int OCHUNKS = OUT_DIM / THREADS;
    int tid = threadIdx.x;
    int nblk = blockIdx.x / OCHUNKS;
    int ochunk = blockIdx.x % OCHUNKS;
    int n0 = nblk * NB;
    for (int t = tid; t < NB * IN_DIM; t += THREADS) {
        int r = t / IN_DIM, c = t % IN_DIM;
        s_in[r][c] = in[(size_t)(n0 + r) * IN_DIM + c];
    }
    __syncthreads();
    int o = ochunk * THREADS + tid;
    float acc[NB];
#pragma unroll
    for (int r = 0; r < NB; ++r) acc[r] = 0.f;
    for (int k = 0; k < IN_DIM; ++k) {
        float w = W[(size_t)k * OUT_DIM + o];
#pragma unroll
        for (int r = 0; r < NB; ++r) acc[r] = fmaf(s_in[r][k], w, acc[r]);
    }
    float b = bias[o];
#pragma unroll
    for (int r = 0; r < NB; ++r)
        out[(size_t)(n0 + r) * OUT_DIM + o] = fmaxf(acc[r] + b, 0.f);
}

// ---------------- FC2: dual-input (s1:192 | a:1024) @ wf2(1216x256) ----------------
__global__ __launch_bounds__(256) void k_fc2(
    const float* __restrict__ s1, const float* __restrict__ av,
    const float* __restrict__ W, const float* __restrict__ bias,
    float* __restrict__ out)
{
    __shared__ float s_in[8][1216];
    int tid = threadIdx.x;
    int n0 = blockIdx.x * 8;
    for (int t = tid; t < 8 * 192; t += 256) {
        int r = t / 192, c = t % 192;
        s_in[r][c] = s1[(size_t)(n0 + r) * 192 + c];
    }
    for (int t = tid; t < 8 * 1024; t += 256) {
        int r = t / 1024, c = t % 1024;
        s_in[r][192 + c] = av[(size_t)(n0 + r) * 1024 + c];
    }
    __syncthreads();
    float acc[8];
#pragma unroll
    for (int r = 0; r < 8; ++r) acc[r] = 0.f;
    for (int k = 0; k < 1216; ++k) {
        float w = W[(size_t)k * 256 + tid];
#pragma unroll
        for (int r = 0; r < 8; ++r) acc[r] = fmaf(s_in[r][k], w, acc[r]);
    }
    float b = bias[tid];
#pragma unroll
    for (int r = 0; r < 8; ++r)
        out[(size_t)(n0 + r) * 256 + tid] = fmaxf(acc[r] + b, 0.f);
}

// ---------------- FC5 + sigmoid + BCE partial sums ----------------
__global__ __launch_bounds__(256) void k_fc5(
    const float* __restrict__ in, const float* __restrict__ w5,
    const float* __restrict__ b5, const float* __restrict__ labels,
    float* __restrict__ out, float* __restrict__ lsum)
{
    __shared__ float red[4];
    int tid = threadIdx.x;
    int lane = tid & 63;
    int wv = tid >> 6;
    int n = blockIdx.x * 4 + wv;
    float part = 0.f;
    if (n < N_PTS) {
        const float* r = in + (size_t)n * 128;
        float d = r[lane] * w5[lane] + r[64 + lane] * w5[64 + lane];
        for (int off = 32; off > 0; off >>= 1) d += __shfl_down(d, off, 64);
        if (lane == 0) {
            float v = d + b5[0];
            float s = 1.f / (1.f + expf(-v));
            out[1 + n] = s;
            float p = fminf(fmaxf(s, 1e-7f), 1.f - 1e-7f);
            float lab = labels[n];
            part = lab * logf(p) + (1.f - lab) * logf(1.f - p);
        }
    }
    if (lane == 0) red[wv] = part;
    __syncthreads();
    if (tid == 0) atomicAdd(lsum, red[0] + red[1] + red[2] + red[3]);
}

__global__ void k_final(const float* __restrict__ lsum, float* __restrict__ out)
{
    out[0] = -lsum[0] / (float)N_PTS;
}

// ---------------- launch ----------------
extern "C" void kernel_launch(void* const* d_in, const int* in_sizes, int n_in,
                              void* d_out, int out_size, void* d_ws, size_t ws_size,
                              hipStream_t stream)
{
    const float* x   = (const float*)d_in[0];
    const int*   ei  = (const int*)d_in[1];
    const float* lab = (const float*)d_in[2];
    const float* w1a = (const float*)d_in[3];  const float* b1a = (const float*)d_in[4];
    const float* w1b = (const float*)d_in[5];  const float* b1b = (const float*)d_in[6];
    const float* w2a = (const float*)d_in[7];  const float* b2a = (const float*)d_in[8];
    const float* w2b = (const float*)d_in[9];  const float* b2b = (const float*)d_in[10];
    const float* w3  = (const float*)d_in[11]; const float* b3  = (const float*)d_in[12];
    const float* wf1 = (const float*)d_in[13]; const float* bf1 = (const float*)d_in[14];
    const float* wf2 = (const float*)d_in[15]; const float* bf2 = (const float*)d_in[16];
    const float* wf3 = (const float*)d_in[17]; const float* bf3 = (const float*)d_in[18];
    const float* wf4 = (const float*)d_in[19]; const float* bf4 = (const float*)d_in[20];
    const float* wf5 = (const float*)d_in[21]; const float* bf5 = (const float*)d_in[22];
    float* out = (float*)d_out;

    char* wsp = (char*)d_ws;
    size_t off = 0;
    auto alloc = [&](size_t bytes) -> void* {
        void* p = wsp + off;
        off += (bytes + 255) & ~(size_t)255;
        return p;
    };
    // persistent buffers
    float* x1    = (float*)alloc((size_t)N_PTS * 64 * 4);
    float* yv    = (float*)alloc((size_t)N_PTS * 64 * 4);
    float* zv    = (float*)alloc((size_t)N_PTS * 64 * 4);
    int*   nbr   = (int*)  alloc((size_t)N_PTS * KNB * 4);
    float* lsum  = (float*)alloc(256);
    // overlapped region: {featT, Dm} during KNN ; {s1, av, c1, c2, c3} during MLP head
    size_t regionA = off;
    float* featT = (float*)alloc((size_t)64 * N_PTS * 4);            // 2.56 MB
    float* Dm    = (float*)alloc((size_t)CHUNK * N_PTS * 4);         // 40 MB
    off = regionA;                                                   // rewind: alias
    float* s1    = (float*)alloc((size_t)N_PTS * 192 * 4);
    float* av    = (float*)alloc((size_t)N_PTS * 1024 * 4);
    float* c1    = (float*)alloc((size_t)N_PTS * 256 * 4);
    float* c2    = (float*)alloc((size_t)N_PTS * 256 * 4);
    float* c3    = (float*)alloc((size_t)N_PTS * 128 * 4);

    hipMemsetAsync(x1, 0, (size_t)N_PTS * 64 * 4, stream);
    hipMemsetAsync(lsum, 0, 4, stream);

    k_edge1<<<N_EDGES / 256, 256, 0, stream>>>(x, ei, w1a, b1a, w1b, b1b, x1);

    // KNN 1 on x1 (chunked distance matrix + register radix select)
    k_transpose<<<157, 256, 0, stream>>>(x1, featT);
    for (int c = 0; c < N_PTS / CHUNK; ++c) {
        k_dist<<<(CHUNK / QT) * JSPLIT, 256, 0, stream>>>(x1, featT, Dm, c * CHUNK);
        k_select<<<CHUNK, 256, 0, stream>>>(Dm, nbr, c * CHUNK);
    }
    k_conv2<<<N_PTS, 256, 0, stream>>>(x1, nbr, w2a, b2a, w2b, b2b, yv);

    // KNN 2 on yv
    k_transpose<<<157, 256, 0, stream>>>(yv, featT);
    for (int c = 0; c < N_PTS / CHUNK; ++c) {
        k_dist<<<(CHUNK / QT) * JSPLIT, 256, 0, stream>>>(yv, featT, Dm, c * CHUNK);
        k_select<<<CHUNK, 256, 0, stream>>>(Dm, nbr, c * CHUNK);
    }
    k_conv3<<<N_PTS, 256, 0, stream>>>(yv, nbr, w3, b3, zv);

    k_concat<<<(N_PTS * 192 + 255) / 256, 256, 0, stream>>>(x1, yv, zv, s1);
    k_fc<192, 1024, 8, 256><<<(N_PTS / 8) * (1024 / 256), 256, 0, stream>>>(s1, wf1, bf1, av);
    k_fc2<<<N_PTS / 8, 256, 0, stream>>>(s1, av, wf2, bf2, c1);
    k_fc<256, 256, 8, 256><<<N_PTS / 8, 256, 0, stream>>>(c1, wf3, bf3, c2);
    k_fc<256, 128, 8, 128><<<N_PTS / 8, 128, 0, stream>>>(c2, wf4, bf4, c3);
    k_fc5<<<(N_PTS + 3) / 4, 256, 0, stream>>>(c3, wf5, bf5, lab, out, lsum);
    k_final<<<1, 1, 0, stream>>>(lsum, out);
}

// Round 10
// 2439.180 us; speedup vs baseline: 3.8943x; 1.0019x over previous
//
#include <hip/hip_runtime.h>
#include <math.h>

#define N_PTS 10000
#define KNB 60
#define N_EDGES 160000
#define QT 10              // queries per k_dist tile
#define NG 2500            // point-groups of 4 (10000/4)
#define CHUNK 1000         // query rows per D-chunk (40 MB)
#define JSPLIT 10          // point-axis split in k_dist (NG/JSPLIT = 250)
#define PAD 68             // df/h row stride: 272B rows -> 16B aligned, bank-spread

static __device__ __forceinline__ float finf() { return __int_as_float(0x7f800000); }

// ---------------- Stage 1: warp-per-edge MLP2 + coalesced segment_max atomics ----------
__global__ __launch_bounds__(256) void k_edge1(
    const float* __restrict__ x, const int* __restrict__ ei,
    const float* __restrict__ w1a, const float* __restrict__ b1a,
    const float* __restrict__ w1b, const float* __restrict__ b1b,
    float* __restrict__ x1)
{
    __shared__ float sw1a[32 * 64];    // 8KB
    __shared__ float sw1b[64 * 64];    // 16KB
    __shared__ float sb1a[64], sb1b[64];
    __shared__ float hbuf[4][64];
    int tid = threadIdx.x;
    for (int t = tid; t < 32 * 64; t += 256) sw1a[t] = w1a[t];
    for (int t = tid; t < 64 * 64; t += 256) sw1b[t] = w1b[t];
    if (tid < 64) { sb1a[tid] = b1a[tid]; sb1b[tid] = b1b[tid]; }
    __syncthreads();

    int lane = tid & 63;
    int wv = tid >> 6;
    int e0 = blockIdx.x * 256 + wv * 64;

    for (int it = 0; it < 64; ++it) {
        int e = e0 + it;
        int src = ei[e];
        int dst = ei[N_EDGES + e];
        const float4* xi4 = (const float4*)(x + (size_t)dst * 16);
        const float4* xj4 = (const float4*)(x + (size_t)src * 16);
        float f[32];
#pragma unroll
        for (int q = 0; q < 4; ++q) {
            float4 a = xi4[q];              // broadcast loads (uniform addr per wave)
            float4 b = xj4[q];
            f[4 * q + 0] = a.x; f[4 * q + 1] = a.y;
            f[4 * q + 2] = a.z; f[4 * q + 3] = a.w;
            f[16 + 4 * q + 0] = b.x - a.x; f[16 + 4 * q + 1] = b.y - a.y;
            f[16 + 4 * q + 2] = b.z - a.z; f[16 + 4 * q + 3] = b.w - a.w;
        }
        float h = sb1a[lane];
#pragma unroll
        for (int d = 0; d < 32; ++d) h = fmaf(f[d], sw1a[d * 64 + lane], h);
        h = fmaxf(h, 0.f);
        hbuf[wv][lane] = h;                 // wave-synchronous LDS exchange
        float m = sb1b[lane];
#pragma unroll 8
        for (int k = 0; k < 64; ++k) m = fmaf(hbuf[wv][k], sw1b[k * 64 + lane], m);
        m = fmaxf(m, 0.f);
        atomicMax((int*)&x1[(size_t)dst * 64 + lane], __float_as_int(m));
    }
}

// ---------------- transpose feat[10000][64] -> featT[64][10000] ----------------
__global__ __launch_bounds__(256) void k_transpose(const float* __restrict__ feat,
                                                   float* __restrict__ featT)
{
    __shared__ float tile[64][65];
    int tid = threadIdx.x;
    int jb = blockIdx.x * 64;
    for (int t = tid; t < 64 * 64; t += 256) {
        int j = t >> 6, d = t & 63;
        if (jb + j < N_PTS) tile[j][d] = feat[(size_t)(jb + j) * 64 + d];
    }
    __syncthreads();
    for (int t = tid; t < 64 * 64; t += 256) {
        int d = t >> 6, j = t & 63;
        if (jb + j < N_PTS) featT[(size_t)d * N_PTS + jb + j] = tile[j][d];
    }
}

// ---------------- distance chunk: rows [row0, row0+CHUNK), QT queries x 250 groups/block ----
// Per-pair fmaf chain is dims-ascending (single accumulator) == verified round-1/3 chain.
__global__ __launch_bounds__(256) void k_dist(const float* __restrict__ feat,
                                              const float* __restrict__ featT,
                                              float* __restrict__ D, int row0)
{
    __shared__ float qtile[QT][64];
    int tid = threadIdx.x;
    int qi = blockIdx.x / JSPLIT;
    int js = blockIdx.x % JSPLIT;
    int qb = row0 + qi * QT;
    for (int t = tid; t < QT * 64; t += 256) {
        int q = t >> 6, d = t & 63;
        qtile[q][d] = feat[(size_t)(qb + q) * 64 + d];
    }
    __syncthreads();

    const float4* fT4 = (const float4*)featT;       // [64][NG] float4s
    const float4* qt4 = (const float4*)qtile;       // [QT][16]
    int g0 = js * (NG / JSPLIT);
    int g1 = g0 + (NG / JSPLIT);

    for (int g = g0 + tid; g < g1; g += 256) {
        float acc[QT][4];
#pragma unroll
        for (int q = 0; q < QT; ++q) {
            acc[q][0] = 0.f; acc[q][1] = 0.f; acc[q][2] = 0.f; acc[q][3] = 0.f;
        }
        for (int dc = 0; dc < 16; ++dc) {
            float4 p0 = fT4[(size_t)(4 * dc + 0) * NG + g];
            float4 p1 = fT4[(size_t)(4 * dc + 1) * NG + g];
            float4 p2 = fT4[(size_t)(4 * dc + 2) * NG + g];
            float4 p3 = fT4[(size_t)(4 * dc + 3) * NG + g];
#pragma unroll
            for (int q = 0; q < QT; ++q) {
                float4 xq = qt4[q * 16 + dc];       // LDS broadcast
                float dx;
                dx = xq.x - p0.x; acc[q][0] = fmaf(dx, dx, acc[q][0]);
                dx = xq.y - p1.x; acc[q][0] = fmaf(dx, dx, acc[q][0]);
                dx = xq.z - p2.x; acc[q][0] = fmaf(dx, dx, acc[q][0]);
                dx = xq.w - p3.x; acc[q][0] = fmaf(dx, dx, acc[q][0]);
                dx = xq.x - p0.y; acc[q][1] = fmaf(dx, dx, acc[q][1]);
                dx = xq.y - p1.y; acc[q][1] = fmaf(dx, dx, acc[q][1]);
                dx = xq.z - p2.y; acc[q][1] = fmaf(dx, dx, acc[q][1]);
                dx = xq.w - p3.y; acc[q][1] = fmaf(dx, dx, acc[q][1]);
                dx = xq.x - p0.z; acc[q][2] = fmaf(dx, dx, acc[q][2]);
                dx = xq.y - p1.z; acc[q][2] = fmaf(dx, dx, acc[q][2]);
                dx = xq.z - p2.z; acc[q][2] = fmaf(dx, dx, acc[q][2]);
                dx = xq.w - p3.z; acc[q][2] = fmaf(dx, dx, acc[q][2]);
                dx = xq.x - p0.w; acc[q][3] = fmaf(dx, dx, acc[q][3]);
                dx = xq.y - p1.w; acc[q][3] = fmaf(dx, dx, acc[q][3]);
                dx = xq.z - p2.w; acc[q][3] = fmaf(dx, dx, acc[q][3]);
                dx = xq.w - p3.w; acc[q][3] = fmaf(dx, dx, acc[q][3]);
            }
        }
#pragma unroll
        for (int q = 0; q < QT; ++q) {
            float4 v = make_float4(acc[q][0], acc[q][1], acc[q][2], acc[q][3]);
            ((float4*)(D + (size_t)(qb + q - row0) * N_PTS))[g] = v;
        }
    }
}

// ---------------- radix find over replicated histogram, shfl-scan (2 barriers) --------
// hist layout: [reps][2048]; counts = sum over replicas (exact). Thread t owns bins
// 8t..8t+7 (ascending with t) -> prefix order == bin numeric order, as before.
static __device__ __forceinline__ void radix_find_r(
    const unsigned* hist, int reps, unsigned need, int tid,
    volatile unsigned* wtot, volatile unsigned* outB, volatile unsigned* outCB)
{
    int lane = tid & 63;
    int wv = tid >> 6;
    int base = tid * 8;
    unsigned my = 0;
    for (int w = 0; w < reps; ++w)
#pragma unroll
        for (int b = 0; b < 8; ++b) my += hist[w * 2048 + base + b];

    unsigned incl = my;
#pragma unroll
    for (int off = 1; off < 64; off <<= 1) {
        unsigned v = __shfl_up(incl, off, 64);
        if (lane >= off) incl += v;
    }
    if (lane == 63) wtot[wv] = incl;
    __syncthreads();
    unsigned woff = 0;
    for (int w = 0; w < wv; ++w) woff += wtot[w];
    incl += woff;
    unsigned excl = incl - my;
    if (excl < need && incl >= need) {   // exactly one thread
        unsigned run = excl;
#pragma unroll
        for (int b = 0; b < 8; ++b) {
            unsigned h = 0;
            for (int w = 0; w < reps; ++w) h += hist[w * 2048 + base + b];
            if (run + h >= need) { *outB = base + b; *outCB = run; break; }
            run += h;
        }
    }
    __syncthreads();
}

__global__ __launch_bounds__(256) void k_select(const float* __restrict__ D,
                                                int* __restrict__ nbr, int row0)
{
    __shared__ unsigned hist4[4][2048];     // 32KB: per-wave level-1 replicas / level-2 in [0]
    __shared__ unsigned cand_key[512];
    __shared__ int      cand_idx[512];
    __shared__ unsigned wtot[4];
    __shared__ unsigned sB1, sCB1, sB2, sCB2, s_cnt, s_slot;

    int i = row0 + blockIdx.x;
    int tid = threadIdx.x;
    int wv = tid >> 6;
    if (tid == 0) { s_cnt = 0; s_slot = 0; }

    // load row into registers: 10 float4 groups per thread, g = tid + 256*r
    unsigned kv[10][4];
    const float4* row4 = (const float4*)(D + (size_t)blockIdx.x * N_PTS);
#pragma unroll
    for (int r = 0; r < 10; ++r) {
        int g = tid + 256 * r;
        if (g < NG) {
            float4 v = row4[g];
            kv[r][0] = __float_as_uint(v.x);
            kv[r][1] = __float_as_uint(v.y);
            kv[r][2] = __float_as_uint(v.z);
            kv[r][3] = __float_as_uint(v.w);
            if (g == (i >> 2)) kv[r][i & 3] = 0x7f800000u;   // diagonal -> +inf
        } else {
            kv[r][0] = kv[r][1] = kv[r][2] = kv[r][3] = 0x7fffffffu;  // OOB sentinel
        }
    }

    // ---- level 1: per-wave replicated histogram on bits 30:20 ----
    for (int b = tid; b < 4 * 2048; b += 256) ((unsigned*)hist4)[b] = 0;
    __syncthreads();
#pragma unroll
    for (int r = 0; r < 10; ++r)
#pragma unroll
        for (int c = 0; c < 4; ++c) atomicAdd(&hist4[wv][kv[r][c] >> 20], 1u);
    __syncthreads();
    radix_find_r((const unsigned*)hist4, 4, KNB, tid, wtot, &sB1, &sCB1);
    unsigned B1 = sB1;
    unsigned need2 = KNB - sCB1;

    // ---- level 2: single histogram (few keys) on bits 19:9 within bin B1 ----
    for (int b = tid; b < 2048; b += 256) hist4[0][b] = 0;
    __syncthreads();
#pragma unroll
    for (int r = 0; r < 10; ++r)
#pragma unroll
        for (int c = 0; c < 4; ++c) {
            unsigned k = kv[r][c];
            if ((k >> 20) == B1) atomicAdd(&hist4[0][(k >> 9) & 2047u], 1u);
        }
    __syncthreads();
    radix_find_r((const unsigned*)hist4, 1, need2, tid, wtot, &sB2, &sCB2);
    unsigned B2 = sB2;

    // ---- gather: definite neighbors + boundary candidates ----
#pragma unroll
    for (int r = 0; r < 10; ++r)
#pragma unroll
        for (int c = 0; c < 4; ++c) {
            unsigned k = kv[r][c];
            unsigned b1 = k >> 20;
            int j = 4 * (tid + 256 * r) + c;
            if (b1 < B1) {
                unsigned slot = atomicAdd(&s_slot, 1u);
                nbr[(size_t)i * KNB + slot] = j;
            } else if (b1 == B1) {
                unsigned b2 = (k >> 9) & 2047u;
                if (b2 < B2) {
                    unsigned slot = atomicAdd(&s_slot, 1u);
                    nbr[(size_t)i * KNB + slot] = j;
                } else if (b2 == B2) {
                    unsigned cc = atomicAdd(&s_cnt, 1u);
                    if (cc < 512) { cand_key[cc] = k; cand_idx[cc] = j; }
                }
            }
        }
    __syncthreads();

    // boundary bin: needf smallest by (key, idx) — cnt is typically 1-5
    if (tid == 0) {
        int definite = (int)s_slot;
        int needf = KNB - definite;
        int cnt = (int)(s_cnt < 512u ? s_cnt : 512u);
        for (int t = 0; t < needf; ++t) {
            unsigned bk = 0xFFFFFFFFu;
            int bi = 0x7FFFFFFF, bp = -1;
            for (int c = 0; c < cnt; ++c) {
                unsigned k = cand_key[c];
                int id = cand_idx[c];
                if (k < bk || (k == bk && id < bi)) { bk = k; bi = id; bp = c; }
            }
            cand_key[bp] = 0xFFFFFFFFu;
            nbr[(size_t)i * KNB + definite + t] = bi;
        }
    }
}

// ---------------- Stage 2: EdgeConv MLP2 + max over K, register-tiled ----------------
__global__ __launch_bounds__(256) void k_conv2(
    const float* __restrict__ feat, const int* __restrict__ nbr,
    const float* __restrict__ w2a, const float* __restrict__ b2a,
    const float* __restrict__ w2b, const float* __restrict__ b2b,
    float* __restrict__ out)
{
    __shared__ float wbuf[64 * 64];    // 16KB: phase1 w2a[0:64], phase2 w2a[64:128], phase3 w2b
    __shared__ float df[64][PAD];      // 17KB (rows 60..63 zeroed)
    __shared__ float h[64][PAD];       // 17KB
    __shared__ float xi_s[64], hx[64], sba[64], sbb[64];
    __shared__ int   nbr_s[KNB];
    __shared__ float redm[4][64];      // per-wave partial max
    int tid = threadIdx.x;
    int node = blockIdx.x;
    int og = tid & 15, kg = tid >> 4;
    int wv = tid >> 6;

    // P1: stage w2a rows 0..63 + vectors
    for (int t = tid; t < 4096; t += 256) wbuf[t] = w2a[t];
    if (tid < 64) {
        sba[tid] = b2a[tid]; sbb[tid] = b2b[tid];
        xi_s[tid] = feat[(size_t)node * 64 + tid];
    }
    if (tid < KNB) nbr_s[tid] = nbr[(size_t)node * KNB + tid];
    __syncthreads();

    // P2: hx (exact 64-chain per o, threads 0..63) + gather df + zero pad rows
    for (int t = tid; t < KNB * 64; t += 256) {
        int k = t >> 6, d = t & 63;
        df[k][d] = feat[(size_t)nbr_s[k] * 64 + d] - xi_s[d];
    }
    if (tid < 4 * 64) df[60 + (tid >> 6)][tid & 63] = 0.f;
    if (tid < 64) {
        float acc = sba[tid];
        for (int d = 0; d < 64; ++d) acc = fmaf(xi_s[d], wbuf[d * 64 + tid], acc);
        hx[tid] = acc;
    }
    __syncthreads();

    // P3: stage w2a rows 64..127
    for (int t = tid; t < 4096; t += 256) wbuf[t] = w2a[4096 + t];
    __syncthreads();

    // P4: layer 1, 4k x 4o register tile
    {
        int k0 = 4 * kg;
        float acc[4][4];
#pragma unroll
        for (int j = 0; j < 4; ++j)
#pragma unroll
            for (int i = 0; i < 4; ++i) acc[j][i] = hx[4 * og + i];
        for (int d = 0; d < 64; d += 4) {
            float4 a0 = *(const float4*)&df[k0 + 0][d];
            float4 a1 = *(const float4*)&df[k0 + 1][d];
            float4 a2 = *(const float4*)&df[k0 + 2][d];
            float4 a3 = *(const float4*)&df[k0 + 3][d];
            float4 b0 = *(const float4*)&wbuf[(d + 0) * 64 + 4 * og];
            float4 b1 = *(const float4*)&wbuf[(d + 1) * 64 + 4 * og];
            float4 b2 = *(const float4*)&wbuf[(d + 2) * 64 + 4 * og];
            float4 b3 = *(const float4*)&wbuf[(d + 3) * 64 + 4 * og];
            const float* av[4] = {(const float*)&a0, (const float*)&a1,
                                  (const float*)&a2, (const float*)&a3};
#pragma unroll
            for (int j = 0; j < 4; ++j) {
#pragma unroll
                for (int i = 0; i < 4; ++i) {
                    acc[j][i] = fmaf(av[j][0], ((const float*)&b0)[i], acc[j][i]);
                    acc[j][i] = fmaf(av[j][1], ((const float*)&b1)[i], acc[j][i]);
                    acc[j][i] = fmaf(av[j][2], ((const float*)&b2)[i], acc[j][i]);
                    acc[j][i] = fmaf(av[j][3], ((const float*)&b3)[i], acc[j][i]);
                }
            }
        }
#pragma unroll
        for (int j = 0; j < 4; ++j) {
            float4 hv;
            hv.x = fmaxf(acc[j][0], 0.f); hv.y = fmaxf(acc[j][1], 0.f);
            hv.z = fmaxf(acc[j][2], 0.f); hv.w = fmaxf(acc[j][3], 0.f);
            *(float4*)&h[k0 + j][4 * og] = hv;
        }
    }
    __syncthreads();

    // P5: stage w2b
    for (int t = tid; t < 4096; t += 256) wbuf[t] = w2b[t];
    __syncthreads();

    // P6: layer 2 + max over k
    {
        int k0 = 4 * kg;
        float acc[4][4];
#pragma unroll
        for (int j = 0; j < 4; ++j)
#pragma unroll
            for (int i = 0; i < 4; ++i) acc[j][i] = sbb[4 * og + i];
        for (int d = 0; d < 64; d += 4) {
            float4 a0 = *(const float4*)&h[k0 + 0][d];
            float4 a1 = *(const float4*)&h[k0 + 1][d];
            float4 a2 = *(const float4*)&h[k0 + 2][d];
            float4 a3 = *(const float4*)&h[k0 + 3][d];
            float4 b0 = *(const float4*)&wbuf[(d + 0) * 64 + 4 * og];
            float4 b1 = *(const float4*)&wbuf[(d + 1) * 64 + 4 * og];
            float4 b2 = *(const float4*)&wbuf[(d + 2) * 64 + 4 * og];
            float4 b3 = *(const float4*)&wbuf[(d + 3) * 64 + 4 * og];
            const float* av[4] = {(const float*)&a0, (const float*)&a1,
                                  (const float*)&a2, (const float*)&a3};
#pragma unroll
            for (int j = 0; j < 4; ++j) {
#pragma unroll
                for (int i = 0; i < 4; ++i) {
                    acc[j][i] = fmaf(av[j][0], ((const float*)&b0)[i], acc[j][i]);
                    acc[j][i] = fmaf(av[j][1], ((const float*)&b1)[i], acc[j][i]);
                    acc[j][i] = fmaf(av[j][2], ((const float*)&b2)[i], acc[j][i]);
                    acc[j][i] = fmaf(av[j][3], ((const float*)&b3)[i], acc[j][i]);
                }
            }
        }
        float m[4];
#pragma unroll
        for (int i = 0; i < 4; ++i) {
            float v = 0.f;   // all true outputs are >= 0 (relu), so 0 is identity
            if (kg < 15) {
#pragma unroll
                for (int j = 0; j < 4; ++j) v = fmaxf(v, fmaxf(acc[j][i], 0.f));
            }
            m[i] = v;
        }
        // reduce max across the wave's 4 kg-subgroups (lanes ^16, ^32)
#pragma unroll
        for (int i = 0; i < 4; ++i) {
            m[i] = fmaxf(m[i], __shfl_xor(m[i], 16, 64));
            m[i] = fmaxf(m[i], __shfl_xor(m[i], 32, 64));
        }
        if ((tid & 63) < 16) {
#pragma unroll
            for (int i = 0; i < 4; ++i) redm[wv][4 * og + i] = m[i];
        }
    }
    __syncthreads();
    if (tid < 64)
        out[(size_t)node * 64 + tid] =
            fmaxf(fmaxf(redm[0][tid], redm[1][tid]), fmaxf(redm[2][tid], redm[3][tid]));
}

// ---------------- Stage 3: single-layer EdgeConv + max over K, register-tiled ----------------
__global__ __launch_bounds__(256) void k_conv3(
    const float* __restrict__ feat, const int* __restrict__ nbr,
    const float* __restrict__ w3, const float* __restrict__ b3,
    float* __restrict__ out)
{
    __shared__ float wbuf[64 * 64];    // 16KB: phase1 w3[0:64], phase2 w3[64:128]
    __shared__ float df[64][PAD];      // 17KB
    __shared__ float xi_s[64], hx[64], sb[64];
    __shared__ int   nbr_s[KNB];
    __shared__ float redm[4][64];
    int tid = threadIdx.x;
    int node = blockIdx.x;
    int og = tid & 15, kg = tid >> 4;
    int wv = tid >> 6;

    for (int t = tid; t < 4096; t += 256) wbuf[t] = w3[t];
    if (tid < 64) { sb[tid] = b3[tid]; xi_s[tid] = feat[(size_t)node * 64 + tid]; }
    if (tid < KNB) nbr_s[tid] = nbr[(size_t)node * KNB + tid];
    __syncthreads();

    for (int t = tid; t < KNB * 64; t += 256) {
        int k = t >> 6, d = t & 63;
        df[k][d] = feat[(size_t)nbr_s[k] * 64 + d] - xi_s[d];
    }
    if (tid < 4 * 64) df[60 + (tid >> 6)][tid & 63] = 0.f;
    if (tid < 64) {
        float acc = sb[tid];
        for (int d = 0; d < 64; ++d) acc = fmaf(xi_s[d], wbuf[d * 64 + tid], acc);
        hx[tid] = acc;
    }
    __syncthreads();

    for (int t = tid; t < 4096; t += 256) wbuf[t] = w3[4096 + t];
    __syncthreads();

    {
        int k0 = 4 * kg;
        float acc[4][4];
#pragma unroll
        for (int j = 0; j < 4; ++j)
#pragma unroll
            for (int i = 0; i < 4; ++i) acc[j][i] = hx[4 * og + i];
        for (int d = 0; d < 64; d += 4) {
            float4 a0 = *(const float4*)&df[k0 + 0][d];
            float4 a1 = *(const float4*)&df[k0 + 1][d];
            float4 a2 = *(const float4*)&df[k0 + 2][d];
            float4 a3 = *(const float4*)&df[k0 + 3][d];
            float4 b0 = *(const float4*)&wbuf[(d + 0) * 64 + 4 * og];
            float4 b1 = *(const float4*)&wbuf[(d + 1) * 64 + 4 * og];
            float4 b2 = *(const float4*)&wbuf[(d + 2) * 64 + 4 * og];
            float4 b3 = *(const float4*)&wbuf[(d + 3) * 64 + 4 * og];
            const float* av[4] = {(const float*)&a0, (const float*)&a1,
                                  (const float*)&a2, (const float*)&a3};
#pragma unroll
            for (int j = 0; j < 4; ++j) {
#pragma unroll
                for (int i = 0; i < 4; ++i) {
                    acc[j][i] = fmaf(av[j][0], ((const float*)&b0)[i], acc[j][i]);
                    acc[j][i] = fmaf(av[j][1], ((const float*)&b1)[i], acc[j][i]);
                    acc[j][i] = fmaf(av[j][2], ((const float*)&b2)[i], acc[j][i]);
                    acc[j][i] = fmaf(av[j][3], ((const float*)&b3)[i], acc[j][i]);
                }
            }
        }
        float m[4];
#pragma unroll
        for (int i = 0; i < 4; ++i) {
            float v = 0.f;
            if (kg < 15) {
#pragma unroll
                for (int j = 0; j < 4; ++j) v = fmaxf(v, fmaxf(acc[j][i], 0.f));
            }
            m[i] = v;
        }
#pragma unroll
        for (int i = 0; i < 4; ++i) {
            m[i] = fmaxf(m[i], __shfl_xor(m[i], 16, 64));
            m[i] = fmaxf(m[i], __shfl_xor(m[i], 32, 64));
        }
        if ((tid & 63) < 16) {
#pragma unroll
            for (int i = 0; i < 4; ++i) redm[wv][4 * og + i] = m[i];
        }
    }
    __syncthreads();
    if (tid < 64)
        out[(size_t)node * 64 + tid] =
            fmaxf(fmaxf(redm[0][tid], redm[1][tid]), fmaxf(redm[2][tid], redm[3][tid]));
}

// ---------------- concat [x1 | y | z] -> s1 (N x 192) ----------------
__global__ void k_concat(const float* __restrict__ x1, const float* __restrict__ yv,
                         const float* __restrict__ zv, float* __restrict__ s1)
{
    int gid = blockIdx.x * 256 + threadIdx.x;
    if (gid >= N_PTS * 192) return;
    int n = gid / 192, c = gid % 192;
    float v = (c < 64) ? x1[n * 64 + c]
            : (c < 128) ? yv[n * 64 + (c - 64)]
                        : zv[n * 64 + (c - 128)];
    s1[gid] = v;
}

// ---------------- generic FC: out = relu(in @ W + b), NB rows per block ----------------
template <int IN_DIM, int OUT_DIM, int NB, int THREADS>
__global__ __launch_bounds__(THREADS) void k_fc(
    const float* __restrict__ in, const float* __restrict__ W,
    const float* __restrict__ bias, float* __restrict__ out)
{
    __shared__ float s_in[NB][IN_DIM];
    constexpr int OCHUNKS = OUT_DIM / THREADS;
    int tid = threadIdx.x;
    int nblk = blockIdx.x / OCHUNKS;
    int ochunk = blockIdx.x % OCHUNKS;
    int n0 = nblk * NB;
    for (int t = tid; t < NB * IN_DIM; t += THREADS) {
        int r = t / IN_DIM, c = t % IN_DIM;
        s_in[r][c] = in[(size_t)(n0 + r) * IN_DIM + c];
    }
    __syncthreads();
    int o = ochunk * THREADS + tid;
    float acc[NB];
#pragma unroll
    for (int r = 0; r < NB; ++r) acc[r] = 0.f;
    for (int k = 0; k < IN_DIM; ++k) {
        float w = W[(size_t)k * OUT_DIM + o];
#pragma unroll
        for (int r = 0; r < NB; ++r) acc[r] = fmaf(s_in[r][k], w, acc[r]);
    }
    float b = bias[o];
#pragma unroll
    for (int r = 0; r < NB; ++r)
        out[(size_t)(n0 + r) * OUT_DIM + o] = fmaxf(acc[r] + b, 0.f);
}

// ---------------- FC2: dual-input (s1:192 | a:1024) @ wf2(1216x256) ----------------
__global__ __launch_bounds__(256) void k_fc2(
    const float* __restrict__ s1, const float* __restrict__ av,
    const float* __restrict__ W, const float* __restrict__ bias,
    float* __restrict__ out)
{
    __shared__ float s_in[8][1216];
    int tid = threadIdx.x;
    int n0 = blockIdx.x * 8;
    for (int t = tid; t < 8 * 192; t += 256) {
        int r = t / 192, c = t % 192;
        s_in[r][c] = s1[(size_t)(n0 + r) * 192 + c];
    }
    for (int t = tid; t < 8 * 1024; t += 256) {
        int r = t / 1024, c = t % 1024;
        s_in[r][192 + c] = av[(size_t)(n0 + r) * 1024 + c];
    }
    __syncthreads();
    float acc[8];
#pragma unroll
    for (int r = 0; r < 8; ++r) acc[r] = 0.f;
    for (int k = 0; k < 1216; ++k) {
        float w = W[(size_t)k * 256 + tid];
#pragma unroll
        for (int r = 0; r < 8; ++r) acc[r] = fmaf(s_in[r][k], w, acc[r]);
    }
    float b = bias[tid];
#pragma unroll
    for (int r = 0; r < 8; ++r)
        out[(size_t)(n0 + r) * 256 + tid] = fmaxf(acc[r] + b, 0.f);
}

// ---------------- FC5 + sigmoid + BCE partial sums ----------------
__global__ __launch_bounds__(256) void k_fc5(
    const float* __restrict__ in, const float* __restrict__ w5,
    const float* __restrict__ b5, const float* __restrict__ labels,
    float* __restrict__ out, float* __restrict__ lsum)
{
    __shared__ float red[4];
    int tid = threadIdx.x;
    int lane = tid & 63;
    int wv = tid >> 6;
    int n = blockIdx.x * 4 + wv;
    float part = 0.f;
    if (n < N_PTS) {
        const float* r = in + (size_t)n * 128;
        float d = r[lane] * w5[lane] + r[64 + lane] * w5[64 + lane];
        for (int off = 32; off > 0; off >>= 1) d += __shfl_down(d, off, 64);
        if (lane == 0) {
            float v = d + b5[0];
            float s = 1.f / (1.f + expf(-v));
            out[1 + n] = s;
            float p = fminf(fmaxf(s, 1e-7f), 1.f - 1e-7f);
            float lab = labels[n];
            part = lab * logf(p) + (1.f - lab) * logf(1.f - p);
        }
    }
    if (lane == 0) red[wv] = part;
    __syncthreads();
    if (tid == 0) atomicAdd(lsum, red[0] + red[1] + red[2] + red[3]);
}

__global__ void k_final(const float* __restrict__ lsum, float* __restrict__ out)
{
    out[0] = -lsum[0] / (float)N_PTS;
}

// ---------------- launch ----------------
extern "C" void kernel_launch(void* const* d_in, const int* in_sizes, int n_in,
                              void* d_out, int out_size, void* d_ws, size_t ws_size,
                              hipStream_t stream)
{
    const float* x   = (const float*)d_in[0];
    const int*   ei  = (const int*)d_in[1];
    const float* lab = (const float*)d_in[2];
    const float* w1a = (const float*)d_in[3];  const float* b1a = (const float*)d_in[4];
    const float* w1b = (const float*)d_in[5];  const float* b1b = (const float*)d_in[6];
    const float* w2a = (const float*)d_in[7];  const float* b2a = (const float*)d_in[8];
    const float* w2b = (const float*)d_in[9];  const float* b2b = (const float*)d_in[10];
    const float* w3  = (const float*)d_in[11]; const float* b3  = (const float*)d_in[12];
    const float* wf1 = (const float*)d_in[13]; const float* bf1 = (const float*)d_in[14];
    const float* wf2 = (const float*)d_in[15]; const float* bf2 = (const float*)d_in[16];
    const float* wf3 = (const float*)d_in[17]; const float* bf3 = (const float*)d_in[18];
    const float* wf4 = (const float*)d_in[19]; const float* bf4 = (const float*)d_in[20];
    const float* wf5 = (const float*)d_in[21]; const float* bf5 = (const float*)d_in[22];
    float* out = (float*)d_out;

    char* wsp = (char*)d_ws;
    size_t off = 0;
    auto alloc = [&](size_t bytes) -> void* {
        void* p = wsp + off;
        off += (bytes + 255) & ~(size_t)255;
        return p;
    };
    // persistent buffers
    float* x1    = (float*)alloc((size_t)N_PTS * 64 * 4);
    float* yv    = (float*)alloc((size_t)N_PTS * 64 * 4);
    float* zv    = (float*)alloc((size_t)N_PTS * 64 * 4);
    int*   nbr   = (int*)  alloc((size_t)N_PTS * KNB * 4);
    float* lsum  = (float*)alloc(256);
    // overlapped region: {featT, Dm} during KNN ; {s1, av, c1, c2, c3} during MLP head
    size_t regionA = off;
    float* featT = (float*)alloc((size_t)64 * N_PTS * 4);            // 2.56 MB
    float* Dm    = (float*)alloc((size_t)CHUNK * N_PTS * 4);         // 40 MB
    off = regionA;                                                   // rewind: alias
    float* s1    = (float*)alloc((size_t)N_PTS * 192 * 4);
    float* av    = (float*)alloc((size_t)N_PTS * 1024 * 4);
    float* c1    = (float*)alloc((size_t)N_PTS * 256 * 4);
    float* c2    = (float*)alloc((size_t)N_PTS * 256 * 4);
    float* c3    = (float*)alloc((size_t)N_PTS * 128 * 4);

    hipMemsetAsync(x1, 0, (size_t)N_PTS * 64 * 4, stream);
    hipMemsetAsync(lsum, 0, 4, stream);

    k_edge1<<<N_EDGES / 256, 256, 0, stream>>>(x, ei, w1a, b1a, w1b, b1b, x1);

    // KNN 1 on x1 (chunked distance matrix + register radix select)
    k_transpose<<<157, 256, 0, stream>>>(x1, featT);
    for (int c = 0; c < N_PTS / CHUNK; ++c) {
        k_dist<<<(CHUNK / QT) * JSPLIT, 256, 0, stream>>>(x1, featT, Dm, c * CHUNK);
        k_select<<<CHUNK, 256, 0, stream>>>(Dm, nbr, c * CHUNK);
    }
    k_conv2<<<N_PTS, 256, 0, stream>>>(x1, nbr, w2a, b2a, w2b, b2b, yv);

    // KNN 2 on yv
    k_transpose<<<157, 256, 0, stream>>>(yv, featT);
    for (int c = 0; c < N_PTS / CHUNK; ++c) {
        k_dist<<<(CHUNK / QT) * JSPLIT, 256, 0, stream>>>(yv, featT, Dm, c * CHUNK);
        k_select<<<CHUNK, 256, 0, stream>>>(Dm, nbr, c * CHUNK);
    }
    k_conv3<<<N_PTS, 256, 0, stream>>>(yv, nbr, w3, b3, zv);

    k_concat<<<(N_PTS * 192 + 255) / 256, 256, 0, stream>>>(x1, yv, zv, s1);
    k_fc<192, 1024, 8, 256><<<(N_PTS / 8) * (1024 / 256), 256, 0, stream>>>(s1, wf1, bf1, av);
    k_fc2<<<N_PTS / 8, 256, 0, stream>>>(s1, av, wf2, bf2, c1);
    k_fc<256, 256, 8, 256><<<N_PTS / 8, 256, 0, stream>>>(c1, wf3, bf3, c2);
    k_fc<256, 128, 8, 128><<<N_PTS / 8, 128, 0, stream>>>(c2, wf4, bf4, c3);
    k_fc5<<<(N_PTS + 3) / 4, 256, 0, stream>>>(c3, wf5, bf5, lab, out, lsum);
    k_final<<<1, 1, 0, stream>>>(lsum, out);
}

// Round 11
// 2330.524 us; speedup vs baseline: 4.0759x; 1.0466x over previous
//
#include <hip/hip_runtime.h>
#include <math.h>

#define N_PTS 10000
#define KNB 60
#define N_EDGES 160000
#define QT 10              // queries per k_dist tile
#define NG 2500            // point-groups of 4 (10000/4)
#define JSPLIT 10          // point-axis split in k_dist
#define PAD 68             // df/h row stride: 272B rows -> 16B aligned, bank-spread

static __device__ __forceinline__ float finf() { return __int_as_float(0x7f800000); }

// ---------------- Stage 1: warp-per-edge MLP2 + coalesced segment_max atomics ----------
__global__ __launch_bounds__(256) void k_edge1(
    const float* __restrict__ x, const int* __restrict__ ei,
    const float* __restrict__ w1a, const float* __restrict__ b1a,
    const float* __restrict__ w1b, const float* __restrict__ b1b,
    float* __restrict__ x1)
{
    __shared__ float sw1a[32 * 64];    // 8KB
    __shared__ float sw1b[64 * 64];    // 16KB
    __shared__ float sb1a[64], sb1b[64];
    __shared__ float hbuf[4][64];
    int tid = threadIdx.x;
    for (int t = tid; t < 32 * 64; t += 256) sw1a[t] = w1a[t];
    for (int t = tid; t < 64 * 64; t += 256) sw1b[t] = w1b[t];
    if (tid < 64) { sb1a[tid] = b1a[tid]; sb1b[tid] = b1b[tid]; }
    __syncthreads();

    int lane = tid & 63;
    int wv = tid >> 6;
    int e0 = blockIdx.x * 256 + wv * 64;

    for (int it = 0; it < 64; ++it) {
        int e = e0 + it;
        int src = ei[e];
        int dst = ei[N_EDGES + e];
        const float4* xi4 = (const float4*)(x + (size_t)dst * 16);
        const float4* xj4 = (const float4*)(x + (size_t)src * 16);
        float f[32];
#pragma unroll
        for (int q = 0; q < 4; ++q) {
            float4 a = xi4[q];              // broadcast loads (uniform addr per wave)
            float4 b = xj4[q];
            f[4 * q + 0] = a.x; f[4 * q + 1] = a.y;
            f[4 * q + 2] = a.z; f[4 * q + 3] = a.w;
            f[16 + 4 * q + 0] = b.x - a.x; f[16 + 4 * q + 1] = b.y - a.y;
            f[16 + 4 * q + 2] = b.z - a.z; f[16 + 4 * q + 3] = b.w - a.w;
        }
        float h = sb1a[lane];
#pragma unroll
        for (int d = 0; d < 32; ++d) h = fmaf(f[d], sw1a[d * 64 + lane], h);
        h = fmaxf(h, 0.f);
        hbuf[wv][lane] = h;                 // wave-synchronous LDS exchange
        float m = sb1b[lane];
#pragma unroll 8
        for (int k = 0; k < 64; ++k) m = fmaf(hbuf[wv][k], sw1b[k * 64 + lane], m);
        m = fmaxf(m, 0.f);
        atomicMax((int*)&x1[(size_t)dst * 64 + lane], __float_as_int(m));
    }
}

// ---------------- transpose feat[10000][64] -> featT[64][10000] ----------------
__global__ __launch_bounds__(256) void k_transpose(const float* __restrict__ feat,
                                                   float* __restrict__ featT)
{
    __shared__ float tile[64][65];
    int tid = threadIdx.x;
    int jb = blockIdx.x * 64;
    for (int t = tid; t < 64 * 64; t += 256) {
        int j = t >> 6, d = t & 63;
        if (jb + j < N_PTS) tile[j][d] = feat[(size_t)(jb + j) * 64 + d];
    }
    __syncthreads();
    for (int t = tid; t < 64 * 64; t += 256) {
        int d = t >> 6, j = t & 63;
        if (jb + j < N_PTS) featT[(size_t)d * N_PTS + jb + j] = tile[j][d];
    }
}

// ---------------- distance chunk: rows [row0, row0+chunk), QT queries/tile ----------
// Per-pair fmaf chain is dims-ascending (single accumulator) == verified round-1/3 chain.
__global__ __launch_bounds__(256) void k_dist(const float* __restrict__ feat,
                                              const float* __restrict__ featT,
                                              float* __restrict__ D, int row0)
{
    __shared__ float qtile[QT][64];
    int tid = threadIdx.x;
    int qi = blockIdx.x / JSPLIT;
    int js = blockIdx.x % JSPLIT;
    int qb = row0 + qi * QT;
    for (int t = tid; t < QT * 64; t += 256) {
        int q = t >> 6, d = t & 63;
        qtile[q][d] = feat[(size_t)(qb + q) * 64 + d];
    }
    __syncthreads();

    const float4* fT4 = (const float4*)featT;       // [64][NG] float4s
    const float4* qt4 = (const float4*)qtile;       // [QT][16]
    int g0 = js * (NG / JSPLIT);
    int g1 = g0 + (NG / JSPLIT);

    for (int g = g0 + tid; g < g1; g += 256) {
        float acc[QT][4];
#pragma unroll
        for (int q = 0; q < QT; ++q) {
            acc[q][0] = 0.f; acc[q][1] = 0.f; acc[q][2] = 0.f; acc[q][3] = 0.f;
        }
        for (int dc = 0; dc < 16; ++dc) {
            float4 p0 = fT4[(size_t)(4 * dc + 0) * NG + g];
            float4 p1 = fT4[(size_t)(4 * dc + 1) * NG + g];
            float4 p2 = fT4[(size_t)(4 * dc + 2) * NG + g];
            float4 p3 = fT4[(size_t)(4 * dc + 3) * NG + g];
#pragma unroll
            for (int q = 0; q < QT; ++q) {
                float4 xq = qt4[q * 16 + dc];       // LDS broadcast
                float dx;
                dx = xq.x - p0.x; acc[q][0] = fmaf(dx, dx, acc[q][0]);
                dx = xq.y - p1.x; acc[q][0] = fmaf(dx, dx, acc[q][0]);
                dx = xq.z - p2.x; acc[q][0] = fmaf(dx, dx, acc[q][0]);
                dx = xq.w - p3.x; acc[q][0] = fmaf(dx, dx, acc[q][0]);
                dx = xq.x - p0.y; acc[q][1] = fmaf(dx, dx, acc[q][1]);
                dx = xq.y - p1.y; acc[q][1] = fmaf(dx, dx, acc[q][1]);
                dx = xq.z - p2.y; acc[q][1] = fmaf(dx, dx, acc[q][1]);
                dx = xq.w - p3.y; acc[q][1] = fmaf(dx, dx, acc[q][1]);
                dx = xq.x - p0.z; acc[q][2] = fmaf(dx, dx, acc[q][2]);
                dx = xq.y - p1.z; acc[q][2] = fmaf(dx, dx, acc[q][2]);
                dx = xq.z - p2.z; acc[q][2] = fmaf(dx, dx, acc[q][2]);
                dx = xq.w - p3.z; acc[q][2] = fmaf(dx, dx, acc[q][2]);
                dx = xq.x - p0.w; acc[q][3] = fmaf(dx, dx, acc[q][3]);
                dx = xq.y - p1.w; acc[q][3] = fmaf(dx, dx, acc[q][3]);
                dx = xq.z - p2.w; acc[q][3] = fmaf(dx, dx, acc[q][3]);
                dx = xq.w - p3.w; acc[q][3] = fmaf(dx, dx, acc[q][3]);
            }
        }
#pragma unroll
        for (int q = 0; q < QT; ++q) {
            float4 v = make_float4(acc[q][0], acc[q][1], acc[q][2], acc[q][3]);
            ((float4*)(D + (size_t)(qb + q - row0) * N_PTS))[g] = v;
        }
    }
}

// ---------------- radix find over replicated histogram, shfl-scan (2 barriers) --------
static __device__ __forceinline__ void radix_find_r(
    const unsigned* hist, int reps, unsigned need, int tid,
    volatile unsigned* wtot, volatile unsigned* outB, volatile unsigned* outCB)
{
    int lane = tid & 63;
    int wv = tid >> 6;
    int base = tid * 8;
    unsigned my = 0;
    for (int w = 0; w < reps; ++w)
#pragma unroll
        for (int b = 0; b < 8; ++b) my += hist[w * 2048 + base + b];

    unsigned incl = my;
#pragma unroll
    for (int off = 1; off < 64; off <<= 1) {
        unsigned v = __shfl_up(incl, off, 64);
        if (lane >= off) incl += v;
    }
    if (lane == 63) wtot[wv] = incl;
    __syncthreads();
    unsigned woff = 0;
    for (int w = 0; w < wv; ++w) woff += wtot[w];
    incl += woff;
    unsigned excl = incl - my;
    if (excl < need && incl >= need) {   // exactly one thread
        unsigned run = excl;
#pragma unroll
        for (int b = 0; b < 8; ++b) {
            unsigned h = 0;
            for (int w = 0; w < reps; ++w) h += hist[w * 2048 + base + b];
            if (run + h >= need) { *outB = base + b; *outCB = run; break; }
            run += h;
        }
    }
    __syncthreads();
}

__global__ __launch_bounds__(256) void k_select(const float* __restrict__ D,
                                                int* __restrict__ nbr, int row0)
{
    __shared__ unsigned hist4[4][2048];     // 32KB
    __shared__ unsigned cand_key[512];
    __shared__ int      cand_idx[512];
    __shared__ unsigned wtot[4];
    __shared__ unsigned sB1, sCB1, sB2, sCB2, s_cnt, s_slot;

    int i = row0 + blockIdx.x;
    int tid = threadIdx.x;
    int wv = tid >> 6;
    if (tid == 0) { s_cnt = 0; s_slot = 0; }

    unsigned kv[10][4];
    const float4* row4 = (const float4*)(D + (size_t)blockIdx.x * N_PTS);
#pragma unroll
    for (int r = 0; r < 10; ++r) {
        int g = tid + 256 * r;
        if (g < NG) {
            float4 v = row4[g];
            kv[r][0] = __float_as_uint(v.x);
            kv[r][1] = __float_as_uint(v.y);
            kv[r][2] = __float_as_uint(v.z);
            kv[r][3] = __float_as_uint(v.w);
            if (g == (i >> 2)) kv[r][i & 3] = 0x7f800000u;   // diagonal -> +inf
        } else {
            kv[r][0] = kv[r][1] = kv[r][2] = kv[r][3] = 0x7fffffffu;  // OOB sentinel
        }
    }

    for (int b = tid; b < 4 * 2048; b += 256) ((unsigned*)hist4)[b] = 0;
    __syncthreads();
#pragma unroll
    for (int r = 0; r < 10; ++r)
#pragma unroll
        for (int c = 0; c < 4; ++c) atomicAdd(&hist4[wv][kv[r][c] >> 20], 1u);
    __syncthreads();
    radix_find_r((const unsigned*)hist4, 4, KNB, tid, wtot, &sB1, &sCB1);
    unsigned B1 = sB1;
    unsigned need2 = KNB - sCB1;

    for (int b = tid; b < 2048; b += 256) hist4[0][b] = 0;
    __syncthreads();
#pragma unroll
    for (int r = 0; r < 10; ++r)
#pragma unroll
        for (int c = 0; c < 4; ++c) {
            unsigned k = kv[r][c];
            if ((k >> 20) == B1) atomicAdd(&hist4[0][(k >> 9) & 2047u], 1u);
        }
    __syncthreads();
    radix_find_r((const unsigned*)hist4, 1, need2, tid, wtot, &sB2, &sCB2);
    unsigned B2 = sB2;

#pragma unroll
    for (int r = 0; r < 10; ++r)
#pragma unroll
        for (int c = 0; c < 4; ++c) {
            unsigned k = kv[r][c];
            unsigned b1 = k >> 20;
            int j = 4 * (tid + 256 * r) + c;
            if (b1 < B1) {
                unsigned slot = atomicAdd(&s_slot, 1u);
                nbr[(size_t)i * KNB + slot] = j;
            } else if (b1 == B1) {
                unsigned b2 = (k >> 9) & 2047u;
                if (b2 < B2) {
                    unsigned slot = atomicAdd(&s_slot, 1u);
                    nbr[(size_t)i * KNB + slot] = j;
                } else if (b2 == B2) {
                    unsigned cc = atomicAdd(&s_cnt, 1u);
                    if (cc < 512) { cand_key[cc] = k; cand_idx[cc] = j; }
                }
            }
        }
    __syncthreads();

    if (tid == 0) {
        int definite = (int)s_slot;
        int needf = KNB - definite;
        int cnt = (int)(s_cnt < 512u ? s_cnt : 512u);
        for (int t = 0; t < needf; ++t) {
            unsigned bk = 0xFFFFFFFFu;
            int bi = 0x7FFFFFFF, bp = -1;
            for (int c = 0; c < cnt; ++c) {
                unsigned k = cand_key[c];
                int id = cand_idx[c];
                if (k < bk || (k == bk && id < bi)) { bk = k; bi = id; bp = c; }
            }
            cand_key[bp] = 0xFFFFFFFFu;
            nbr[(size_t)i * KNB + definite + t] = bi;
        }
    }
}

// ---------------- Stage 2: EdgeConv MLP2 + max over K, 128 thr, 8k x 4o tiles --------
// LDS-pipe relief: 12 ds_read_b128 per 128 FMA-inst (was 8 per 64). Chains unchanged.
__global__ __launch_bounds__(128) void k_conv2(
    const float* __restrict__ feat, const int* __restrict__ nbr,
    const float* __restrict__ w2a, const float* __restrict__ b2a,
    const float* __restrict__ w2b, const float* __restrict__ b2b,
    float* __restrict__ out)
{
    __shared__ float wbuf[64 * 64];    // 16KB
    __shared__ float df[64][PAD];      // 17KB (rows 60..63 zeroed)
    __shared__ float h[64][PAD];       // 17KB
    __shared__ float xi_s[64], hx[64], sba[64], sbb[64];
    __shared__ int   nbr_s[KNB];
    __shared__ float redm[2][64];
    int tid = threadIdx.x;             // 0..127
    int node = blockIdx.x;
    int og = tid & 15;                 // o-tile 4*og
    int kg = tid >> 4;                 // 0..7, k-tile 8*kg
    int wv = tid >> 6;                 // 0..1

    for (int t = tid; t < 4096; t += 128) wbuf[t] = w2a[t];
    if (tid < 64) {
        sba[tid] = b2a[tid]; sbb[tid] = b2b[tid];
        xi_s[tid] = feat[(size_t)node * 64 + tid];
    }
    if (tid < KNB) nbr_s[tid] = nbr[(size_t)node * KNB + tid];
    __syncthreads();

    for (int t = tid; t < KNB * 64; t += 128) {
        int k = t >> 6, d = t & 63;
        df[k][d] = feat[(size_t)nbr_s[k] * 64 + d] - xi_s[d];
    }
    for (int t = tid; t < 4 * 64; t += 128) df[60 + (t >> 6)][t & 63] = 0.f;
    if (tid < 64) {
        float acc = sba[tid];
        for (int d = 0; d < 64; ++d) acc = fmaf(xi_s[d], wbuf[d * 64 + tid], acc);
        hx[tid] = acc;
    }
    __syncthreads();

    for (int t = tid; t < 4096; t += 128) wbuf[t] = w2a[4096 + t];
    __syncthreads();

    // layer 1
    {
        int k0 = 8 * kg;
        float acc[8][4];
#pragma unroll
        for (int j = 0; j < 8; ++j)
#pragma unroll
            for (int i = 0; i < 4; ++i) acc[j][i] = hx[4 * og + i];
        for (int d = 0; d < 64; d += 4) {
            float4 a0 = *(const float4*)&df[k0 + 0][d];
            float4 a1 = *(const float4*)&df[k0 + 1][d];
            float4 a2 = *(const float4*)&df[k0 + 2][d];
            float4 a3 = *(const float4*)&df[k0 + 3][d];
            float4 a4 = *(const float4*)&df[k0 + 4][d];
            float4 a5 = *(const float4*)&df[k0 + 5][d];
            float4 a6 = *(const float4*)&df[k0 + 6][d];
            float4 a7 = *(const float4*)&df[k0 + 7][d];
            float4 b0 = *(const float4*)&wbuf[(d + 0) * 64 + 4 * og];
            float4 b1 = *(const float4*)&wbuf[(d + 1) * 64 + 4 * og];
            float4 b2 = *(const float4*)&wbuf[(d + 2) * 64 + 4 * og];
            float4 b3 = *(const float4*)&wbuf[(d + 3) * 64 + 4 * og];
            const float* av[8] = {(const float*)&a0, (const float*)&a1,
                                  (const float*)&a2, (const float*)&a3,
                                  (const float*)&a4, (const float*)&a5,
                                  (const float*)&a6, (const float*)&a7};
#pragma unroll
            for (int j = 0; j < 8; ++j) {
#pragma unroll
                for (int i = 0; i < 4; ++i) {
                    acc[j][i] = fmaf(av[j][0], ((const float*)&b0)[i], acc[j][i]);
                    acc[j][i] = fmaf(av[j][1], ((const float*)&b1)[i], acc[j][i]);
                    acc[j][i] = fmaf(av[j][2], ((const float*)&b2)[i], acc[j][i]);
                    acc[j][i] = fmaf(av[j][3], ((const float*)&b3)[i], acc[j][i]);
                }
            }
        }
#pragma unroll
        for (int j = 0; j < 8; ++j) {
            float4 hv;
            hv.x = fmaxf(acc[j][0], 0.f); hv.y = fmaxf(acc[j][1], 0.f);
            hv.z = fmaxf(acc[j][2], 0.f); hv.w = fmaxf(acc[j][3], 0.f);
            *(float4*)&h[k0 + j][4 * og] = hv;
        }
    }
    __syncthreads();

    for (int t = tid; t < 4096; t += 128) wbuf[t] = w2b[t];
    __syncthreads();

    // layer 2 + max over k
    {
        int k0 = 8 * kg;
        float acc[8][4];
#pragma unroll
        for (int j = 0; j < 8; ++j)
#pragma unroll
            for (int i = 0; i < 4; ++i) acc[j][i] = sbb[4 * og + i];
        for (int d = 0; d < 64; d += 4) {
            float4 a0 = *(const float4*)&h[k0 + 0][d];
            float4 a1 = *(const float4*)&h[k0 + 1][d];
            float4 a2 = *(const float4*)&h[k0 + 2][d];
            float4 a3 = *(const float4*)&h[k0 + 3][d];
            float4 a4 = *(const float4*)&h[k0 + 4][d];
            float4 a5 = *(const float4*)&h[k0 + 5][d];
            float4 a6 = *(const float4*)&h[k0 + 6][d];
            float4 a7 = *(const float4*)&h[k0 + 7][d];
            float4 b0 = *(const float4*)&wbuf[(d + 0) * 64 + 4 * og];
            float4 b1 = *(const float4*)&wbuf[(d + 1) * 64 + 4 * og];
            float4 b2 = *(const float4*)&wbuf[(d + 2) * 64 + 4 * og];
            float4 b3 = *(const float4*)&wbuf[(d + 3) * 64 + 4 * og];
            const float* av[8] = {(const float*)&a0, (const float*)&a1,
                                  (const float*)&a2, (const float*)&a3,
                                  (const float*)&a4, (const float*)&a5,
                                  (const float*)&a6, (const float*)&a7};
#pragma unroll
            for (int j = 0; j < 8; ++j) {
#pragma unroll
                for (int i = 0; i < 4; ++i) {
                    acc[j][i] = fmaf(av[j][0], ((const float*)&b0)[i], acc[j][i]);
                    acc[j][i] = fmaf(av[j][1], ((const float*)&b1)[i], acc[j][i]);
                    acc[j][i] = fmaf(av[j][2], ((const float*)&b2)[i], acc[j][i]);
                    acc[j][i] = fmaf(av[j][3], ((const float*)&b3)[i], acc[j][i]);
                }
            }
        }
        float m[4];
#pragma unroll
        for (int i = 0; i < 4; ++i) {
            float v = 0.f;   // all true outputs >= 0 (relu): 0 is identity
#pragma unroll
            for (int j = 0; j < 8; ++j)
                if (k0 + j < KNB) v = fmaxf(v, fmaxf(acc[j][i], 0.f));
            m[i] = v;
        }
#pragma unroll
        for (int i = 0; i < 4; ++i) {
            m[i] = fmaxf(m[i], __shfl_xor(m[i], 16, 64));
            m[i] = fmaxf(m[i], __shfl_xor(m[i], 32, 64));
        }
        if ((tid & 63) < 16) {
#pragma unroll
            for (int i = 0; i < 4; ++i) redm[wv][4 * og + i] = m[i];
        }
    }
    __syncthreads();
    if (tid < 64)
        out[(size_t)node * 64 + tid] = fmaxf(redm[0][tid], redm[1][tid]);
}

// ---------------- Stage 3: single-layer EdgeConv + max over K + fused concat ----------
__global__ __launch_bounds__(128) void k_conv3(
    const float* __restrict__ feat, const int* __restrict__ nbr,
    const float* __restrict__ w3, const float* __restrict__ b3,
    const float* __restrict__ x1, float* __restrict__ s1)
{
    __shared__ float wbuf[64 * 64];    // 16KB
    __shared__ float df[64][PAD];      // 17KB
    __shared__ float xi_s[64], hx[64], sb[64];
    __shared__ int   nbr_s[KNB];
    __shared__ float redm[2][64];
    int tid = threadIdx.x;
    int node = blockIdx.x;
    int og = tid & 15;
    int kg = tid >> 4;
    int wv = tid >> 6;

    for (int t = tid; t < 4096; t += 128) wbuf[t] = w3[t];
    if (tid < 64) { sb[tid] = b3[tid]; xi_s[tid] = feat[(size_t)node * 64 + tid]; }
    if (tid < KNB) nbr_s[tid] = nbr[(size_t)node * KNB + tid];
    __syncthreads();

    for (int t = tid; t < KNB * 64; t += 128) {
        int k = t >> 6, d = t & 63;
        df[k][d] = feat[(size_t)nbr_s[k] * 64 + d] - xi_s[d];
    }
    for (int t = tid; t < 4 * 64; t += 128) df[60 + (t >> 6)][t & 63] = 0.f;
    if (tid < 64) {
        float acc = sb[tid];
        for (int d = 0; d < 64; ++d) acc = fmaf(xi_s[d], wbuf[d * 64 + tid], acc);
        hx[tid] = acc;
    }
    __syncthreads();

    for (int t = tid; t < 4096; t += 128) wbuf[t] = w3[4096 + t];
    __syncthreads();

    {
        int k0 = 8 * kg;
        float acc[8][4];
#pragma unroll
        for (int j = 0; j < 8; ++j)
#pragma unroll
            for (int i = 0; i < 4; ++i) acc[j][i] = hx[4 * og + i];
        for (int d = 0; d < 64; d += 4) {
            float4 a0 = *(const float4*)&df[k0 + 0][d];
            float4 a1 = *(const float4*)&df[k0 + 1][d];
            float4 a2 = *(const float4*)&df[k0 + 2][d];
            float4 a3 = *(const float4*)&df[k0 + 3][d];
            float4 a4 = *(const float4*)&df[k0 + 4][d];
            float4 a5 = *(const float4*)&df[k0 + 5][d];
            float4 a6 = *(const float4*)&df[k0 + 6][d];
            float4 a7 = *(const float4*)&df[k0 + 7][d];
            float4 b0 = *(const float4*)&wbuf[(d + 0) * 64 + 4 * og];
            float4 b1 = *(const float4*)&wbuf[(d + 1) * 64 + 4 * og];
            float4 b2 = *(const float4*)&wbuf[(d + 2) * 64 + 4 * og];
            float4 b3 = *(const float4*)&wbuf[(d + 3) * 64 + 4 * og];
            const float* av[8] = {(const float*)&a0, (const float*)&a1,
                                  (const float*)&a2, (const float*)&a3,
                                  (const float*)&a4, (const float*)&a5,
                                  (const float*)&a6, (const float*)&a7};
#pragma unroll
            for (int j = 0; j < 8; ++j) {
#pragma unroll
                for (int i = 0; i < 4; ++i) {
                    acc[j][i] = fmaf(av[j][0], ((const float*)&b0)[i], acc[j][i]);
                    acc[j][i] = fmaf(av[j][1], ((const float*)&b1)[i], acc[j][i]);
                    acc[j][i] = fmaf(av[j][2], ((const float*)&b2)[i], acc[j][i]);
                    acc[j][i] = fmaf(av[j][3], ((const float*)&b3)[i], acc[j][i]);
                }
            }
        }
        float m[4];
#pragma unroll
        for (int i = 0; i < 4; ++i) {
            float v = 0.f;
#pragma unroll
            for (int j = 0; j < 8; ++j)
                if (k0 + j < KNB) v = fmaxf(v, fmaxf(acc[j][i], 0.f));
            m[i] = v;
        }
#pragma unroll
        for (int i = 0; i < 4; ++i) {
            m[i] = fmaxf(m[i], __shfl_xor(m[i], 16, 64));
            m[i] = fmaxf(m[i], __shfl_xor(m[i], 32, 64));
        }
        if ((tid & 63) < 16) {
#pragma unroll
            for (int i = 0; i < 4; ++i) redm[wv][4 * og + i] = m[i];
        }
    }
    __syncthreads();
    if (tid < 64) {
        float z = fmaxf(redm[0][tid], redm[1][tid]);
        float* row = s1 + (size_t)node * 192;
        row[tid]       = x1[(size_t)node * 64 + tid];
        row[64 + tid]  = xi_s[tid];        // yv row (this kernel's feat)
        row[128 + tid] = z;
    }
}

// ---------------- generic FC: out = relu(in @ W + b), NB rows per block ----------------
template <int IN_DIM, int OUT_DIM, int NB, int THREADS>
__global__ __launch_bounds__(THREADS) void k_fc(
    const float* __restrict__ in, const float* __restrict__ W,
    const float* __restrict__ bias, float* __restrict__ out)
{
    __shared__ float s_in[NB][IN_DIM];
    constexpr int OCHUNKS = OUT_DIM / THREADS;
    int tid = threadIdx.x;
    int nblk = blockIdx.x / OCHUNKS;
    int ochunk = blockIdx.x % OCHUNKS;
    int n0 = nblk * NB;
    for (int t = tid; t < NB * IN_DIM; t += THREADS) {
        int r = t / IN_DIM, c = t % IN_DIM;
        s_in[r][c] = in[(size_t)(n0 + r) * IN_DIM + c];
    }
    __syncthreads();
    int o = ochunk * THREADS + tid;
    float acc[NB];
#pragma unroll
    for (int r = 0; r < NB; ++r) acc[r] = 0.f;
    for (int k = 0; k < IN_DIM; ++k) {
        float w = W[(size_t)k * OUT_DIM + o];
#pragma unroll
        for (int r = 0; r < NB; ++r) acc[r] = fmaf(s_in[r][k], w, acc[r]);
    }
    float b = bias[o];
#pragma unroll
    for (int r = 0; r < NB; ++r)
        out[(size_t)(n0 + r) * OUT_DIM + o] = fmaxf(acc[r] + b, 0.f);
}

// ---------------- FC2: dual-input (s1:192 | a:1024) @ wf2(1216x256) ----------------
__global__ __launch_bounds__(256) void k_fc2(
    const float* __restrict__ s1, const float* __restrict__ av,
    const float* __restrict__ W, const float* __restrict__ bias,
    float* __restrict__ out)
{
    __shared__ float s_in[8][1216];
    int tid = threadIdx.x;
    int n0 = blockIdx.x * 8;
    for (int t = tid; t < 8 * 192; t += 256) {
        int r = t / 192, c = t % 192;
        s_in[r][c] = s1[(size_t)(n0 + r) * 192 + c];
    }
    for (int t = tid; t < 8 * 1024; t += 256) {
        int r = t / 1024, c = t % 1024;
        s_in[r][192 + c] = av[(size_t)(n0 + r) * 1024 + c];
    }
    __syncthreads();
    float acc[8];
#pragma unroll
    for (int r = 0; r < 8; ++r) acc[r] = 0.f;
    for (int k = 0; k < 1216; ++k) {
        float w = W[(size_t)k * 256 + tid];
#pragma unroll
        for (int r = 0; r < 8; ++r) acc[r] = fmaf(s_in[r][k], w, acc[r]);
    }
    float b = bias[tid];
#pragma unroll
    for (int r = 0; r < 8; ++r)
        out[(size_t)(n0 + r) * 256 + tid] = fmaxf(acc[r] + b, 0.f);
}

// ---------------- FC5 + sigmoid + BCE partial sums ----------------
__global__ __launch_bounds__(256) void k_fc5(
    const float* __restrict__ in, const float* __restrict__ w5,
    const float* __restrict__ b5, const float* __restrict__ labels,
    float* __restrict__ out, float* __restrict__ lsum)
{
    __shared__ float red[4];
    int tid = threadIdx.x;
    int lane = tid & 63;
    int wv = tid >> 6;
    int n = blockIdx.x * 4 + wv;
    float part = 0.f;
    if (n < N_PTS) {
        const float* r = in + (size_t)n * 128;
        float d = r[lane] * w5[lane] + r[64 + lane] * w5[64 + lane];
        for (int off = 32; off > 0; off >>= 1) d += __shfl_down(d, off, 64);
        if (lane == 0) {
            float v = d + b5[0];
            float s = 1.f / (1.f + expf(-v));
            out[1 + n] = s;
            float p = fminf(fmaxf(s, 1e-7f), 1.f - 1e-7f);
            float lab = labels[n];
            part = lab * logf(p) + (1.f - lab) * logf(1.f - p);
        }
    }
    if (lane == 0) red[wv] = part;
    __syncthreads();
    if (tid == 0) atomicAdd(lsum, red[0] + red[1] + red[2] + red[3]);
}

__global__ void k_final(const float* __restrict__ lsum, float* __restrict__ out)
{
    out[0] = -lsum[0] / (float)N_PTS;
}

// ---------------- launch ----------------
extern "C" void kernel_launch(void* const* d_in, const int* in_sizes, int n_in,
                              void* d_out, int out_size, void* d_ws, size_t ws_size,
                              hipStream_t stream)
{
    const float* x   = (const float*)d_in[0];
    const int*   ei  = (const int*)d_in[1];
    const float* lab = (const float*)d_in[2];
    const float* w1a = (const float*)d_in[3];  const float* b1a = (const float*)d_in[4];
    const float* w1b = (const float*)d_in[5];  const float* b1b = (const float*)d_in[6];
    const float* w2a = (const float*)d_in[7];  const float* b2a = (const float*)d_in[8];
    const float* w2b = (const float*)d_in[9];  const float* b2b = (const float*)d_in[10];
    const float* w3  = (const float*)d_in[11]; const float* b3  = (const float*)d_in[12];
    const float* wf1 = (const float*)d_in[13]; const float* bf1 = (const float*)d_in[14];
    const float* wf2 = (const float*)d_in[15]; const float* bf2 = (const float*)d_in[16];
    const float* wf3 = (const float*)d_in[17]; const float* bf3 = (const float*)d_in[18];
    const float* wf4 = (const float*)d_in[19]; const float* bf4 = (const float*)d_in[20];
    const float* wf5 = (const float*)d_in[21]; const float* bf5 = (const float*)d_in[22];
    float* out = (float*)d_out;

    char* wsp = (char*)d_ws;
    size_t off = 0;
    auto pad256 = [](size_t b) { return (b + 255) & ~(size_t)255; };
    auto alloc = [&](size_t bytes) -> void* {
        void* p = wsp + off;
        off += pad256(bytes);
        return p;
    };
    // persistent buffers
    float* x1    = (float*)alloc((size_t)N_PTS * 64 * 4);
    float* yv    = (float*)alloc((size_t)N_PTS * 64 * 4);
    int*   nbr   = (int*)  alloc((size_t)N_PTS * KNB * 4);
    float* lsum  = (float*)alloc(256);
    size_t regionA = off;

    // adaptive chunk: biggest D-chunk that fits alongside persistents (graph-safe:
    // depends only on ws_size). 1000 is the known-good fallback (84 MB total).
    size_t mlpBytes = pad256((size_t)N_PTS * 192 * 4) + pad256((size_t)N_PTS * 1024 * 4)
                    + pad256((size_t)N_PTS * 256 * 4) * 2 + pad256((size_t)N_PTS * 128 * 4);
    size_t ftBytes = pad256((size_t)64 * N_PTS * 4);
    int chunk = 1000;
    const int cands[3] = {2500, 2000, 1000};
    for (int ci = 0; ci < 3; ++ci) {
        size_t knn = ftBytes + pad256((size_t)cands[ci] * N_PTS * 4);
        size_t need = regionA + (knn > mlpBytes ? knn : mlpBytes);
        if (need <= ws_size) { chunk = cands[ci]; break; }
    }

    float* featT = (float*)alloc((size_t)64 * N_PTS * 4);
    float* Dm    = (float*)alloc((size_t)chunk * N_PTS * 4);
    off = regionA;                                                   // rewind: alias
    float* s1    = (float*)alloc((size_t)N_PTS * 192 * 4);
    float* av    = (float*)alloc((size_t)N_PTS * 1024 * 4);
    float* c1    = (float*)alloc((size_t)N_PTS * 256 * 4);
    float* c2    = (float*)alloc((size_t)N_PTS * 256 * 4);
    float* c3    = (float*)alloc((size_t)N_PTS * 128 * 4);

    hipMemsetAsync(x1, 0, (size_t)N_PTS * 64 * 4, stream);
    hipMemsetAsync(lsum, 0, 4, stream);

    k_edge1<<<N_EDGES / 256, 256, 0, stream>>>(x, ei, w1a, b1a, w1b, b1b, x1);

    // KNN 1 on x1
    k_transpose<<<157, 256, 0, stream>>>(x1, featT);
    for (int c0 = 0; c0 < N_PTS; c0 += chunk) {
        k_dist<<<(chunk / QT) * JSPLIT, 256, 0, stream>>>(x1, featT, Dm, c0);
        k_select<<<chunk, 256, 0, stream>>>(Dm, nbr, c0);
    }
    k_conv2<<<N_PTS, 128, 0, stream>>>(x1, nbr, w2a, b2a, w2b, b2b, yv);

    // KNN 2 on yv
    k_transpose<<<157, 256, 0, stream>>>(yv, featT);
    for (int c0 = 0; c0 < N_PTS; c0 += chunk) {
        k_dist<<<(chunk / QT) * JSPLIT, 256, 0, stream>>>(yv, featT, Dm, c0);
        k_select<<<chunk, 256, 0, stream>>>(Dm, nbr, c0);
    }
    k_conv3<<<N_PTS, 128, 0, stream>>>(yv, nbr, w3, b3, x1, s1);   // fused concat

    k_fc<192, 1024, 8, 256><<<(N_PTS / 8) * (1024 / 256), 256, 0, stream>>>(s1, wf1, bf1, av);
    k_fc2<<<N_PTS / 8, 256, 0, stream>>>(s1, av, wf2, bf2, c1);
    k_fc<256, 256, 8, 256><<<N_PTS / 8, 256, 0, stream>>>(c1, wf3, bf3, c2);
    k_fc<256, 128, 8, 128><<<N_PTS / 8, 128, 0, stream>>>(c2, wf4, bf4, c3);
    k_fc5<<<(N_PTS + 3) / 4, 256, 0, stream>>>(c3, wf5, bf5, lab, out, lsum);
    k_final<<<1, 1, 0, stream>>>(lsum, out);
}

// Round 12
// 2268.302 us; speedup vs baseline: 4.1877x; 1.0274x over previous
//
#include <hip/hip_runtime.h>
#include <math.h>

#define N_PTS 10000
#define KNB 60
#define N_EDGES 160000
#define QT 10              // queries per k_dist tile
#define NG 2500            // point-groups of 4 (10000/4)
#define JSPLIT 10          // point-axis split in k_dist
#define PAD 68             // df/h row stride: 272B rows -> 16B aligned, bank-spread

static __device__ __forceinline__ float finf() { return __int_as_float(0x7f800000); }

// ---------------- Stage 1: warp-per-edge MLP2 + coalesced segment_max atomics ----------
__global__ __launch_bounds__(256) void k_edge1(
    const float* __restrict__ x, const int* __restrict__ ei,
    const float* __restrict__ w1a, const float* __restrict__ b1a,
    const float* __restrict__ w1b, const float* __restrict__ b1b,
    float* __restrict__ x1)
{
    __shared__ float sw1a[32 * 64];    // 8KB
    __shared__ float sw1b[64 * 64];    // 16KB
    __shared__ float sb1a[64], sb1b[64];
    __shared__ float hbuf[4][64];
    int tid = threadIdx.x;
    for (int t = tid; t < 32 * 64; t += 256) sw1a[t] = w1a[t];
    for (int t = tid; t < 64 * 64; t += 256) sw1b[t] = w1b[t];
    if (tid < 64) { sb1a[tid] = b1a[tid]; sb1b[tid] = b1b[tid]; }
    __syncthreads();

    int lane = tid & 63;
    int wv = tid >> 6;
    int e0 = blockIdx.x * 256 + wv * 64;

    for (int it = 0; it < 64; ++it) {
        int e = e0 + it;
        int src = ei[e];
        int dst = ei[N_EDGES + e];
        const float4* xi4 = (const float4*)(x + (size_t)dst * 16);
        const float4* xj4 = (const float4*)(x + (size_t)src * 16);
        float f[32];
#pragma unroll
        for (int q = 0; q < 4; ++q) {
            float4 a = xi4[q];              // broadcast loads (uniform addr per wave)
            float4 b = xj4[q];
            f[4 * q + 0] = a.x; f[4 * q + 1] = a.y;
            f[4 * q + 2] = a.z; f[4 * q + 3] = a.w;
            f[16 + 4 * q + 0] = b.x - a.x; f[16 + 4 * q + 1] = b.y - a.y;
            f[16 + 4 * q + 2] = b.z - a.z; f[16 + 4 * q + 3] = b.w - a.w;
        }
        float h = sb1a[lane];
#pragma unroll
        for (int d = 0; d < 32; ++d) h = fmaf(f[d], sw1a[d * 64 + lane], h);
        h = fmaxf(h, 0.f);
        hbuf[wv][lane] = h;                 // wave-synchronous LDS exchange
        float m = sb1b[lane];
#pragma unroll 8
        for (int k = 0; k < 64; ++k) m = fmaf(hbuf[wv][k], sw1b[k * 64 + lane], m);
        m = fmaxf(m, 0.f);
        atomicMax((int*)&x1[(size_t)dst * 64 + lane], __float_as_int(m));
    }
}

// ---------------- transpose feat[10000][64] -> featT[64][10000] ----------------
__global__ __launch_bounds__(256) void k_transpose(const float* __restrict__ feat,
                                                   float* __restrict__ featT)
{
    __shared__ float tile[64][65];
    int tid = threadIdx.x;
    int jb = blockIdx.x * 64;
    for (int t = tid; t < 64 * 64; t += 256) {
        int j = t >> 6, d = t & 63;
        if (jb + j < N_PTS) tile[j][d] = feat[(size_t)(jb + j) * 64 + d];
    }
    __syncthreads();
    for (int t = tid; t < 64 * 64; t += 256) {
        int d = t >> 6, j = t & 63;
        if (jb + j < N_PTS) featT[(size_t)d * N_PTS + jb + j] = tile[j][d];
    }
}

// ---------------- distance chunk: rows [row0, row0+chunk), QT queries/tile ----------
// Per-pair fmaf chain is dims-ascending (single accumulator) == verified round-1/3 chain.
__global__ __launch_bounds__(256) void k_dist(const float* __restrict__ feat,
                                              const float* __restrict__ featT,
                                              float* __restrict__ D, int row0)
{
    __shared__ float qtile[QT][64];
    int tid = threadIdx.x;
    int qi = blockIdx.x / JSPLIT;
    int js = blockIdx.x % JSPLIT;
    int qb = row0 + qi * QT;
    for (int t = tid; t < QT * 64; t += 256) {
        int q = t >> 6, d = t & 63;
        qtile[q][d] = feat[(size_t)(qb + q) * 64 + d];
    }
    __syncthreads();

    const float4* fT4 = (const float4*)featT;       // [64][NG] float4s
    const float4* qt4 = (const float4*)qtile;       // [QT][16]
    int g0 = js * (NG / JSPLIT);
    int g1 = g0 + (NG / JSPLIT);

    for (int g = g0 + tid; g < g1; g += 256) {
        float acc[QT][4];
#pragma unroll
        for (int q = 0; q < QT; ++q) {
            acc[q][0] = 0.f; acc[q][1] = 0.f; acc[q][2] = 0.f; acc[q][3] = 0.f;
        }
        for (int dc = 0; dc < 16; ++dc) {
            float4 p0 = fT4[(size_t)(4 * dc + 0) * NG + g];
            float4 p1 = fT4[(size_t)(4 * dc + 1) * NG + g];
            float4 p2 = fT4[(size_t)(4 * dc + 2) * NG + g];
            float4 p3 = fT4[(size_t)(4 * dc + 3) * NG + g];
#pragma unroll
            for (int q = 0; q < QT; ++q) {
                float4 xq = qt4[q * 16 + dc];       // LDS broadcast
                float dx;
                dx = xq.x - p0.x; acc[q][0] = fmaf(dx, dx, acc[q][0]);
                dx = xq.y - p1.x; acc[q][0] = fmaf(dx, dx, acc[q][0]);
                dx = xq.z - p2.x; acc[q][0] = fmaf(dx, dx, acc[q][0]);
                dx = xq.w - p3.x; acc[q][0] = fmaf(dx, dx, acc[q][0]);
                dx = xq.x - p0.y; acc[q][1] = fmaf(dx, dx, acc[q][1]);
                dx = xq.y - p1.y; acc[q][1] = fmaf(dx, dx, acc[q][1]);
                dx = xq.z - p2.y; acc[q][1] = fmaf(dx, dx, acc[q][1]);
                dx = xq.w - p3.y; acc[q][1] = fmaf(dx, dx, acc[q][1]);
                dx = xq.x - p0.z; acc[q][2] = fmaf(dx, dx, acc[q][2]);
                dx = xq.y - p1.z; acc[q][2] = fmaf(dx, dx, acc[q][2]);
                dx = xq.z - p2.z; acc[q][2] = fmaf(dx, dx, acc[q][2]);
                dx = xq.w - p3.z; acc[q][2] = fmaf(dx, dx, acc[q][2]);
                dx = xq.x - p0.w; acc[q][3] = fmaf(dx, dx, acc[q][3]);
                dx = xq.y - p1.w; acc[q][3] = fmaf(dx, dx, acc[q][3]);
                dx = xq.z - p2.w; acc[q][3] = fmaf(dx, dx, acc[q][3]);
                dx = xq.w - p3.w; acc[q][3] = fmaf(dx, dx, acc[q][3]);
            }
        }
#pragma unroll
        for (int q = 0; q < QT; ++q) {
            float4 v = make_float4(acc[q][0], acc[q][1], acc[q][2], acc[q][3]);
            ((float4*)(D + (size_t)(qb + q - row0) * N_PTS))[g] = v;
        }
    }
}

// ---------------- radix find over replicated histogram, shfl-scan (2 barriers) --------
static __device__ __forceinline__ void radix_find_r(
    const unsigned* hist, int reps, unsigned need, int tid,
    volatile unsigned* wtot, volatile unsigned* outB, volatile unsigned* outCB)
{
    int lane = tid & 63;
    int wv = tid >> 6;
    int base = tid * 8;
    unsigned my = 0;
    for (int w = 0; w < reps; ++w)
#pragma unroll
        for (int b = 0; b < 8; ++b) my += hist[w * 2048 + base + b];

    unsigned incl = my;
#pragma unroll
    for (int off = 1; off < 64; off <<= 1) {
        unsigned v = __shfl_up(incl, off, 64);
        if (lane >= off) incl += v;
    }
    if (lane == 63) wtot[wv] = incl;
    __syncthreads();
    unsigned woff = 0;
    for (int w = 0; w < wv; ++w) woff += wtot[w];
    incl += woff;
    unsigned excl = incl - my;
    if (excl < need && incl >= need) {   // exactly one thread
        unsigned run = excl;
#pragma unroll
        for (int b = 0; b < 8; ++b) {
            unsigned h = 0;
            for (int w = 0; w < reps; ++w) h += hist[w * 2048 + base + b];
            if (run + h >= need) { *outB = base + b; *outCB = run; break; }
            run += h;
        }
    }
    __syncthreads();
}

__global__ __launch_bounds__(256) void k_select(const float* __restrict__ D,
                                                int* __restrict__ nbr, int row0)
{
    __shared__ unsigned hist4[4][2048];     // 32KB
    __shared__ unsigned cand_key[512];
    __shared__ int      cand_idx[512];
    __shared__ unsigned wtot[4];
    __shared__ unsigned sB1, sCB1, sB2, sCB2, s_cnt, s_slot;

    int i = row0 + blockIdx.x;
    int tid = threadIdx.x;
    int wv = tid >> 6;
    if (tid == 0) { s_cnt = 0; s_slot = 0; }

    unsigned kv[10][4];
    const float4* row4 = (const float4*)(D + (size_t)blockIdx.x * N_PTS);
#pragma unroll
    for (int r = 0; r < 10; ++r) {
        int g = tid + 256 * r;
        if (g < NG) {
            float4 v = row4[g];
            kv[r][0] = __float_as_uint(v.x);
            kv[r][1] = __float_as_uint(v.y);
            kv[r][2] = __float_as_uint(v.z);
            kv[r][3] = __float_as_uint(v.w);
            if (g == (i >> 2)) kv[r][i & 3] = 0x7f800000u;   // diagonal -> +inf
        } else {
            kv[r][0] = kv[r][1] = kv[r][2] = kv[r][3] = 0x7fffffffu;  // OOB sentinel
        }
    }

    for (int b = tid; b < 4 * 2048; b += 256) ((unsigned*)hist4)[b] = 0;
    __syncthreads();
#pragma unroll
    for (int r = 0; r < 10; ++r)
#pragma unroll
        for (int c = 0; c < 4; ++c) atomicAdd(&hist4[wv][kv[r][c] >> 20], 1u);
    __syncthreads();
    radix_find_r((const unsigned*)hist4, 4, KNB, tid, wtot, &sB1, &sCB1);
    unsigned B1 = sB1;
    unsigned need2 = KNB - sCB1;

    for (int b = tid; b < 2048; b += 256) hist4[0][b] = 0;
    __syncthreads();
#pragma unroll
    for (int r = 0; r < 10; ++r)
#pragma unroll
        for (int c = 0; c < 4; ++c) {
            unsigned k = kv[r][c];
            if ((k >> 20) == B1) atomicAdd(&hist4[0][(k >> 9) & 2047u], 1u);
        }
    __syncthreads();
    radix_find_r((const unsigned*)hist4, 1, need2, tid, wtot, &sB2, &sCB2);
    unsigned B2 = sB2;

#pragma unroll
    for (int r = 0; r < 10; ++r)
#pragma unroll
        for (int c = 0; c < 4; ++c) {
            unsigned k = kv[r][c];
            unsigned b1 = k >> 20;
            int j = 4 * (tid + 256 * r) + c;
            if (b1 < B1) {
                unsigned slot = atomicAdd(&s_slot, 1u);
                nbr[(size_t)i * KNB + slot] = j;
            } else if (b1 == B1) {
                unsigned b2 = (k >> 9) & 2047u;
                if (b2 < B2) {
                    unsigned slot = atomicAdd(&s_slot, 1u);
                    nbr[(size_t)i * KNB + slot] = j;
                } else if (b2 == B2) {
                    unsigned cc = atomicAdd(&s_cnt, 1u);
                    if (cc < 512) { cand_key[cc] = k; cand_idx[cc] = j; }
                }
            }
        }
    __syncthreads();

    if (tid == 0) {
        int definite = (int)s_slot;
        int needf = KNB - definite;
        int cnt = (int)(s_cnt < 512u ? s_cnt : 512u);
        for (int t = 0; t < needf; ++t) {
            unsigned bk = 0xFFFFFFFFu;
            int bi = 0x7FFFFFFF, bp = -1;
            for (int c = 0; c < cnt; ++c) {
                unsigned k = cand_key[c];
                int id = cand_idx[c];
                if (k < bk || (k == bk && id < bi)) { bk = k; bi = id; bp = c; }
            }
            cand_key[bp] = 0xFFFFFFFFu;
            nbr[(size_t)i * KNB + definite + t] = bi;
        }
    }
}

// ---------------- Stage 2: EdgeConv MLP2 + max over K, 256 thr, h aliased over df ------
// 35.5KB LDS -> 4 blocks/CU. Chains d-ascending, identical init -> bit-identical.
__global__ __launch_bounds__(256) void k_conv2(
    const float* __restrict__ feat, const int* __restrict__ nbr,
    const float* __restrict__ w2a, const float* __restrict__ b2a,
    const float* __restrict__ w2b, const float* __restrict__ b2b,
    float* __restrict__ out)
{
    __shared__ float wbuf[64 * 64];    // 16KB: w2a_lo -> w2a_hi -> w2b
    __shared__ float dfh[64][PAD];     // 17.4KB: df (layer1) then h (layer2)
    __shared__ float xi_s[64], hx[64], sba[64], sbb[64];
    __shared__ int   nbr_s[KNB];
    __shared__ float redm[4][64];
    int tid = threadIdx.x;
    int node = blockIdx.x;
    int og = tid & 15, kg = tid >> 4;  // 4o x 4k tile; kg==15 masked in max
    int wv = tid >> 6;

    // P1: stage w2a rows 0..63 + vectors
    for (int t = tid; t < 4096; t += 256) wbuf[t] = w2a[t];
    if (tid < 64) {
        sba[tid] = b2a[tid]; sbb[tid] = b2b[tid];
        xi_s[tid] = feat[(size_t)node * 64 + tid];
    }
    if (tid < KNB) nbr_s[tid] = nbr[(size_t)node * KNB + tid];
    __syncthreads();

    // P2: gather df + zero pad rows + hx
    for (int t = tid; t < KNB * 64; t += 256) {
        int k = t >> 6, d = t & 63;
        dfh[k][d] = feat[(size_t)nbr_s[k] * 64 + d] - xi_s[d];
    }
    if (tid < 4 * 64) dfh[60 + (tid >> 6)][tid & 63] = 0.f;
    if (tid < 64) {
        float acc = sba[tid];
        for (int d = 0; d < 64; ++d) acc = fmaf(xi_s[d], wbuf[d * 64 + tid], acc);
        hx[tid] = acc;
    }
    __syncthreads();

    // P3: stage w2a rows 64..127
    for (int t = tid; t < 4096; t += 256) wbuf[t] = w2a[4096 + t];
    __syncthreads();

    // P4: layer 1 into registers (no LDS write yet)
    float4 hv[4];
    {
        int k0 = 4 * kg;
        float acc[4][4];
#pragma unroll
        for (int j = 0; j < 4; ++j)
#pragma unroll
            for (int i = 0; i < 4; ++i) acc[j][i] = hx[4 * og + i];
        for (int d = 0; d < 64; d += 4) {
            float4 a0 = *(const float4*)&dfh[k0 + 0][d];
            float4 a1 = *(const float4*)&dfh[k0 + 1][d];
            float4 a2 = *(const float4*)&dfh[k0 + 2][d];
            float4 a3 = *(const float4*)&dfh[k0 + 3][d];
            float4 b0 = *(const float4*)&wbuf[(d + 0) * 64 + 4 * og];
            float4 b1 = *(const float4*)&wbuf[(d + 1) * 64 + 4 * og];
            float4 b2 = *(const float4*)&wbuf[(d + 2) * 64 + 4 * og];
            float4 b3 = *(const float4*)&wbuf[(d + 3) * 64 + 4 * og];
            const float* av[4] = {(const float*)&a0, (const float*)&a1,
                                  (const float*)&a2, (const float*)&a3};
#pragma unroll
            for (int j = 0; j < 4; ++j) {
#pragma unroll
                for (int i = 0; i < 4; ++i) {
                    acc[j][i] = fmaf(av[j][0], ((const float*)&b0)[i], acc[j][i]);
                    acc[j][i] = fmaf(av[j][1], ((const float*)&b1)[i], acc[j][i]);
                    acc[j][i] = fmaf(av[j][2], ((const float*)&b2)[i], acc[j][i]);
                    acc[j][i] = fmaf(av[j][3], ((const float*)&b3)[i], acc[j][i]);
                }
            }
        }
#pragma unroll
        for (int j = 0; j < 4; ++j) {
            hv[j].x = fmaxf(acc[j][0], 0.f); hv[j].y = fmaxf(acc[j][1], 0.f);
            hv[j].z = fmaxf(acc[j][2], 0.f); hv[j].w = fmaxf(acc[j][3], 0.f);
        }
    }
    __syncthreads();      // all df reads done -> safe to overwrite with h

    // P5: write h into dfh + stage w2b
    {
        int k0 = 4 * kg;
#pragma unroll
        for (int j = 0; j < 4; ++j) *(float4*)&dfh[k0 + j][4 * og] = hv[j];
    }
    for (int t = tid; t < 4096; t += 256) wbuf[t] = w2b[t];
    __syncthreads();

    // P6: layer 2 + max over k
    {
        int k0 = 4 * kg;
        float acc[4][4];
#pragma unroll
        for (int j = 0; j < 4; ++j)
#pragma unroll
            for (int i = 0; i < 4; ++i) acc[j][i] = sbb[4 * og + i];
        for (int d = 0; d < 64; d += 4) {
            float4 a0 = *(const float4*)&dfh[k0 + 0][d];
            float4 a1 = *(const float4*)&dfh[k0 + 1][d];
            float4 a2 = *(const float4*)&dfh[k0 + 2][d];
            float4 a3 = *(const float4*)&dfh[k0 + 3][d];
            float4 b0 = *(const float4*)&wbuf[(d + 0) * 64 + 4 * og];
            float4 b1 = *(const float4*)&wbuf[(d + 1) * 64 + 4 * og];
            float4 b2 = *(const float4*)&wbuf[(d + 2) * 64 + 4 * og];
            float4 b3 = *(const float4*)&wbuf[(d + 3) * 64 + 4 * og];
            const float* av[4] = {(const float*)&a0, (const float*)&a1,
                                  (const float*)&a2, (const float*)&a3};
#pragma unroll
            for (int j = 0; j < 4; ++j) {
#pragma unroll
                for (int i = 0; i < 4; ++i) {
                    acc[j][i] = fmaf(av[j][0], ((const float*)&b0)[i], acc[j][i]);
                    acc[j][i] = fmaf(av[j][1], ((const float*)&b1)[i], acc[j][i]);
                    acc[j][i] = fmaf(av[j][2], ((const float*)&b2)[i], acc[j][i]);
                    acc[j][i] = fmaf(av[j][3], ((const float*)&b3)[i], acc[j][i]);
                }
            }
        }
        float m[4];
#pragma unroll
        for (int i = 0; i < 4; ++i) {
            float v = 0.f;   // true outputs >= 0 (relu): 0 is identity
            if (kg < 15) {
#pragma unroll
                for (int j = 0; j < 4; ++j) v = fmaxf(v, fmaxf(acc[j][i], 0.f));
            }
            m[i] = v;
        }
#pragma unroll
        for (int i = 0; i < 4; ++i) {
            m[i] = fmaxf(m[i], __shfl_xor(m[i], 16, 64));
            m[i] = fmaxf(m[i], __shfl_xor(m[i], 32, 64));
        }
        if ((tid & 63) < 16) {
#pragma unroll
            for (int i = 0; i < 4; ++i) redm[wv][4 * og + i] = m[i];
        }
    }
    __syncthreads();
    if (tid < 64)
        out[(size_t)node * 64 + tid] =
            fmaxf(fmaxf(redm[0][tid], redm[1][tid]), fmaxf(redm[2][tid], redm[3][tid]));
}

// ---------------- Stage 3: single-layer EdgeConv + max over K + fused concat ----------
__global__ __launch_bounds__(256) void k_conv3(
    const float* __restrict__ feat, const int* __restrict__ nbr,
    const float* __restrict__ w3, const float* __restrict__ b3,
    const float* __restrict__ x1, float* __restrict__ s1)
{
    __shared__ float wbuf[64 * 64];    // 16KB
    __shared__ float df[64][PAD];      // 17.4KB
    __shared__ float xi_s[64], hx[64], sb[64];
    __shared__ int   nbr_s[KNB];
    __shared__ float redm[4][64];
    int tid = threadIdx.x;
    int node = blockIdx.x;
    int og = tid & 15, kg = tid >> 4;
    int wv = tid >> 6;

    for (int t = tid; t < 4096; t += 256) wbuf[t] = w3[t];
    if (tid < 64) { sb[tid] = b3[tid]; xi_s[tid] = feat[(size_t)node * 64 + tid]; }
    if (tid < KNB) nbr_s[tid] = nbr[(size_t)node * KNB + tid];
    __syncthreads();

    for (int t = tid; t < KNB * 64; t += 256) {
        int k = t >> 6, d = t & 63;
        df[k][d] = feat[(size_t)nbr_s[k] * 64 + d] - xi_s[d];
    }
    if (tid < 4 * 64) df[60 + (tid >> 6)][tid & 63] = 0.f;
    if (tid < 64) {
        float acc = sb[tid];
        for (int d = 0; d < 64; ++d) acc = fmaf(xi_s[d], wbuf[d * 64 + tid], acc);
        hx[tid] = acc;
    }
    __syncthreads();

    for (int t = tid; t < 4096; t += 256) wbuf[t] = w3[4096 + t];
    __syncthreads();

    {
        int k0 = 4 * kg;
        float acc[4][4];
#pragma unroll
        for (int j = 0; j < 4; ++j)
#pragma unroll
            for (int i = 0; i < 4; ++i) acc[j][i] = hx[4 * og + i];
        for (int d = 0; d < 64; d += 4) {
            float4 a0 = *(const float4*)&df[k0 + 0][d];
            float4 a1 = *(const float4*)&df[k0 + 1][d];
            float4 a2 = *(const float4*)&df[k0 + 2][d];
            float4 a3 = *(const float4*)&df[k0 + 3][d];
            float4 b0 = *(const float4*)&wbuf[(d + 0) * 64 + 4 * og];
            float4 b1 = *(const float4*)&wbuf[(d + 1) * 64 + 4 * og];
            float4 b2 = *(const float4*)&wbuf[(d + 2) * 64 + 4 * og];
            float4 b3 = *(const float4*)&wbuf[(d + 3) * 64 + 4 * og];
            const float* av[4] = {(const float*)&a0, (const float*)&a1,
                                  (const float*)&a2, (const float*)&a3};
#pragma unroll
            for (int j = 0; j < 4; ++j) {
#pragma unroll
                for (int i = 0; i < 4; ++i) {
                    acc[j][i] = fmaf(av[j][0], ((const float*)&b0)[i], acc[j][i]);
                    acc[j][i] = fmaf(av[j][1], ((const float*)&b1)[i], acc[j][i]);
                    acc[j][i] = fmaf(av[j][2], ((const float*)&b2)[i], acc[j][i]);
                    acc[j][i] = fmaf(av[j][3], ((const float*)&b3)[i], acc[j][i]);
                }
            }
        }
        float m[4];
#pragma unroll
        for (int i = 0; i < 4; ++i) {
            float v = 0.f;
            if (kg < 15) {
#pragma unroll
                for (int j = 0; j < 4; ++j) v = fmaxf(v, fmaxf(acc[j][i], 0.f));
            }
            m[i] = v;
        }
#pragma unroll
        for (int i = 0; i < 4; ++i) {
            m[i] = fmaxf(m[i], __shfl_xor(m[i], 16, 64));
            m[i] = fmaxf(m[i], __shfl_xor(m[i], 32, 64));
        }
        if ((tid & 63) < 16) {
#pragma unroll
            for (int i = 0; i < 4; ++i) redm[wv][4 * og + i] = m[i];
        }
    }
    __syncthreads();
    if (tid < 64) {
        float z = fmaxf(fmaxf(redm[0][tid], redm[1][tid]),
                        fmaxf(redm[2][tid], redm[3][tid]));
        float* row = s1 + (size_t)node * 192;
        row[tid]       = x1[(size_t)node * 64 + tid];
        row[64 + tid]  = xi_s[tid];        // yv row (this kernel's feat)
        row[128 + tid] = z;
    }
}

// ---------------- generic FC: out = relu(in @ W + b), NB rows per block ----------------
template <int IN_DIM, int OUT_DIM, int NB, int THREADS>
__global__ __launch_bounds__(THREADS) void k_fc(
    const float* __restrict__ in, const float* __restrict__ W,
    const float* __restrict__ bias, float* __restrict__ out)
{
    __shared__ float s_in[NB][IN_DIM];
    constexpr int OCHUNKS = OUT_DIM / THREADS;
    int tid = threadIdx.x;
    int nblk = blockIdx.x / OCHUNKS;
    int ochunk = blockIdx.x % OCHUNKS;
    int n0 = nblk * NB;
    for (int t = tid; t < NB * IN_DIM; t += THREADS) {
        int r = t / IN_DIM, c = t % IN_DIM;
        s_in[r][c] = in[(size_t)(n0 + r) * IN_DIM + c];
    }
    __syncthreads();
    int o = ochunk * THREADS + tid;
    float acc[NB];
#pragma unroll
    for (int r = 0; r < NB; ++r) acc[r] = 0.f;
    for (int k = 0; k < IN_DIM; ++k) {
        float w = W[(size_t)k * OUT_DIM + o];
#pragma unroll
        for (int r = 0; r < NB; ++r) acc[r] = fmaf(s_in[r][k], w, acc[r]);
    }
    float b = bias[o];
#pragma unroll
    for (int r = 0; r < NB; ++r)
        out[(size_t)(n0 + r) * OUT_DIM + o] = fmaxf(acc[r] + b, 0.f);
}

// ---------------- FC2: dual-input (s1:192 | a:1024) @ wf2(1216x256) ----------------
__global__ __launch_bounds__(256) void k_fc2(
    const float* __restrict__ s1, const float* __restrict__ av,
    const float* __restrict__ W, const float* __restrict__ bias,
    float* __restrict__ out)
{
    __shared__ float s_in[8][1216];
    int tid = threadIdx.x;
    int n0 = blockIdx.x * 8;
    for (int t = tid; t < 8 * 192; t += 256) {
        int r = t / 192, c = t % 192;
        s_in[r][c] = s1[(size_t)(n0 + r) * 192 + c];
    }
    for (int t = tid; t < 8 * 1024; t += 256) {
        int r = t / 1024, c = t % 1024;
        s_in[r][192 + c] = av[(size_t)(n0 + r) * 1024 + c];
    }
    __syncthreads();
    float acc[8];
#pragma unroll
    for (int r = 0; r < 8; ++r) acc[r] = 0.f;
    for (int k = 0; k < 1216; ++k) {
        float w = W[(size_t)k * 256 + tid];
#pragma unroll
        for (int r = 0; r < 8; ++r) acc[r] = fmaf(s_in[r][k], w, acc[r]);
    }
    float b = bias[tid];
#pragma unroll
    for (int r = 0; r < 8; ++r)
        out[(size_t)(n0 + r) * 256 + tid] = fmaxf(acc[r] + b, 0.f);
}

// ---------------- FC5 + sigmoid + BCE partial sums ----------------
__global__ __launch_bounds__(256) void k_fc5(
    const float* __restrict__ in, const float* __restrict__ w5,
    const float* __restrict__ b5, const float* __restrict__ labels,
    float* __restrict__ out, float* __restrict__ lsum)
{
    __shared__ float red[4];
    int tid = threadIdx.x;
    int lane = tid & 63;
    int wv = tid >> 6;
    int n = blockIdx.x * 4 + wv;
    float part = 0.f;
    if (n < N_PTS) {
        const float* r = in + (size_t)n * 128;
        float d = r[lane] * w5[lane] + r[64 + lane] * w5[64 + lane];
        for (int off = 32; off > 0; off >>= 1) d += __shfl_down(d, off, 64);
        if (lane == 0) {
            float v = d + b5[0];
            float s = 1.f / (1.f + expf(-v));
            out[1 + n] = s;
            float p = fminf(fmaxf(s, 1e-7f), 1.f - 1e-7f);
            float lab = labels[n];
            part = lab * logf(p) + (1.f - lab) * logf(1.f - p);
        }
    }
    if (lane == 0) red[wv] = part;
    __syncthreads();
    if (tid == 0) atomicAdd(lsum, red[0] + red[1] + red[2] + red[3]);
}

__global__ void k_final(const float* __restrict__ lsum, float* __restrict__ out)
{
    out[0] = -lsum[0] / (float)N_PTS;
}

// ---------------- launch ----------------
extern "C" void kernel_launch(void* const* d_in, const int* in_sizes, int n_in,
                              void* d_out, int out_size, void* d_ws, size_t ws_size,
                              hipStream_t stream)
{
    const float* x   = (const float*)d_in[0];
    const int*   ei  = (const int*)d_in[1];
    const float* lab = (const float*)d_in[2];
    const float* w1a = (const float*)d_in[3];  const float* b1a = (const float*)d_in[4];
    const float* w1b = (const float*)d_in[5];  const float* b1b = (const float*)d_in[6];
    const float* w2a = (const float*)d_in[7];  const float* b2a = (const float*)d_in[8];
    const float* w2b = (const float*)d_in[9];  const float* b2b = (const float*)d_in[10];
    const float* w3  = (const float*)d_in[11]; const float* b3  = (const float*)d_in[12];
    const float* wf1 = (const float*)d_in[13]; const float* bf1 = (const float*)d_in[14];
    const float* wf2 = (const float*)d_in[15]; const float* bf2 = (const float*)d_in[16];
    const float* wf3 = (const float*)d_in[17]; const float* bf3 = (const float*)d_in[18];
    const float* wf4 = (const float*)d_in[19]; const float* bf4 = (const float*)d_in[20];
    const float* wf5 = (const float*)d_in[21]; const float* bf5 = (const float*)d_in[22];
    float* out = (float*)d_out;

    char* wsp = (char*)d_ws;
    size_t off = 0;
    auto pad256 = [](size_t b) { return (b + 255) & ~(size_t)255; };
    auto alloc = [&](size_t bytes) -> void* {
        void* p = wsp + off;
        off += pad256(bytes);
        return p;
    };
    // persistent buffers
    float* x1    = (float*)alloc((size_t)N_PTS * 64 * 4);
    float* yv    = (float*)alloc((size_t)N_PTS * 64 * 4);
    int*   nbr   = (int*)  alloc((size_t)N_PTS * KNB * 4);
    float* lsum  = (float*)alloc(256);
    size_t regionA = off;

    // adaptive chunk: biggest D-chunk that fits (graph-safe: depends only on ws_size).
    size_t mlpBytes = pad256((size_t)N_PTS * 192 * 4) + pad256((size_t)N_PTS * 1024 * 4)
                    + pad256((size_t)N_PTS * 256 * 4) * 2 + pad256((size_t)N_PTS * 128 * 4);
    size_t ftBytes = pad256((size_t)64 * N_PTS * 4);
    int chunk = 1000;
    const int cands[4] = {5000, 2500, 2000, 1000};
    for (int ci = 0; ci < 4; ++ci) {
        size_t knn = ftBytes + pad256((size_t)cands[ci] * N_PTS * 4);
        size_t need = regionA + (knn > mlpBytes ? knn : mlpBytes);
        if (need <= ws_size) { chunk = cands[ci]; break; }
    }

    float* featT = (float*)alloc((size_t)64 * N_PTS * 4);
    float* Dm    = (float*)alloc((size_t)chunk * N_PTS * 4);
    off = regionA;                                                   // rewind: alias
    float* s1    = (float*)alloc((size_t)N_PTS * 192 * 4);
    float* av    = (float*)alloc((size_t)N_PTS * 1024 * 4);
    float* c1    = (float*)alloc((size_t)N_PTS * 256 * 4);
    float* c2    = (float*)alloc((size_t)N_PTS * 256 * 4);
    float* c3    = (float*)alloc((size_t)N_PTS * 128 * 4);

    hipMemsetAsync(x1, 0, (size_t)N_PTS * 64 * 4, stream);
    hipMemsetAsync(lsum, 0, 4, stream);

    k_edge1<<<N_EDGES / 256, 256, 0, stream>>>(x, ei, w1a, b1a, w1b, b1b, x1);

    // KNN 1 on x1
    k_transpose<<<157, 256, 0, stream>>>(x1, featT);
    for (int c0 = 0; c0 < N_PTS; c0 += chunk) {
        k_dist<<<(chunk / QT) * JSPLIT, 256, 0, stream>>>(x1, featT, Dm, c0);
        k_select<<<chunk, 256, 0, stream>>>(Dm, nbr, c0);
    }
    k_conv2<<<N_PTS, 256, 0, stream>>>(x1, nbr, w2a, b2a, w2b, b2b, yv);

    // KNN 2 on yv
    k_transpose<<<157, 256, 0, stream>>>(yv, featT);
    for (int c0 = 0; c0 < N_PTS; c0 += chunk) {
        k_dist<<<(chunk / QT) * JSPLIT, 256, 0, stream>>>(yv, featT, Dm, c0);
        k_select<<<chunk, 256, 0, stream>>>(Dm, nbr, c0);
    }
    k_conv3<<<N_PTS, 256, 0, stream>>>(yv, nbr, w3, b3, x1, s1);   // fused concat

    k_fc<192, 1024, 16, 256><<<(N_PTS / 16) * (1024 / 256), 256, 0, stream>>>(s1, wf1, bf1, av);
    k_fc2<<<N_PTS / 8, 256, 0, stream>>>(s1, av, wf2, bf2, c1);
    k_fc<256, 256, 16, 256><<<N_PTS / 16, 256, 0, stream>>>(c1, wf3, bf3, c2);
    k_fc<256, 128, 16, 128><<<N_PTS / 16, 128, 0, stream>>>(c2, wf4, bf4, c3);
    k_fc5<<<(N_PTS + 3) / 4, 256, 0, stream>>>(c3, wf5, bf5, lab, out, lsum);
    k_final<<<1, 1, 0, stream>>>(lsum, out);
}